// Round 4
// baseline (115.353 us; speedup 1.0000x reference)
//
#include <hip/hip_runtime.h>
#include <hip/hip_bf16.h>
#include <cmath>

// Problem constants (LocalAttention: B=2, S=2048, D=1024, H=16, HD=64, W=16)
#define S_LEN 2048
#define DMODEL 1024
#define NH 16
#define HD_DIM 64

typedef __bf16 bf16;
typedef __bf16 bf16x2 __attribute__((ext_vector_type(2)));
typedef __bf16 bf16x8 __attribute__((ext_vector_type(8)));
typedef float f32x4 __attribute__((ext_vector_type(4)));

// ---------------------------------------------------------------------------
// fp32 -> bf16 convert (vectorized, 4 elems/thread)
// ---------------------------------------------------------------------------
__global__ void cvt_f32_bf16(const float* __restrict__ in, bf16* __restrict__ out, int n) {
    int i = (blockIdx.x * blockDim.x + threadIdx.x) * 4;
    if (i < n) {
        float4 v = *(const float4*)(in + i);
        bf16 o[4];
        o[0] = (bf16)v.x; o[1] = (bf16)v.y; o[2] = (bf16)v.z; o[3] = (bf16)v.w;
        *(short4*)(out + i) = *(const short4*)o;
    }
}

// ---------------------------------------------------------------------------
// All four W [K][N] fp32 -> Wt [N][K] bf16 in one launch (grid.z = which W)
// ---------------------------------------------------------------------------
__global__ void transpose_cvt_all(const float* __restrict__ Wq, const float* __restrict__ Wk,
                                  const float* __restrict__ Wv, const float* __restrict__ Wo,
                                  bf16* __restrict__ wtall, bf16* __restrict__ wot) {
    __shared__ float tile[64][65];
    int z = blockIdx.z;
    const float* W = (z == 0) ? Wq : (z == 1) ? Wk : (z == 2) ? Wv : Wo;
    bf16* Wt = (z == 3) ? wot : wtall + (size_t)z * 1048576;
    int k0 = blockIdx.y * 64, n0 = blockIdx.x * 64;
    int tr = threadIdx.x >> 6, tc = threadIdx.x & 63;
#pragma unroll
    for (int i = 0; i < 16; ++i) {
        int r = tr + i * 4;
        tile[r][tc] = W[(size_t)(k0 + r) * DMODEL + n0 + tc];
    }
    __syncthreads();
#pragma unroll
    for (int i = 0; i < 16; ++i) {
        int r = tr + i * 4;  // local n index
        Wt[(size_t)(n0 + r) * DMODEL + k0 + tc] = (bf16)tile[tc][r];
    }
}

// ---------------------------------------------------------------------------
// concat bq|bk|bv -> bias_all[3072]
// ---------------------------------------------------------------------------
__global__ void bias_concat(const float* __restrict__ bq, const float* __restrict__ bk,
                            const float* __restrict__ bv, float* __restrict__ out) {
    int i = blockIdx.x * 256 + threadIdx.x;  // 0..3071
    float v;
    if (i < 1024)       v = bq[i];
    else if (i < 2048)  v = bk[i - 1024];
    else                v = bv[i - 2048];
    out[i] = v;
}

// ---------------------------------------------------------------------------
// async global->LDS, 16B per lane (dest = wave-uniform base + lane*16)
// ---------------------------------------------------------------------------
__device__ __forceinline__ void gload_lds16(const void* g, void* l) {
    __builtin_amdgcn_global_load_lds((const __attribute__((address_space(1))) void*)g,
                                     (__attribute__((address_space(3))) void*)l, 16, 0, 0);
}

// ===========================================================================
// 256x256 8-phase GEMM (T2 swizzle + T3/T4 counted vmcnt(6) + T5 setprio)
//   C[M][N](bf16) = A[M][K](bf16) * Bt[N][K](bf16)^T + bias[N]
//   512 threads = 8 waves (2 M x 4 N), per-wave 128x64 output.
//   Pipeline depth: 3 half-tiles in flight at every VMC(6) (m201 steady state).
//   Stage placement derived from buffer-region death times:
//     buf.B dead after p2 -> stage next B at p3/p4; buf.A dead after p3 -> p4/p5.
// ===========================================================================
#define BAR() asm volatile("s_barrier" ::: "memory")
#define VMC(N) asm volatile("s_waitcnt vmcnt(" #N ")" ::: "memory")

#define STAGE_A(T, H, DB) do {                                                         \
    gload_lds16(aSrc + (size_t)((H) * 128) * KDIM + (T) * 64,                          \
                aDst + (DB) * 32768 + (H) * 16384);                                    \
    gload_lds16(aSrc + (size_t)((H) * 128 + 64) * KDIM + (T) * 64,                     \
                aDst + (DB) * 32768 + (H) * 16384 + 8192);                             \
} while (0)
#define STAGE_B(T, H, DB) do {                                                         \
    gload_lds16(bSrc + (size_t)((H) * 128) * KDIM + (T) * 64,                          \
                bDst + (DB) * 32768 + (H) * 16384);                                    \
    gload_lds16(bSrc + (size_t)((H) * 128 + 64) * KDIM + (T) * 64,                     \
                bDst + (DB) * 32768 + (H) * 16384 + 8192);                             \
} while (0)
#define RD_A(D, MH) do {                                                               \
    _Pragma("unroll") for (int _m = 0; _m < 4; ++_m) {                                 \
        a[_m][0] = *(const bf16x8*)(sc + (D) * 32768 + aBase + ((MH) * 4 + _m) * 2048 + ks0); \
        a[_m][1] = *(const bf16x8*)(sc + (D) * 32768 + aBase + ((MH) * 4 + _m) * 2048 + ks1); \
    }                                                                                  \
} while (0)
#define RD_B(D, NB) do {                                                               \
    _Pragma("unroll") for (int _n = 0; _n < 2; ++_n) {                                 \
        b[(NB) * 2 + _n][0] = *(const bf16x8*)(sc + (D) * 32768 + bBase + ((NB) * 2 + _n) * 2048 + ks0); \
        b[(NB) * 2 + _n][1] = *(const bf16x8*)(sc + (D) * 32768 + bBase + ((NB) * 2 + _n) * 2048 + ks1); \
    }                                                                                  \
} while (0)
#define MFMA16(MH, NB) do {                                                            \
    __builtin_amdgcn_s_setprio(1);                                                     \
    _Pragma("unroll") for (int _m = 0; _m < 4; ++_m)                                   \
    _Pragma("unroll") for (int _n = 0; _n < 2; ++_n)                                   \
    _Pragma("unroll") for (int _k = 0; _k < 2; ++_k)                                   \
        acc[(MH) * 4 + _m][(NB) * 2 + _n] = __builtin_amdgcn_mfma_f32_16x16x32_bf16(   \
            a[_m][_k], b[(NB) * 2 + _n][_k], acc[(MH) * 4 + _m][(NB) * 2 + _n], 0, 0, 0); \
    __builtin_amdgcn_s_setprio(0);                                                     \
} while (0)

template <int KDIM>
__global__ __launch_bounds__(512, 2) void gemm256(const bf16* __restrict__ A,
                                                  const bf16* __restrict__ Bt,
                                                  bf16* __restrict__ C,
                                                  const float* __restrict__ bias,
                                                  int N) {
    __shared__ bf16 smem[65536];  // 128 KiB: A[0:64K), B[64K:128K)
    char* sc = (char*)smem;

    const int tid  = threadIdx.x;
    const int wv   = tid >> 6;
    const int lane = tid & 63;
    const int ll   = lane & 15;
    const int kh   = lane >> 4;
    const int wm   = wv >> 2;  // 0..1
    const int wn   = wv & 3;   // 0..3
    const int m0   = blockIdx.x * 256;
    const int n0   = blockIdx.y * 256;

    // Staging: per-thread inverse-swizzled global source, linear LDS dest.
    const int swcol = (((tid & 7) ^ ((tid >> 3) & 7)) << 3);  // element offset
    const bf16* aSrc = A + (size_t)(m0 + (tid >> 3)) * KDIM + swcol;
    const bf16* bSrc = Bt + (size_t)(n0 + (tid >> 3)) * KDIM + swcol;
    char* aDst = sc + wv * 1024;
    char* bDst = sc + 65536 + wv * 1024;

    // Read side: swizzle XOR = ((row&7)<<4), row&7 == ll&7 for all fragments.
    const int aBase = wm * 16384 + ll * 128;
    const int bBase = 65536 + (wn >> 1) * 16384 + ((wn & 1) * 64 + ll) * 128;
    const int ks0 = ((kh ^ (ll & 7)) << 4);        // k-slice 0 col-block byte
    const int ks1 = (((4 | kh) ^ (ll & 7)) << 4);  // k-slice 1

    f32x4 acc[8][4] = {};
    bf16x8 a[4][2], b[4][2];

    // ---- prologue: tile0 fully + tile1 {B.h0, B.h1, A.h0}; VMC(6) keeps 3
    //      half-tiles in flight entering steady state ----
    STAGE_B(0, 0, 0); STAGE_B(0, 1, 0); STAGE_A(0, 0, 0); STAGE_A(0, 1, 0);
    STAGE_B(1, 0, 1); STAGE_B(1, 1, 1); STAGE_A(1, 0, 1);
    VMC(6); BAR();

    constexpr int NT = KDIM / 64;  // K-tiles (even, >=4)

    // steady state in-flight at p4's VMC(6): t+1{B0,B1,A0,A1} (8, drained) +
    // t+2{B0,B1,A0} (6, kept); at p8's VMC(6): t+2 drained, t+3{B0,B1,A0} kept.
#pragma unroll 1
    for (int t = 0; t < NT - 2; t += 2) {
        RD_A(0, 0); RD_B(0, 0); STAGE_A(t + 1, 1, 1);                       BAR(); MFMA16(0, 0); BAR();
        RD_B(0, 1);                                                         BAR(); MFMA16(0, 1); BAR();
        RD_A(0, 1);             STAGE_B(t + 2, 0, 0);                       BAR(); MFMA16(1, 1); BAR();
                                STAGE_B(t + 2, 1, 0); STAGE_A(t + 2, 0, 0); BAR(); MFMA16(1, 0); VMC(6); BAR();
        RD_A(1, 0); RD_B(1, 0); STAGE_A(t + 2, 1, 0);                       BAR(); MFMA16(0, 0); BAR();
        RD_B(1, 1);                                                         BAR(); MFMA16(0, 1); BAR();
        RD_A(1, 1);             STAGE_B(t + 3, 0, 1);                       BAR(); MFMA16(1, 1); BAR();
                                STAGE_B(t + 3, 1, 1); STAGE_A(t + 3, 0, 1); BAR(); MFMA16(1, 0); VMC(6); BAR();
    }

    // ---- epilogue: tiles NT-2 (buf0), NT-1 (buf1) ----
    {
        RD_A(0, 0); RD_B(0, 0); STAGE_A(NT - 1, 1, 1); BAR(); MFMA16(0, 0); BAR();
        RD_B(0, 1);                                    BAR(); MFMA16(0, 1); BAR();
        RD_A(0, 1);                                    BAR(); MFMA16(1, 1); BAR();
                                                       BAR(); MFMA16(1, 0); VMC(0); BAR();
        RD_A(1, 0); RD_B(1, 0);                        BAR(); MFMA16(0, 0); BAR();
        RD_B(1, 1);                                    BAR(); MFMA16(0, 1); BAR();
        RD_A(1, 1);                                    BAR(); MFMA16(1, 1); BAR();
                                                              MFMA16(1, 0);
    }

    // ---- C write: row = wm*128+mf*16+kh*4+r, col = wn*64+nf*16+ll ----
#pragma unroll
    for (int nf = 0; nf < 4; ++nf) {
        const int col = n0 + wn * 64 + nf * 16 + ll;
        const float bv_ = bias[col];
#pragma unroll
        for (int mf = 0; mf < 8; ++mf) {
            const int row = m0 + wm * 128 + mf * 16 + kh * 4;
#pragma unroll
            for (int r = 0; r < 4; ++r)
                C[(size_t)(row + r) * N + col] = (bf16)(acc[mf][nf][r] + bv_);
        }
    }
}

// ===========================================================================
// Output projection: 128x128 tile, BK=64, double-buffered 2-phase
// (stage next tile before compute; one vmcnt(0)+barrier per K-tile),
// T2 swizzle, fp32 output (coalesced 64B lines). K = 1024. 4 waves.
// ===========================================================================
#define OP_STAGE(D, TT) do {                                                           \
    _Pragma("unroll") for (int _i = 0; _i < 4; ++_i) {                                 \
        gload_lds16(aSrc + (size_t)(_i * 32) * 1024 + (TT) * 64,                       \
                    aDst + (D) * 16384 + _i * 4096);                                   \
        gload_lds16(bSrc + (size_t)(_i * 32) * 1024 + (TT) * 64,                       \
                    bDst + (D) * 16384 + _i * 4096);                                   \
    }                                                                                  \
} while (0)

__global__ __launch_bounds__(256) void gemm_op(const bf16* __restrict__ A,
                                               const bf16* __restrict__ Bt,
                                               float* __restrict__ C,
                                               const float* __restrict__ bias,
                                               int N) {
    __shared__ bf16 smem[32768];  // 64 KiB: A[2][16KB] at 0, B[2][16KB] at 32768
    char* sc = (char*)smem;
    const int tid  = threadIdx.x;
    const int wv   = tid >> 6;
    const int lane = tid & 63;
    const int ll   = lane & 15;
    const int kh   = lane >> 4;
    const int wm   = wv >> 1;  // 0..1
    const int wn   = wv & 1;   // 0..1
    const int m0   = blockIdx.x * 128;
    const int n0   = blockIdx.y * 128;

    const int swcol = (((tid & 7) ^ ((tid >> 3) & 7)) << 3);
    const bf16* aSrc = A + (size_t)(m0 + (tid >> 3)) * 1024 + swcol;
    const bf16* bSrc = Bt + (size_t)(n0 + (tid >> 3)) * 1024 + swcol;
    char* aDst = sc + tid * 16;
    char* bDst = sc + 32768 + tid * 16;

    const int aBase = (wm * 64 + ll) * 128;
    const int bBase = 32768 + (wn * 64 + ll) * 128;
    const int ks0 = ((kh ^ (ll & 7)) << 4);
    const int ks1 = (((4 | kh) ^ (ll & 7)) << 4);

    f32x4 acc[4][4] = {};
    bf16x8 af[4][2], bfr[4][2];

    OP_STAGE(0, 0);
    VMC(0); BAR();

#pragma unroll 1
    for (int t = 0; t < 16; ++t) {
        const int d = t & 1;
        if (t < 15) OP_STAGE(d ^ 1, t + 1);
#pragma unroll
        for (int mf = 0; mf < 4; ++mf) {
            af[mf][0] = *(const bf16x8*)(sc + d * 16384 + aBase + mf * 2048 + ks0);
            af[mf][1] = *(const bf16x8*)(sc + d * 16384 + aBase + mf * 2048 + ks1);
        }
#pragma unroll
        for (int nf = 0; nf < 4; ++nf) {
            bfr[nf][0] = *(const bf16x8*)(sc + d * 16384 + bBase + nf * 2048 + ks0);
            bfr[nf][1] = *(const bf16x8*)(sc + d * 16384 + bBase + nf * 2048 + ks1);
        }
        __builtin_amdgcn_s_setprio(1);
#pragma unroll
        for (int mf = 0; mf < 4; ++mf)
#pragma unroll
            for (int nf = 0; nf < 4; ++nf)
#pragma unroll
                for (int k = 0; k < 2; ++k)
                    acc[mf][nf] = __builtin_amdgcn_mfma_f32_16x16x32_bf16(
                        af[mf][k], bfr[nf][k], acc[mf][nf], 0, 0, 0);
        __builtin_amdgcn_s_setprio(0);
        if (t < 15) { VMC(0); BAR(); }
    }

#pragma unroll
    for (int mf = 0; mf < 4; ++mf) {
#pragma unroll
        for (int nf = 0; nf < 4; ++nf) {
            int col = n0 + wn * 64 + nf * 16 + ll;
            float bv_ = bias[col];
#pragma unroll
            for (int r = 0; r < 4; ++r) {
                int row = m0 + wm * 64 + mf * 16 + kh * 4 + r;
                C[(size_t)row * N + col] = acc[mf][nf][r] + bv_;
            }
        }
    }
}

// ---------------------------------------------------------------------------
// V column sums, stage 1: partial[b*128+chunk][1024] = sum of 16 rows of V
// grid = 256 blocks, 256 threads.
// ---------------------------------------------------------------------------
__global__ __launch_bounds__(256) void vsum_part(const bf16* __restrict__ qkv,
                                                 float* __restrict__ part) {
    int blk = blockIdx.x;       // 0..255
    int b = blk >> 7, chunk = blk & 127;
    int cg = threadIdx.x & 127; // column group of 8
    int jp = threadIdx.x >> 7;  // 0..1
    int j0 = chunk * 16 + jp * 8;

    float acc[8] = {};
#pragma unroll
    for (int r = 0; r < 8; ++r) {
        int j = j0 + r;
        bf16x8 v = *(const bf16x8*)&qkv[(size_t)(b * S_LEN + j) * 3072 + 2048 + cg * 8];
#pragma unroll
        for (int e = 0; e < 8; ++e) acc[e] += (float)v[e];
    }

    __shared__ float red[256][8];
#pragma unroll
    for (int e = 0; e < 8; ++e) red[threadIdx.x][e] = acc[e];
    __syncthreads();
    if (jp == 0) {
        float* outp = part + ((size_t)blk << 10) + cg * 8;
#pragma unroll
        for (int e = 0; e < 8; ++e)
            outp[e] = red[threadIdx.x][e] + red[threadIdx.x + 128][e];
    }
}

// ---------------------------------------------------------------------------
// V column sums, stage 2: vsum[b*1024 + col] = sum over 128 chunks
// ---------------------------------------------------------------------------
__global__ void vsum_final(const float* __restrict__ part, float* __restrict__ vsum) {
    int idx = blockIdx.x * 256 + threadIdx.x;  // 0..2047
    int b = idx >> 10, col = idx & 1023;
    float s = 0.f;
#pragma unroll
    for (int c = 0; c < 128; ++c) s += part[(((size_t)b * 128 + c) << 10) + col];
    vsum[idx] = s;  // layout [b][h][d] == b*1024 + h*64 + d
}

// ---------------------------------------------------------------------------
// Band attention. Per block: one (b, h, 64-row i-tile).
//   w_ij = expm1(q_i . k_j / 8)  for |i-j| <= 8, 0 <= j < S
//   ctx_i = (sum_j w_ij v_j + Vsum) / (sum_j w_ij + S)
// ---------------------------------------------------------------------------
__global__ __launch_bounds__(256) void band_attn(const bf16* __restrict__ qkv,
                                                 const float* __restrict__ vsum,
                                                 bf16* __restrict__ ctx) {
    int bid = blockIdx.x;
    int it = bid & 31;
    int h  = (bid >> 5) & 15;
    int b  = bid >> 9;
    const int i0 = it * 64;

    __shared__ bf16 qs[64 * 72];
    __shared__ bf16 ks[80 * 72];
    __shared__ bf16 vs[80 * 72];
    __shared__ float wsc[64 * 19];
    __shared__ float wsum[64];

    int tid = threadIdx.x;

    // load q tile (64 rows x 128B)
    for (int idx = tid; idx < 64 * 8; idx += 256) {
        int r = idx >> 3, c = idx & 7;
        size_t g = (size_t)(b * S_LEN + i0 + r) * 3072 + h * 64 + c * 8;
        *(int4*)&qs[r * 72 + c * 8] = *(const int4*)&qkv[g];
    }
    // load k/v tiles (80 rows, j = i0-8+r), zero-fill out of range
    for (int idx = tid; idx < 80 * 8; idx += 256) {
        int r = idx >> 3, c = idx & 7;
        int j = i0 - 8 + r;
        int4 kv = {0, 0, 0, 0}, vv = {0, 0, 0, 0};
        if (j >= 0 && j < S_LEN) {
            size_t base = (size_t)(b * S_LEN + j) * 3072 + h * 64 + c * 8;
            kv = *(const int4*)&qkv[base + 1024];
            vv = *(const int4*)&qkv[base + 2048];
        }
        *(int4*)&ks[r * 72 + c * 8] = kv;
        *(int4*)&vs[r * 72 + c * 8] = vv;
    }
    __syncthreads();

    // phase 2: band weights (q-row hoisted to registers, reused over jj)
    {
        int i = tid >> 2, jg = tid & 3;
        bf16x8 qv[8];
#pragma unroll
        for (int c = 0; c < 8; ++c) qv[c] = *(const bf16x8*)&qs[i * 72 + c * 8];
        for (int jj = jg; jj < 17; jj += 4) {
            int j = i0 + i - 8 + jj;
            float w = 0.f;
            if (j >= 0 && j < S_LEN) {
                float dot = 0.f;
#pragma unroll
                for (int c = 0; c < 8; ++c) {
                    bf16x8 kv = *(const bf16x8*)&ks[(i + jj) * 72 + c * 8];
#pragma unroll
                    for (int e = 0; e < 8; ++e) dot += (float)qv[c][e] * (float)kv[e];
                }
                w = expm1f(dot * 0.125f);
            }
            wsc[i * 19 + jj] = w;
        }
    }
    __syncthreads();
    if (tid < 64) {
        float s = 0.f;
#pragma unroll
        for (int jj = 0; jj < 17; ++jj) s += wsc[tid * 19 + jj];
        wsum[tid] = s + (float)S_LEN;
    }
    __syncthreads();

    // phase 3: weighted V accumulation, 2 cols/thread (b32 LDS reads, 4B stores)
    {
        int d0 = (tid & 31) * 2, ig = tid >> 5;
        float vb0 = vsum[(b * NH + h) * HD_DIM + d0];
        float vb1 = vsum[(b * NH + h) * HD_DIM + d0 + 1];
        for (int i = ig; i < 64; i += 8) {
            float a0 = vb0, a1 = vb1;
#pragma unroll
            for (int jj = 0; jj < 17; ++jj) {
                float w = wsc[i * 19 + jj];
                bf16x2 pv = *(const bf16x2*)&vs[(i + jj) * 72 + d0];
                a0 += w * (float)pv[0];
                a1 += w * (float)pv[1];
            }
            float inv = 1.0f / wsum[i];
            bf16x2 st;
            st[0] = (bf16)(a0 * inv);
            st[1] = (bf16)(a1 * inv);
            *(bf16x2*)&ctx[(size_t)(b * S_LEN + i0 + i) * 1024 + h * 64 + d0] = st;
        }
    }
}

// ---------------------------------------------------------------------------
extern "C" void kernel_launch(void* const* d_in, const int* in_sizes, int n_in,
                              void* d_out, int out_size, void* d_ws, size_t ws_size,
                              hipStream_t stream) {
    const float* x  = (const float*)d_in[0];
    const float* Wq = (const float*)d_in[1];
    const float* Wk = (const float*)d_in[2];
    const float* Wv = (const float*)d_in[3];
    const float* Wo = (const float*)d_in[4];
    const float* bq = (const float*)d_in[5];
    const float* bk = (const float*)d_in[6];
    const float* bv = (const float*)d_in[7];
    const float* bo = (const float*)d_in[8];

    char* ws = (char*)d_ws;
    bf16*  xb    = (bf16*)(ws);                       // 8 MB   x as bf16
    bf16*  wtall = (bf16*)(ws + 8388608);             // 6 MB   [Wq^T;Wk^T;Wv^T] bf16 [3072][1024]
    bf16*  wot   = (bf16*)(ws + 14680064);            // 2 MB   Wo^T bf16 [1024][1024]
    float* ball  = (float*)(ws + 16777216);           // 12 KB  bias concat [3072]
    bf16*  qkv   = (bf16*)(ws + 16789504);            // 24 MB  [4096][3072] bf16
    bf16*  ctxb  = (bf16*)(ws + 41955328);            // 8 MB   ctx bf16 [4096][1024]
    float* vsm   = (float*)(ws + 50343936);           // 8 KB   [32][64] == [b][h][d]
    float* vpart = (float*)(ws);                      // 1 MB, aliases xb (dead after QKV GEMM)

    cvt_f32_bf16<<<4096, 256, 0, stream>>>(x, xb, 4194304);
    transpose_cvt_all<<<dim3(16, 16, 4), 256, 0, stream>>>(Wq, Wk, Wv, Wo, wtall, wot);
    bias_concat<<<12, 256, 0, stream>>>(bq, bk, bv, ball);

    // QKV projection: [4096][1024] x [3072][1024]^T -> [4096][3072] bf16
    gemm256<1024><<<dim3(16, 12), 512, 0, stream>>>(xb, wtall, qkv, ball, 3072);

    vsum_part<<<256, 256, 0, stream>>>(qkv, vpart);
    vsum_final<<<8, 256, 0, stream>>>(vpart, vsm);
    band_attn<<<1024, 256, 0, stream>>>(qkv, vsm, ctxb);

    // output projection -> d_out fp32
    gemm_op<<<dim3(32, 8), 256, 0, stream>>>(ctxb, wot, (float*)d_out, bo, 1024);
}

// Round 5
// 111.113 us; speedup vs baseline: 1.0382x; 1.0382x over previous
//
#include <hip/hip_runtime.h>
#include <hip/hip_bf16.h>
#include <cmath>

// Problem constants (LocalAttention: B=2, S=2048, D=1024, H=16, HD=64, W=16)
#define S_LEN 2048
#define DMODEL 1024
#define NH 16
#define HD_DIM 64

typedef __bf16 bf16;
typedef __bf16 bf16x2 __attribute__((ext_vector_type(2)));
typedef __bf16 bf16x8 __attribute__((ext_vector_type(8)));
typedef float f32x4 __attribute__((ext_vector_type(4)));

// ---------------------------------------------------------------------------
// Fused preprocessing: block-range dispatch
//   [0,2048)      : x fp32 -> bf16 (8 elems/thread)
//   [2048,3072)   : W[K][N] fp32 -> Wt[N][K] bf16 transpose (4 matrices)
//   [3072,3084)   : bias concat bq|bk|bv -> ball[3072]
// ---------------------------------------------------------------------------
__global__ __launch_bounds__(256) void prep_all(const float* __restrict__ x,
                                                const float* __restrict__ Wq,
                                                const float* __restrict__ Wk,
                                                const float* __restrict__ Wv,
                                                const float* __restrict__ Wo,
                                                const float* __restrict__ bq,
                                                const float* __restrict__ bk,
                                                const float* __restrict__ bv,
                                                bf16* __restrict__ xb,
                                                bf16* __restrict__ wtall,
                                                bf16* __restrict__ wot,
                                                float* __restrict__ ball) {
    __shared__ float tile[64][65];
    const int bid = blockIdx.x;
    const int tid = threadIdx.x;
    if (bid < 2048) {
        int i = (bid * 256 + tid) * 8;
        float4 v0 = *(const float4*)(x + i);
        float4 v1 = *(const float4*)(x + i + 4);
        bf16x8 o;
        o[0] = (bf16)v0.x; o[1] = (bf16)v0.y; o[2] = (bf16)v0.z; o[3] = (bf16)v0.w;
        o[4] = (bf16)v1.x; o[5] = (bf16)v1.y; o[6] = (bf16)v1.z; o[7] = (bf16)v1.w;
        *(bf16x8*)(xb + i) = o;
    } else if (bid < 3072) {
        int t = bid - 2048;
        int z = t >> 8;
        t &= 255;
        const float* W = (z == 0) ? Wq : (z == 1) ? Wk : (z == 2) ? Wv : Wo;
        bf16* Wt = (z == 3) ? wot : wtall + (size_t)z * 1048576;
        int n0 = (t & 15) * 64, k0 = (t >> 4) * 64;
        int tr = tid >> 6, tc = tid & 63;
#pragma unroll
        for (int i = 0; i < 16; ++i) {
            int r = tr + i * 4;
            tile[r][tc] = W[(size_t)(k0 + r) * DMODEL + n0 + tc];
        }
        __syncthreads();
#pragma unroll
        for (int i = 0; i < 16; ++i) {
            int r = tr + i * 4;  // local n index
            Wt[(size_t)(n0 + r) * DMODEL + k0 + tc] = (bf16)tile[tc][r];
        }
    } else {
        int i = (bid - 3072) * 256 + tid;  // 0..3071
        float v = (i < 1024) ? bq[i] : (i < 2048) ? bk[i - 1024] : bv[i - 2048];
        ball[i] = v;
    }
}

// ---------------------------------------------------------------------------
// async global->LDS, 16B per lane (dest = wave-uniform base + lane*16)
// ---------------------------------------------------------------------------
__device__ __forceinline__ void gload_lds16(const void* g, void* l) {
    __builtin_amdgcn_global_load_lds((const __attribute__((address_space(1))) void*)g,
                                     (__attribute__((address_space(3))) void*)l, 16, 0, 0);
}

// ===========================================================================
// 256x256 8-phase GEMM (T1 XCD swizzle + T2 swizzle + T3/T4 vmcnt(6) + T5)
//   C[M][N](bf16) = A[M][K](bf16) * Bt[N][K](bf16)^T + bias[N]
//   512 threads = 8 waves (2 M x 4 N), per-wave 128x64 output.
//   3 half-tiles in flight at every VMC(6) (m201 steady state).
// ===========================================================================
#define BAR() asm volatile("s_barrier" ::: "memory")
#define VMC(N) asm volatile("s_waitcnt vmcnt(" #N ")" ::: "memory")

#define STAGE_A(T, H, DB) do {                                                         \
    gload_lds16(aSrc + (size_t)((H) * 128) * KDIM + (T) * 64,                          \
                aDst + (DB) * 32768 + (H) * 16384);                                    \
    gload_lds16(aSrc + (size_t)((H) * 128 + 64) * KDIM + (T) * 64,                     \
                aDst + (DB) * 32768 + (H) * 16384 + 8192);                             \
} while (0)
#define STAGE_B(T, H, DB) do {                                                         \
    gload_lds16(bSrc + (size_t)((H) * 128) * KDIM + (T) * 64,                          \
                bDst + (DB) * 32768 + (H) * 16384);                                    \
    gload_lds16(bSrc + (size_t)((H) * 128 + 64) * KDIM + (T) * 64,                     \
                bDst + (DB) * 32768 + (H) * 16384 + 8192);                             \
} while (0)
#define RD_A(D, MH) do {                                                               \
    _Pragma("unroll") for (int _m = 0; _m < 4; ++_m) {                                 \
        a[_m][0] = *(const bf16x8*)(sc + (D) * 32768 + aBase + ((MH) * 4 + _m) * 2048 + ks0); \
        a[_m][1] = *(const bf16x8*)(sc + (D) * 32768 + aBase + ((MH) * 4 + _m) * 2048 + ks1); \
    }                                                                                  \
} while (0)
#define RD_B(D, NB) do {                                                               \
    _Pragma("unroll") for (int _n = 0; _n < 2; ++_n) {                                 \
        b[(NB) * 2 + _n][0] = *(const bf16x8*)(sc + (D) * 32768 + bBase + ((NB) * 2 + _n) * 2048 + ks0); \
        b[(NB) * 2 + _n][1] = *(const bf16x8*)(sc + (D) * 32768 + bBase + ((NB) * 2 + _n) * 2048 + ks1); \
    }                                                                                  \
} while (0)
#define MFMA16(MH, NB) do {                                                            \
    __builtin_amdgcn_s_setprio(1);                                                     \
    _Pragma("unroll") for (int _m = 0; _m < 4; ++_m)                                   \
    _Pragma("unroll") for (int _n = 0; _n < 2; ++_n)                                   \
    _Pragma("unroll") for (int _k = 0; _k < 2; ++_k)                                   \
        acc[(MH) * 4 + _m][(NB) * 2 + _n] = __builtin_amdgcn_mfma_f32_16x16x32_bf16(   \
            a[_m][_k], b[(NB) * 2 + _n][_k], acc[(MH) * 4 + _m][(NB) * 2 + _n], 0, 0, 0); \
    __builtin_amdgcn_s_setprio(0);                                                     \
} while (0)

template <int KDIM>
__global__ __launch_bounds__(512, 2) void gemm256(const bf16* __restrict__ A,
                                                  const bf16* __restrict__ Bt,
                                                  bf16* __restrict__ C,
                                                  const float* __restrict__ bias,
                                                  int N) {
    __shared__ bf16 smem[65536];  // 128 KiB: A[0:64K), B[64K:128K)
    char* sc = (char*)smem;

    const int tid  = threadIdx.x;
    const int wv   = tid >> 6;
    const int lane = tid & 63;
    const int ll   = lane & 15;
    const int kh   = lane >> 4;
    const int wm   = wv >> 2;  // 0..1
    const int wn   = wv & 3;   // 0..3

    // XCD-aware swizzle: 192 blocks, 8 XCDs, 24 consecutive tiles per XCD
    // (m-fastest within XCD -> B-panel reuse stays XCD-local).
    const int flat = blockIdx.y * 16 + blockIdx.x;       // gridDim = (16,12)
    const int L    = (flat & 7) * 24 + (flat >> 3);      // bijective, 192%8==0
    const int m0   = (L & 15) * 256;
    const int n0   = (L >> 4) * 256;

    // Staging: per-thread inverse-swizzled global source, linear LDS dest.
    const int swcol = (((tid & 7) ^ ((tid >> 3) & 7)) << 3);  // element offset
    const bf16* aSrc = A + (size_t)(m0 + (tid >> 3)) * KDIM + swcol;
    const bf16* bSrc = Bt + (size_t)(n0 + (tid >> 3)) * KDIM + swcol;
    char* aDst = sc + wv * 1024;
    char* bDst = sc + 65536 + wv * 1024;

    // Read side: swizzle XOR = ((row&7)<<4), row&7 == ll&7 for all fragments.
    const int aBase = wm * 16384 + ll * 128;
    const int bBase = 65536 + (wn >> 1) * 16384 + ((wn & 1) * 64 + ll) * 128;
    const int ks0 = ((kh ^ (ll & 7)) << 4);        // k-slice 0 col-block byte
    const int ks1 = (((4 | kh) ^ (ll & 7)) << 4);  // k-slice 1

    f32x4 acc[8][4] = {};
    bf16x8 a[4][2], b[4][2];

    // ---- prologue: tile0 fully + tile1 {B.h0, B.h1, A.h0}; VMC(6) keeps 3
    //      half-tiles in flight entering steady state ----
    STAGE_B(0, 0, 0); STAGE_B(0, 1, 0); STAGE_A(0, 0, 0); STAGE_A(0, 1, 0);
    STAGE_B(1, 0, 1); STAGE_B(1, 1, 1); STAGE_A(1, 0, 1);
    VMC(6); BAR();

    constexpr int NT = KDIM / 64;  // K-tiles (even, >=4)

#pragma unroll 1
    for (int t = 0; t < NT - 2; t += 2) {
        RD_A(0, 0); RD_B(0, 0); STAGE_A(t + 1, 1, 1);                       BAR(); MFMA16(0, 0); BAR();
        RD_B(0, 1);                                                         BAR(); MFMA16(0, 1); BAR();
        RD_A(0, 1);             STAGE_B(t + 2, 0, 0);                       BAR(); MFMA16(1, 1); BAR();
                                STAGE_B(t + 2, 1, 0); STAGE_A(t + 2, 0, 0); BAR(); MFMA16(1, 0); VMC(6); BAR();
        RD_A(1, 0); RD_B(1, 0); STAGE_A(t + 2, 1, 0);                       BAR(); MFMA16(0, 0); BAR();
        RD_B(1, 1);                                                         BAR(); MFMA16(0, 1); BAR();
        RD_A(1, 1);             STAGE_B(t + 3, 0, 1);                       BAR(); MFMA16(1, 1); BAR();
                                STAGE_B(t + 3, 1, 1); STAGE_A(t + 3, 0, 1); BAR(); MFMA16(1, 0); VMC(6); BAR();
    }

    // ---- epilogue: tiles NT-2 (buf0), NT-1 (buf1) ----
    {
        RD_A(0, 0); RD_B(0, 0); STAGE_A(NT - 1, 1, 1); BAR(); MFMA16(0, 0); BAR();
        RD_B(0, 1);                                    BAR(); MFMA16(0, 1); BAR();
        RD_A(0, 1);                                    BAR(); MFMA16(1, 1); BAR();
                                                       BAR(); MFMA16(1, 0); VMC(0); BAR();
        RD_A(1, 0); RD_B(1, 0);                        BAR(); MFMA16(0, 0); BAR();
        RD_B(1, 1);                                    BAR(); MFMA16(0, 1); BAR();
        RD_A(1, 1);                                    BAR(); MFMA16(1, 1); BAR();
                                                              MFMA16(1, 0);
    }

    // ---- C write: row = wm*128+mf*16+kh*4+r, col = wn*64+nf*16+ll ----
#pragma unroll
    for (int nf = 0; nf < 4; ++nf) {
        const int col = n0 + wn * 64 + nf * 16 + ll;
        const float bv_ = bias[col];
#pragma unroll
        for (int mf = 0; mf < 8; ++mf) {
            const int row = m0 + wm * 128 + mf * 16 + kh * 4;
#pragma unroll
            for (int r = 0; r < 4; ++r)
                C[(size_t)(row + r) * N + col] = (bf16)(acc[mf][nf][r] + bv_);
        }
    }
}

// ===========================================================================
// Output projection: 128x128 tile, BK=64, 3-buffer counted-vmcnt pipeline.
//   Stage tile t+2 each iteration; VMC(8) waits exactly for tile t (8 loads/
//   thread, issued 2 iterations earlier). One barrier per K-tile. T1+T2.
// ===========================================================================
#define OP_STAGE(D, TT) do {                                                           \
    _Pragma("unroll") for (int _i = 0; _i < 4; ++_i) {                                 \
        gload_lds16(aSrc + (size_t)(_i * 32) * 1024 + (TT) * 64,                       \
                    aDst + (D) * 16384 + _i * 4096);                                   \
        gload_lds16(bSrc + (size_t)(_i * 32) * 1024 + (TT) * 64,                       \
                    bDst + (D) * 16384 + _i * 4096);                                   \
    }                                                                                  \
} while (0)

__global__ __launch_bounds__(256) void gemm_op(const bf16* __restrict__ A,
                                               const bf16* __restrict__ Bt,
                                               float* __restrict__ C,
                                               const float* __restrict__ bias,
                                               int N) {
    __shared__ bf16 smem[49152];  // 96 KiB: A[3][16KB] at 0, B[3][16KB] at 49152
    char* sc = (char*)smem;
    const int tid  = threadIdx.x;
    const int wv   = tid >> 6;
    const int lane = tid & 63;
    const int ll   = lane & 15;
    const int kh   = lane >> 4;
    const int wm   = wv >> 1;  // 0..1
    const int wn   = wv & 1;   // 0..1

    // XCD swizzle: 256 blocks -> each XCD gets exactly one n-panel (all 32 m).
    const int flat = blockIdx.y * 32 + blockIdx.x;   // gridDim = (32,8)
    const int L    = (flat & 7) * 32 + (flat >> 3);
    const int m0   = (L & 31) * 128;
    const int n0   = (L >> 5) * 128;

    const int swcol = (((tid & 7) ^ ((tid >> 3) & 7)) << 3);
    const bf16* aSrc = A + (size_t)(m0 + (tid >> 3)) * 1024 + swcol;
    const bf16* bSrc = Bt + (size_t)(n0 + (tid >> 3)) * 1024 + swcol;
    char* aDst = sc + tid * 16;
    char* bDst = sc + 49152 + tid * 16;

    const int aBase = (wm * 64 + ll) * 128;
    const int bBase = 49152 + (wn * 64 + ll) * 128;
    const int ks0 = ((kh ^ (ll & 7)) << 4);
    const int ks1 = (((4 | kh) ^ (ll & 7)) << 4);

    f32x4 acc[4][4] = {};
    bf16x8 af[4][2], bfr[4][2];

    OP_STAGE(0, 0);
    OP_STAGE(1, 1);

#pragma unroll
    for (int t = 0; t < 16; ++t) {
        const int d = t % 3;
        if (t == 15) { VMC(0); } else { VMC(8); }  // drain exactly tile t
        BAR();
        if (t < 14) OP_STAGE((t + 2) % 3, t + 2);  // targets buf (t-1)%3: reads
                                                   // done before last barrier
#pragma unroll
        for (int mf = 0; mf < 4; ++mf) {
            af[mf][0] = *(const bf16x8*)(sc + d * 16384 + aBase + mf * 2048 + ks0);
            af[mf][1] = *(const bf16x8*)(sc + d * 16384 + aBase + mf * 2048 + ks1);
        }
#pragma unroll
        for (int nf = 0; nf < 4; ++nf) {
            bfr[nf][0] = *(const bf16x8*)(sc + d * 16384 + bBase + nf * 2048 + ks0);
            bfr[nf][1] = *(const bf16x8*)(sc + d * 16384 + bBase + nf * 2048 + ks1);
        }
        __builtin_amdgcn_s_setprio(1);
#pragma unroll
        for (int mf = 0; mf < 4; ++mf)
#pragma unroll
            for (int nf = 0; nf < 4; ++nf)
#pragma unroll
                for (int k = 0; k < 2; ++k)
                    acc[mf][nf] = __builtin_amdgcn_mfma_f32_16x16x32_bf16(
                        af[mf][k], bfr[nf][k], acc[mf][nf], 0, 0, 0);
        __builtin_amdgcn_s_setprio(0);
    }

#pragma unroll
    for (int mf = 0; mf < 4; ++mf) {
#pragma unroll
        for (int nf = 0; nf < 4; ++nf) {
            int col = n0 + wn * 64 + nf * 16 + ll;
            float bv_ = bias[col];
#pragma unroll
            for (int r = 0; r < 4; ++r) {
                int row = m0 + wm * 64 + mf * 16 + kh * 4 + r;
                C[(size_t)row * N + col] = acc[mf][nf][r] + bv_;
            }
        }
    }
}

// ---------------------------------------------------------------------------
// V column sums, stage 1: partial[b*128+chunk][1024] = sum of 16 rows of V
// ---------------------------------------------------------------------------
__global__ __launch_bounds__(256) void vsum_part(const bf16* __restrict__ qkv,
                                                 float* __restrict__ part) {
    int blk = blockIdx.x;       // 0..255
    int b = blk >> 7, chunk = blk & 127;
    int cg = threadIdx.x & 127; // column group of 8
    int jp = threadIdx.x >> 7;  // 0..1
    int j0 = chunk * 16 + jp * 8;

    float acc[8] = {};
#pragma unroll
    for (int r = 0; r < 8; ++r) {
        int j = j0 + r;
        bf16x8 v = *(const bf16x8*)&qkv[(size_t)(b * S_LEN + j) * 3072 + 2048 + cg * 8];
#pragma unroll
        for (int e = 0; e < 8; ++e) acc[e] += (float)v[e];
    }

    __shared__ float red[256][8];
#pragma unroll
    for (int e = 0; e < 8; ++e) red[threadIdx.x][e] = acc[e];
    __syncthreads();
    if (jp == 0) {
        float* outp = part + ((size_t)blk << 10) + cg * 8;
#pragma unroll
        for (int e = 0; e < 8; ++e)
            outp[e] = red[threadIdx.x][e] + red[threadIdx.x + 128][e];
    }
}

// ---------------------------------------------------------------------------
// V column sums, stage 2: vsum[b*1024 + col] = sum over 128 chunks
// ---------------------------------------------------------------------------
__global__ void vsum_final(const float* __restrict__ part, float* __restrict__ vsum) {
    int idx = blockIdx.x * 256 + threadIdx.x;  // 0..2047
    int b = idx >> 10, col = idx & 1023;
    float s = 0.f;
#pragma unroll
    for (int c = 0; c < 128; ++c) s += part[(((size_t)b * 128 + c) << 10) + col];
    vsum[idx] = s;  // layout [b][h][d] == b*1024 + h*64 + d
}

// ---------------------------------------------------------------------------
// Band attention. Per block: one (b, h, 64-row i-tile).
//   w_ij = expm1(q_i . k_j / 8)  for |i-j| <= 8, 0 <= j < S
//   ctx_i = (sum_j w_ij v_j + Vsum) / (sum_j w_ij + S)
// ---------------------------------------------------------------------------
__global__ __launch_bounds__(256) void band_attn(const bf16* __restrict__ qkv,
                                                 const float* __restrict__ vsum,
                                                 bf16* __restrict__ ctx) {
    int bid = blockIdx.x;
    int it = bid & 31;
    int h  = (bid >> 5) & 15;
    int b  = bid >> 9;
    const int i0 = it * 64;

    __shared__ bf16 qs[64 * 72];
    __shared__ bf16 ks[80 * 72];
    __shared__ bf16 vs[80 * 72];
    __shared__ float wsc[64 * 19];
    __shared__ float wsum[64];

    int tid = threadIdx.x;

    // load q tile (64 rows x 128B)
    for (int idx = tid; idx < 64 * 8; idx += 256) {
        int r = idx >> 3, c = idx & 7;
        size_t g = (size_t)(b * S_LEN + i0 + r) * 3072 + h * 64 + c * 8;
        *(int4*)&qs[r * 72 + c * 8] = *(const int4*)&qkv[g];
    }
    // load k/v tiles (80 rows, j = i0-8+r), zero-fill out of range
    for (int idx = tid; idx < 80 * 8; idx += 256) {
        int r = idx >> 3, c = idx & 7;
        int j = i0 - 8 + r;
        int4 kv = {0, 0, 0, 0}, vv = {0, 0, 0, 0};
        if (j >= 0 && j < S_LEN) {
            size_t base = (size_t)(b * S_LEN + j) * 3072 + h * 64 + c * 8;
            kv = *(const int4*)&qkv[base + 1024];
            vv = *(const int4*)&qkv[base + 2048];
        }
        *(int4*)&ks[r * 72 + c * 8] = kv;
        *(int4*)&vs[r * 72 + c * 8] = vv;
    }
    __syncthreads();

    // phase 2: band weights (q-row hoisted to registers, reused over jj)
    {
        int i = tid >> 2, jg = tid & 3;
        bf16x8 qv[8];
#pragma unroll
        for (int c = 0; c < 8; ++c) qv[c] = *(const bf16x8*)&qs[i * 72 + c * 8];
        for (int jj = jg; jj < 17; jj += 4) {
            int j = i0 + i - 8 + jj;
            float w = 0.f;
            if (j >= 0 && j < S_LEN) {
                float dot = 0.f;
#pragma unroll
                for (int c = 0; c < 8; ++c) {
                    bf16x8 kv = *(const bf16x8*)&ks[(i + jj) * 72 + c * 8];
#pragma unroll
                    for (int e = 0; e < 8; ++e) dot += (float)qv[c][e] * (float)kv[e];
                }
                w = expm1f(dot * 0.125f);
            }
            wsc[i * 19 + jj] = w;
        }
    }
    __syncthreads();
    if (tid < 64) {
        float s = 0.f;
#pragma unroll
        for (int jj = 0; jj < 17; ++jj) s += wsc[tid * 19 + jj];
        wsum[tid] = s + (float)S_LEN;
    }
    __syncthreads();

    // phase 3: weighted V accumulation, 2 cols/thread (b32 LDS reads, 4B stores)
    {
        int d0 = (tid & 31) * 2, ig = tid >> 5;
        float vb0 = vsum[(b * NH + h) * HD_DIM + d0];
        float vb1 = vsum[(b * NH + h) * HD_DIM + d0 + 1];
        for (int i = ig; i < 64; i += 8) {
            float a0 = vb0, a1 = vb1;
#pragma unroll
            for (int jj = 0; jj < 17; ++jj) {
                float w = wsc[i * 19 + jj];
                bf16x2 pv = *(const bf16x2*)&vs[(i + jj) * 72 + d0];
                a0 += w * (float)pv[0];
                a1 += w * (float)pv[1];
            }
            float inv = 1.0f / wsum[i];
            bf16x2 st;
            st[0] = (bf16)(a0 * inv);
            st[1] = (bf16)(a1 * inv);
            *(bf16x2*)&ctx[(size_t)(b * S_LEN + i0 + i) * 1024 + h * 64 + d0] = st;
        }
    }
}

// ---------------------------------------------------------------------------
extern "C" void kernel_launch(void* const* d_in, const int* in_sizes, int n_in,
                              void* d_out, int out_size, void* d_ws, size_t ws_size,
                              hipStream_t stream) {
    const float* x  = (const float*)d_in[0];
    const float* Wq = (const float*)d_in[1];
    const float* Wk = (const float*)d_in[2];
    const float* Wv = (const float*)d_in[3];
    const float* Wo = (const float*)d_in[4];
    const float* bq = (const float*)d_in[5];
    const float* bk = (const float*)d_in[6];
    const float* bv = (const float*)d_in[7];
    const float* bo = (const float*)d_in[8];

    char* ws = (char*)d_ws;
    bf16*  xb    = (bf16*)(ws);                       // 8 MB   x as bf16
    bf16*  wtall = (bf16*)(ws + 8388608);             // 6 MB   [Wq^T;Wk^T;Wv^T] bf16 [3072][1024]
    bf16*  wot   = (bf16*)(ws + 14680064);            // 2 MB   Wo^T bf16 [1024][1024]
    float* ball  = (float*)(ws + 16777216);           // 12 KB  bias concat [3072]
    bf16*  qkv   = (bf16*)(ws + 16789504);            // 24 MB  [4096][3072] bf16
    bf16*  ctxb  = (bf16*)(ws + 41955328);            // 8 MB   ctx bf16 [4096][1024]
    float* vsm   = (float*)(ws + 50343936);           // 8 KB   [32][64] == [b][h][d]
    float* vpart = (float*)(ws);                      // 1 MB, aliases xb (dead after QKV GEMM)

    // fused: cvt(2048 blocks) + 4x transpose(1024) + bias(12)
    prep_all<<<3084, 256, 0, stream>>>(x, Wq, Wk, Wv, Wo, bq, bk, bv,
                                       xb, wtall, wot, ball);

    // QKV projection: [4096][1024] x [3072][1024]^T -> [4096][3072] bf16
    gemm256<1024><<<dim3(16, 12), 512, 0, stream>>>(xb, wtall, qkv, ball, 3072);

    vsum_part<<<256, 256, 0, stream>>>(qkv, vpart);
    vsum_final<<<8, 256, 0, stream>>>(vpart, vsm);
    band_attn<<<1024, 256, 0, stream>>>(qkv, vsm, ctxb);

    // output projection -> d_out fp32
    gemm_op<<<dim3(32, 8), 256, 0, stream>>>(ctxb, wot, (float*)d_out, bo, 1024);
}

// Round 6
// 111.041 us; speedup vs baseline: 1.0388x; 1.0006x over previous
//
#include <hip/hip_runtime.h>
#include <hip/hip_bf16.h>
#include <cmath>

// Problem constants (LocalAttention: B=2, S=2048, D=1024, H=16, HD=64, W=16)
#define S_LEN 2048
#define DMODEL 1024
#define NH 16
#define HD_DIM 64

typedef __bf16 bf16;
typedef __bf16 bf16x2 __attribute__((ext_vector_type(2)));
typedef __bf16 bf16x8 __attribute__((ext_vector_type(8)));
typedef float f32x4 __attribute__((ext_vector_type(4)));

// ---------------------------------------------------------------------------
// Fused preprocessing: block-range dispatch
//   [0,2048)      : x fp32 -> bf16 (8 elems/thread)
//   [2048,3072)   : W[K][N] fp32 -> Wt[N][K] bf16 transpose (4 matrices)
//   [3072,3084)   : bias concat bq|bk|bv -> ball[3072]
// ---------------------------------------------------------------------------
__global__ __launch_bounds__(256) void prep_all(const float* __restrict__ x,
                                                const float* __restrict__ Wq,
                                                const float* __restrict__ Wk,
                                                const float* __restrict__ Wv,
                                                const float* __restrict__ Wo,
                                                const float* __restrict__ bq,
                                                const float* __restrict__ bk,
                                                const float* __restrict__ bv,
                                                bf16* __restrict__ xb,
                                                bf16* __restrict__ wtall,
                                                bf16* __restrict__ wot,
                                                float* __restrict__ ball) {
    __shared__ float tile[64][65];
    const int bid = blockIdx.x;
    const int tid = threadIdx.x;
    if (bid < 2048) {
        int i = (bid * 256 + tid) * 8;
        float4 v0 = *(const float4*)(x + i);
        float4 v1 = *(const float4*)(x + i + 4);
        bf16x8 o;
        o[0] = (bf16)v0.x; o[1] = (bf16)v0.y; o[2] = (bf16)v0.z; o[3] = (bf16)v0.w;
        o[4] = (bf16)v1.x; o[5] = (bf16)v1.y; o[6] = (bf16)v1.z; o[7] = (bf16)v1.w;
        *(bf16x8*)(xb + i) = o;
    } else if (bid < 3072) {
        int t = bid - 2048;
        int z = t >> 8;
        t &= 255;
        const float* W = (z == 0) ? Wq : (z == 1) ? Wk : (z == 2) ? Wv : Wo;
        bf16* Wt = (z == 3) ? wot : wtall + (size_t)z * 1048576;
        int n0 = (t & 15) * 64, k0 = (t >> 4) * 64;
        int tr = tid >> 6, tc = tid & 63;
#pragma unroll
        for (int i = 0; i < 16; ++i) {
            int r = tr + i * 4;
            tile[r][tc] = W[(size_t)(k0 + r) * DMODEL + n0 + tc];
        }
        __syncthreads();
#pragma unroll
        for (int i = 0; i < 16; ++i) {
            int r = tr + i * 4;  // local n index
            Wt[(size_t)(n0 + r) * DMODEL + k0 + tc] = (bf16)tile[tc][r];
        }
    } else {
        int i = (bid - 3072) * 256 + tid;  // 0..3071
        float v = (i < 1024) ? bq[i] : (i < 2048) ? bk[i - 1024] : bv[i - 2048];
        ball[i] = v;
    }
}

// ---------------------------------------------------------------------------
// async global->LDS, 16B per lane (dest = wave-uniform base + lane*16)
// ---------------------------------------------------------------------------
__device__ __forceinline__ void gload_lds16(const void* g, void* l) {
    __builtin_amdgcn_global_load_lds((const __attribute__((address_space(1))) void*)g,
                                     (__attribute__((address_space(3))) void*)l, 16, 0, 0);
}

// ===========================================================================
// 256x256 8-phase GEMM (T1 XCD swizzle + T2 swizzle + T3/T4 vmcnt(6) + T5)
//   C[M][N](bf16) = A[M][K](bf16) * Bt[N][K](bf16)^T + bias[N]
//   512 threads = 8 waves (2 M x 4 N), per-wave 128x64 output.
//   3 half-tiles in flight at every VMC(6) (m201 steady state).
// ===========================================================================
#define BAR() asm volatile("s_barrier" ::: "memory")
#define VMC(N) asm volatile("s_waitcnt vmcnt(" #N ")" ::: "memory")

#define STAGE_A(T, H, DB) do {                                                         \
    gload_lds16(aSrc + (size_t)((H) * 128) * KDIM + (T) * 64,                          \
                aDst + (DB) * 32768 + (H) * 16384);                                    \
    gload_lds16(aSrc + (size_t)((H) * 128 + 64) * KDIM + (T) * 64,                     \
                aDst + (DB) * 32768 + (H) * 16384 + 8192);                             \
} while (0)
#define STAGE_B(T, H, DB) do {                                                         \
    gload_lds16(bSrc + (size_t)((H) * 128) * KDIM + (T) * 64,                          \
                bDst + (DB) * 32768 + (H) * 16384);                                    \
    gload_lds16(bSrc + (size_t)((H) * 128 + 64) * KDIM + (T) * 64,                     \
                bDst + (DB) * 32768 + (H) * 16384 + 8192);                             \
} while (0)
#define RD_A(D, MH) do {                                                               \
    _Pragma("unroll") for (int _m = 0; _m < 4; ++_m) {                                 \
        a[_m][0] = *(const bf16x8*)(sc + (D) * 32768 + aBase + ((MH) * 4 + _m) * 2048 + ks0); \
        a[_m][1] = *(const bf16x8*)(sc + (D) * 32768 + aBase + ((MH) * 4 + _m) * 2048 + ks1); \
    }                                                                                  \
} while (0)
#define RD_B(D, NB) do {                                                               \
    _Pragma("unroll") for (int _n = 0; _n < 2; ++_n) {                                 \
        b[(NB) * 2 + _n][0] = *(const bf16x8*)(sc + (D) * 32768 + bBase + ((NB) * 2 + _n) * 2048 + ks0); \
        b[(NB) * 2 + _n][1] = *(const bf16x8*)(sc + (D) * 32768 + bBase + ((NB) * 2 + _n) * 2048 + ks1); \
    }                                                                                  \
} while (0)
#define MFMA16(MH, NB) do {                                                            \
    __builtin_amdgcn_s_setprio(1);                                                     \
    _Pragma("unroll") for (int _m = 0; _m < 4; ++_m)                                   \
    _Pragma("unroll") for (int _n = 0; _n < 2; ++_n)                                   \
    _Pragma("unroll") for (int _k = 0; _k < 2; ++_k)                                   \
        acc[(MH) * 4 + _m][(NB) * 2 + _n] = __builtin_amdgcn_mfma_f32_16x16x32_bf16(   \
            a[_m][_k], b[(NB) * 2 + _n][_k], acc[(MH) * 4 + _m][(NB) * 2 + _n], 0, 0, 0); \
    __builtin_amdgcn_s_setprio(0);                                                     \
} while (0)

template <int KDIM>
__global__ __launch_bounds__(512, 2) void gemm256(const bf16* __restrict__ A,
                                                  const bf16* __restrict__ Bt,
                                                  bf16* __restrict__ C,
                                                  const float* __restrict__ bias,
                                                  int N) {
    __shared__ bf16 smem[65536];  // 128 KiB: A[0:64K), B[64K:128K)
    char* sc = (char*)smem;

    const int tid  = threadIdx.x;
    const int wv   = tid >> 6;
    const int lane = tid & 63;
    const int ll   = lane & 15;
    const int kh   = lane >> 4;
    const int wm   = wv >> 2;  // 0..1
    const int wn   = wv & 3;   // 0..3

    // XCD-aware swizzle: 192 blocks, 8 XCDs, 24 consecutive tiles per XCD
    // (m-fastest within XCD -> B-panel reuse stays XCD-local).
    const int flat = blockIdx.y * 16 + blockIdx.x;       // gridDim = (16,12)
    const int L    = (flat & 7) * 24 + (flat >> 3);      // bijective, 192%8==0
    const int m0   = (L & 15) * 256;
    const int n0   = (L >> 4) * 256;

    // Staging: per-thread inverse-swizzled global source, linear LDS dest.
    const int swcol = (((tid & 7) ^ ((tid >> 3) & 7)) << 3);  // element offset
    const bf16* aSrc = A + (size_t)(m0 + (tid >> 3)) * KDIM + swcol;
    const bf16* bSrc = Bt + (size_t)(n0 + (tid >> 3)) * KDIM + swcol;
    char* aDst = sc + wv * 1024;
    char* bDst = sc + 65536 + wv * 1024;

    // Read side: swizzle XOR = ((row&7)<<4), row&7 == ll&7 for all fragments.
    const int aBase = wm * 16384 + ll * 128;
    const int bBase = 65536 + (wn >> 1) * 16384 + ((wn & 1) * 64 + ll) * 128;
    const int ks0 = ((kh ^ (ll & 7)) << 4);        // k-slice 0 col-block byte
    const int ks1 = (((4 | kh) ^ (ll & 7)) << 4);  // k-slice 1

    f32x4 acc[8][4] = {};
    bf16x8 a[4][2], b[4][2];

    // ---- prologue: tile0 fully + tile1 {B.h0, B.h1, A.h0}; VMC(6) keeps 3
    //      half-tiles in flight entering steady state ----
    STAGE_B(0, 0, 0); STAGE_B(0, 1, 0); STAGE_A(0, 0, 0); STAGE_A(0, 1, 0);
    STAGE_B(1, 0, 1); STAGE_B(1, 1, 1); STAGE_A(1, 0, 1);
    VMC(6); BAR();

    constexpr int NT = KDIM / 64;  // K-tiles (even, >=4)

#pragma unroll 1
    for (int t = 0; t < NT - 2; t += 2) {
        RD_A(0, 0); RD_B(0, 0); STAGE_A(t + 1, 1, 1);                       BAR(); MFMA16(0, 0); BAR();
        RD_B(0, 1);                                                         BAR(); MFMA16(0, 1); BAR();
        RD_A(0, 1);             STAGE_B(t + 2, 0, 0);                       BAR(); MFMA16(1, 1); BAR();
                                STAGE_B(t + 2, 1, 0); STAGE_A(t + 2, 0, 0); BAR(); MFMA16(1, 0); VMC(6); BAR();
        RD_A(1, 0); RD_B(1, 0); STAGE_A(t + 2, 1, 0);                       BAR(); MFMA16(0, 0); BAR();
        RD_B(1, 1);                                                         BAR(); MFMA16(0, 1); BAR();
        RD_A(1, 1);             STAGE_B(t + 3, 0, 1);                       BAR(); MFMA16(1, 1); BAR();
                                STAGE_B(t + 3, 1, 1); STAGE_A(t + 3, 0, 1); BAR(); MFMA16(1, 0); VMC(6); BAR();
    }

    // ---- epilogue: tiles NT-2 (buf0), NT-1 (buf1) ----
    {
        RD_A(0, 0); RD_B(0, 0); STAGE_A(NT - 1, 1, 1); BAR(); MFMA16(0, 0); BAR();
        RD_B(0, 1);                                    BAR(); MFMA16(0, 1); BAR();
        RD_A(0, 1);                                    BAR(); MFMA16(1, 1); BAR();
                                                       BAR(); MFMA16(1, 0); VMC(0); BAR();
        RD_A(1, 0); RD_B(1, 0);                        BAR(); MFMA16(0, 0); BAR();
        RD_B(1, 1);                                    BAR(); MFMA16(0, 1); BAR();
        RD_A(1, 1);                                    BAR(); MFMA16(1, 1); BAR();
                                                              MFMA16(1, 0);
    }

    // ---- C write: row = wm*128+mf*16+kh*4+r, col = wn*64+nf*16+ll ----
#pragma unroll
    for (int nf = 0; nf < 4; ++nf) {
        const int col = n0 + wn * 64 + nf * 16 + ll;
        const float bv_ = bias[col];
#pragma unroll
        for (int mf = 0; mf < 8; ++mf) {
            const int row = m0 + wm * 128 + mf * 16 + kh * 4;
#pragma unroll
            for (int r = 0; r < 4; ++r)
                C[(size_t)(row + r) * N + col] = (bf16)(acc[mf][nf][r] + bv_);
        }
    }
}

// ===========================================================================
// Output projection: 128x128 tile, BK=64, 3-buffer counted-vmcnt pipeline.
//   Stage tile t+2 each iteration; VMC(8) waits exactly for tile t (8 loads/
//   thread, issued 2 iterations earlier). One barrier per K-tile. T1+T2.
// ===========================================================================
#define OP_STAGE(D, TT) do {                                                           \
    _Pragma("unroll") for (int _i = 0; _i < 4; ++_i) {                                 \
        gload_lds16(aSrc + (size_t)(_i * 32) * 1024 + (TT) * 64,                       \
                    aDst + (D) * 16384 + _i * 4096);                                   \
        gload_lds16(bSrc + (size_t)(_i * 32) * 1024 + (TT) * 64,                       \
                    bDst + (D) * 16384 + _i * 4096);                                   \
    }                                                                                  \
} while (0)

__global__ __launch_bounds__(256) void gemm_op(const bf16* __restrict__ A,
                                               const bf16* __restrict__ Bt,
                                               float* __restrict__ C,
                                               const float* __restrict__ bias,
                                               int N) {
    __shared__ bf16 smem[49152];  // 96 KiB: A[3][16KB] at 0, B[3][16KB] at 49152
    char* sc = (char*)smem;
    const int tid  = threadIdx.x;
    const int wv   = tid >> 6;
    const int lane = tid & 63;
    const int ll   = lane & 15;
    const int kh   = lane >> 4;
    const int wm   = wv >> 1;  // 0..1
    const int wn   = wv & 1;   // 0..1

    // XCD swizzle: 256 blocks -> each XCD gets exactly one n-panel (all 32 m).
    const int flat = blockIdx.y * 32 + blockIdx.x;   // gridDim = (32,8)
    const int L    = (flat & 7) * 32 + (flat >> 3);
    const int m0   = (L & 31) * 128;
    const int n0   = (L >> 5) * 128;

    const int swcol = (((tid & 7) ^ ((tid >> 3) & 7)) << 3);
    const bf16* aSrc = A + (size_t)(m0 + (tid >> 3)) * 1024 + swcol;
    const bf16* bSrc = Bt + (size_t)(n0 + (tid >> 3)) * 1024 + swcol;
    char* aDst = sc + tid * 16;
    char* bDst = sc + 49152 + tid * 16;

    const int aBase = (wm * 64 + ll) * 128;
    const int bBase = 49152 + (wn * 64 + ll) * 128;
    const int ks0 = ((kh ^ (ll & 7)) << 4);
    const int ks1 = (((4 | kh) ^ (ll & 7)) << 4);

    f32x4 acc[4][4] = {};
    bf16x8 af[4][2], bfr[4][2];

    OP_STAGE(0, 0);
    OP_STAGE(1, 1);

#pragma unroll
    for (int t = 0; t < 16; ++t) {
        const int d = t % 3;
        if (t == 15) { VMC(0); } else { VMC(8); }  // drain exactly tile t
        BAR();
        if (t < 14) OP_STAGE((t + 2) % 3, t + 2);  // targets buf (t-1)%3: reads
                                                   // done before last barrier
#pragma unroll
        for (int mf = 0; mf < 4; ++mf) {
            af[mf][0] = *(const bf16x8*)(sc + d * 16384 + aBase + mf * 2048 + ks0);
            af[mf][1] = *(const bf16x8*)(sc + d * 16384 + aBase + mf * 2048 + ks1);
        }
#pragma unroll
        for (int nf = 0; nf < 4; ++nf) {
            bfr[nf][0] = *(const bf16x8*)(sc + d * 16384 + bBase + nf * 2048 + ks0);
            bfr[nf][1] = *(const bf16x8*)(sc + d * 16384 + bBase + nf * 2048 + ks1);
        }
        __builtin_amdgcn_s_setprio(1);
#pragma unroll
        for (int mf = 0; mf < 4; ++mf)
#pragma unroll
            for (int nf = 0; nf < 4; ++nf)
#pragma unroll
                for (int k = 0; k < 2; ++k)
                    acc[mf][nf] = __builtin_amdgcn_mfma_f32_16x16x32_bf16(
                        af[mf][k], bfr[nf][k], acc[mf][nf], 0, 0, 0);
        __builtin_amdgcn_s_setprio(0);
    }

#pragma unroll
    for (int mf = 0; mf < 4; ++mf) {
#pragma unroll
        for (int nf = 0; nf < 4; ++nf) {
            int col = n0 + wn * 64 + nf * 16 + ll;
            float bv_ = bias[col];
#pragma unroll
            for (int r = 0; r < 4; ++r) {
                int row = m0 + wm * 64 + mf * 16 + kh * 4 + r;
                C[(size_t)row * N + col] = acc[mf][nf][r] + bv_;
            }
        }
    }
}

// ---------------------------------------------------------------------------
// V column sums, stage 1: partial[b*128+chunk][1024] = sum of 16 rows of V
// ---------------------------------------------------------------------------
__global__ __launch_bounds__(256) void vsum_part(const bf16* __restrict__ qkv,
                                                 float* __restrict__ part) {
    int blk = blockIdx.x;       // 0..255
    int b = blk >> 7, chunk = blk & 127;
    int cg = threadIdx.x & 127; // column group of 8
    int jp = threadIdx.x >> 7;  // 0..1
    int j0 = chunk * 16 + jp * 8;

    float acc[8] = {};
#pragma unroll
    for (int r = 0; r < 8; ++r) {
        int j = j0 + r;
        bf16x8 v = *(const bf16x8*)&qkv[(size_t)(b * S_LEN + j) * 3072 + 2048 + cg * 8];
#pragma unroll
        for (int e = 0; e < 8; ++e) acc[e] += (float)v[e];
    }

    __shared__ float red[256][8];
#pragma unroll
    for (int e = 0; e < 8; ++e) red[threadIdx.x][e] = acc[e];
    __syncthreads();
    if (jp == 0) {
        float* outp = part + ((size_t)blk << 10) + cg * 8;
#pragma unroll
        for (int e = 0; e < 8; ++e)
            outp[e] = red[threadIdx.x][e] + red[threadIdx.x + 128][e];
    }
}

// ---------------------------------------------------------------------------
// V column sums, stage 2: vsum[b*1024 + col] = sum over 128 chunks
// ---------------------------------------------------------------------------
__global__ void vsum_final(const float* __restrict__ part, float* __restrict__ vsum) {
    int idx = blockIdx.x * 256 + threadIdx.x;  // 0..2047
    int b = idx >> 10, col = idx & 1023;
    float s = 0.f;
#pragma unroll
    for (int c = 0; c < 128; ++c) s += part[(((size_t)b * 128 + c) << 10) + col];
    vsum[idx] = s;  // layout [b][h][d] == b*1024 + h*64 + d
}

// ---------------------------------------------------------------------------
// Band attention. Per block: one (b, h, 64-row i-tile).
//   w_ij = expm1(q_i . k_j / 8)  for |i-j| <= 8, 0 <= j < S
//   ctx_i = (sum_j w_ij v_j + Vsum) / (sum_j w_ij + S)
// ---------------------------------------------------------------------------
__global__ __launch_bounds__(256) void band_attn(const bf16* __restrict__ qkv,
                                                 const float* __restrict__ vsum,
                                                 bf16* __restrict__ ctx) {
    int bid = blockIdx.x;
    int it = bid & 31;
    int h  = (bid >> 5) & 15;
    int b  = bid >> 9;
    const int i0 = it * 64;

    __shared__ bf16 qs[64 * 72];
    __shared__ bf16 ks[80 * 72];
    __shared__ bf16 vs[80 * 72];
    __shared__ float wsc[64 * 19];
    __shared__ float wsum[64];

    int tid = threadIdx.x;

    // load q tile (64 rows x 128B)
    for (int idx = tid; idx < 64 * 8; idx += 256) {
        int r = idx >> 3, c = idx & 7;
        size_t g = (size_t)(b * S_LEN + i0 + r) * 3072 + h * 64 + c * 8;
        *(int4*)&qs[r * 72 + c * 8] = *(const int4*)&qkv[g];
    }
    // load k/v tiles (80 rows, j = i0-8+r), zero-fill out of range
    for (int idx = tid; idx < 80 * 8; idx += 256) {
        int r = idx >> 3, c = idx & 7;
        int j = i0 - 8 + r;
        int4 kv = {0, 0, 0, 0}, vv = {0, 0, 0, 0};
        if (j >= 0 && j < S_LEN) {
            size_t base = (size_t)(b * S_LEN + j) * 3072 + h * 64 + c * 8;
            kv = *(const int4*)&qkv[base + 1024];
            vv = *(const int4*)&qkv[base + 2048];
        }
        *(int4*)&ks[r * 72 + c * 8] = kv;
        *(int4*)&vs[r * 72 + c * 8] = vv;
    }
    __syncthreads();

    // phase 2: band weights (q-row hoisted to registers, reused over jj)
    {
        int i = tid >> 2, jg = tid & 3;
        bf16x8 qv[8];
#pragma unroll
        for (int c = 0; c < 8; ++c) qv[c] = *(const bf16x8*)&qs[i * 72 + c * 8];
        for (int jj = jg; jj < 17; jj += 4) {
            int j = i0 + i - 8 + jj;
            float w = 0.f;
            if (j >= 0 && j < S_LEN) {
                float dot = 0.f;
#pragma unroll
                for (int c = 0; c < 8; ++c) {
                    bf16x8 kv = *(const bf16x8*)&ks[(i + jj) * 72 + c * 8];
#pragma unroll
                    for (int e = 0; e < 8; ++e) dot += (float)qv[c][e] * (float)kv[e];
                }
                w = expm1f(dot * 0.125f);
            }
            wsc[i * 19 + jj] = w;
        }
    }
    __syncthreads();
    if (tid < 64) {
        float s = 0.f;
#pragma unroll
        for (int jj = 0; jj < 17; ++jj) s += wsc[tid * 19 + jj];
        wsum[tid] = s + (float)S_LEN;
    }
    __syncthreads();

    // phase 3: weighted V accumulation, 2 cols/thread (b32 LDS reads, 4B stores)
    {
        int d0 = (tid & 31) * 2, ig = tid >> 5;
        float vb0 = vsum[(b * NH + h) * HD_DIM + d0];
        float vb1 = vsum[(b * NH + h) * HD_DIM + d0 + 1];
        for (int i = ig; i < 64; i += 8) {
            float a0 = vb0, a1 = vb1;
#pragma unroll
            for (int jj = 0; jj < 17; ++jj) {
                float w = wsc[i * 19 + jj];
                bf16x2 pv = *(const bf16x2*)&vs[(i + jj) * 72 + d0];
                a0 += w * (float)pv[0];
                a1 += w * (float)pv[1];
            }
            float inv = 1.0f / wsum[i];
            bf16x2 st;
            st[0] = (bf16)(a0 * inv);
            st[1] = (bf16)(a1 * inv);
            *(bf16x2*)&ctx[(size_t)(b * S_LEN + i0 + i) * 1024 + h * 64 + d0] = st;
        }
    }
}

// ---------------------------------------------------------------------------
extern "C" void kernel_launch(void* const* d_in, const int* in_sizes, int n_in,
                              void* d_out, int out_size, void* d_ws, size_t ws_size,
                              hipStream_t stream) {
    const float* x  = (const float*)d_in[0];
    const float* Wq = (const float*)d_in[1];
    const float* Wk = (const float*)d_in[2];
    const float* Wv = (const float*)d_in[3];
    const float* Wo = (const float*)d_in[4];
    const float* bq = (const float*)d_in[5];
    const float* bk = (const float*)d_in[6];
    const float* bv = (const float*)d_in[7];
    const float* bo = (const float*)d_in[8];

    char* ws = (char*)d_ws;
    bf16*  xb    = (bf16*)(ws);                       // 8 MB   x as bf16
    bf16*  wtall = (bf16*)(ws + 8388608);             // 6 MB   [Wq^T;Wk^T;Wv^T] bf16 [3072][1024]
    bf16*  wot   = (bf16*)(ws + 14680064);            // 2 MB   Wo^T bf16 [1024][1024]
    float* ball  = (float*)(ws + 16777216);           // 12 KB  bias concat [3072]
    bf16*  qkv   = (bf16*)(ws + 16789504);            // 24 MB  [4096][3072] bf16
    bf16*  ctxb  = (bf16*)(ws + 41955328);            // 8 MB   ctx bf16 [4096][1024]
    float* vsm   = (float*)(ws + 50343936);           // 8 KB   [32][64] == [b][h][d]
    float* vpart = (float*)(ws);                      // 1 MB, aliases xb (dead after QKV GEMM)

    // fused: cvt(2048 blocks) + 4x transpose(1024) + bias(12)
    prep_all<<<3084, 256, 0, stream>>>(x, Wq, Wk, Wv, Wo, bq, bk, bv,
                                       xb, wtall, wot, ball);

    // QKV projection: [4096][1024] x [3072][1024]^T -> [4096][3072] bf16
    gemm256<1024><<<dim3(16, 12), 512, 0, stream>>>(xb, wtall, qkv, ball, 3072);

    vsum_part<<<256, 256, 0, stream>>>(qkv, vpart);
    vsum_final<<<8, 256, 0, stream>>>(vpart, vsm);
    band_attn<<<1024, 256, 0, stream>>>(qkv, vsm, ctxb);

    // output projection -> d_out fp32
    gemm_op<<<dim3(32, 8), 256, 0, stream>>>(ctxb, wot, (float*)d_out, bo, 1024);
}

// Round 7
// 89.893 us; speedup vs baseline: 1.2832x; 1.2353x over previous
//
#include <hip/hip_runtime.h>
#include <hip/hip_bf16.h>
#include <cmath>

// Problem constants (LocalAttention: B=2, S=2048, D=1024, H=16, HD=64, W=16)
#define S_LEN 2048
#define DMODEL 1024
#define NH 16
#define HD_DIM 64

typedef __bf16 bf16;
typedef __bf16 bf16x2 __attribute__((ext_vector_type(2)));
typedef __bf16 bf16x8 __attribute__((ext_vector_type(8)));
typedef float f32x4 __attribute__((ext_vector_type(4)));

// ---------------------------------------------------------------------------
// Fused preprocessing: block-range dispatch
//   [0,2048)      : x fp32 -> bf16 (8 elems/thread)
//   [2048,3072)   : W[K][N] fp32 -> Wt[N][K] bf16 transpose (4 matrices)
//   [3072,3084)   : bias concat bq|bk|bv -> ball[3072]; seed vsm = 2048*bv
// ---------------------------------------------------------------------------
__global__ __launch_bounds__(256) void prep_all(const float* __restrict__ x,
                                                const float* __restrict__ Wq,
                                                const float* __restrict__ Wk,
                                                const float* __restrict__ Wv,
                                                const float* __restrict__ Wo,
                                                const float* __restrict__ bq,
                                                const float* __restrict__ bk,
                                                const float* __restrict__ bv,
                                                bf16* __restrict__ xb,
                                                bf16* __restrict__ wtall,
                                                bf16* __restrict__ wot,
                                                float* __restrict__ ball,
                                                float* __restrict__ vsm) {
    __shared__ float tile[64][65];
    const int bid = blockIdx.x;
    const int tid = threadIdx.x;
    if (bid < 2048) {
        int i = (bid * 256 + tid) * 8;
        float4 v0 = *(const float4*)(x + i);
        float4 v1 = *(const float4*)(x + i + 4);
        bf16x8 o;
        o[0] = (bf16)v0.x; o[1] = (bf16)v0.y; o[2] = (bf16)v0.z; o[3] = (bf16)v0.w;
        o[4] = (bf16)v1.x; o[5] = (bf16)v1.y; o[6] = (bf16)v1.z; o[7] = (bf16)v1.w;
        *(bf16x8*)(xb + i) = o;
    } else if (bid < 3072) {
        int t = bid - 2048;
        int z = t >> 8;
        t &= 255;
        const float* W = (z == 0) ? Wq : (z == 1) ? Wk : (z == 2) ? Wv : Wo;
        bf16* Wt = (z == 3) ? wot : wtall + (size_t)z * 1048576;
        int n0 = (t & 15) * 64, k0 = (t >> 4) * 64;
        int tr = tid >> 6, tc = tid & 63;
#pragma unroll
        for (int i = 0; i < 16; ++i) {
            int r = tr + i * 4;
            tile[r][tc] = W[(size_t)(k0 + r) * DMODEL + n0 + tc];
        }
        __syncthreads();
#pragma unroll
        for (int i = 0; i < 16; ++i) {
            int r = tr + i * 4;  // local n index
            Wt[(size_t)(n0 + r) * DMODEL + k0 + tc] = (bf16)tile[tc][r];
        }
    } else {
        int i = (bid - 3072) * 256 + tid;  // 0..3071
        float v = (i < 1024) ? bq[i] : (i < 2048) ? bk[i - 1024] : bv[i - 2048];
        ball[i] = v;
        if (i >= 2048) {
            // seed V column-sum accumulators with the bias term (and clear poison)
            int c = i - 2048;
            vsm[c]        = 2048.0f * v;
            vsm[1024 + c] = 2048.0f * v;
        }
    }
}

// ---------------------------------------------------------------------------
// async global->LDS, 16B per lane (dest = wave-uniform base + lane*16)
// ---------------------------------------------------------------------------
__device__ __forceinline__ void gload_lds16(const void* g, void* l) {
    __builtin_amdgcn_global_load_lds((const __attribute__((address_space(1))) void*)g,
                                     (__attribute__((address_space(3))) void*)l, 16, 0, 0);
}

// ===========================================================================
// 256x256 8-phase GEMM (T1 XCD swizzle + T2 swizzle + T3/T4 vmcnt(6) + T5)
//   C[M][N](bf16) = A[M][K](bf16) * Bt[N][K](bf16)^T + bias[N]
//   512 threads = 8 waves (2 M x 4 N), per-wave 128x64 output.
//   3 half-tiles in flight at every VMC(6) (m201 steady state).
//   Epilogue additionally folds V column-sums (n0>=2048) into vsm via
//   shfl-reduce + atomicAdd (replaces the standalone vsum kernels).
// ===========================================================================
#define BAR() asm volatile("s_barrier" ::: "memory")
#define VMC(N) asm volatile("s_waitcnt vmcnt(" #N ")" ::: "memory")

#define STAGE_A(T, H, DB) do {                                                         \
    gload_lds16(aSrc + (size_t)((H) * 128) * KDIM + (T) * 64,                          \
                aDst + (DB) * 32768 + (H) * 16384);                                    \
    gload_lds16(aSrc + (size_t)((H) * 128 + 64) * KDIM + (T) * 64,                     \
                aDst + (DB) * 32768 + (H) * 16384 + 8192);                             \
} while (0)
#define STAGE_B(T, H, DB) do {                                                         \
    gload_lds16(bSrc + (size_t)((H) * 128) * KDIM + (T) * 64,                          \
                bDst + (DB) * 32768 + (H) * 16384);                                    \
    gload_lds16(bSrc + (size_t)((H) * 128 + 64) * KDIM + (T) * 64,                     \
                bDst + (DB) * 32768 + (H) * 16384 + 8192);                             \
} while (0)
#define RD_A(D, MH) do {                                                               \
    _Pragma("unroll") for (int _m = 0; _m < 4; ++_m) {                                 \
        a[_m][0] = *(const bf16x8*)(sc + (D) * 32768 + aBase + ((MH) * 4 + _m) * 2048 + ks0); \
        a[_m][1] = *(const bf16x8*)(sc + (D) * 32768 + aBase + ((MH) * 4 + _m) * 2048 + ks1); \
    }                                                                                  \
} while (0)
#define RD_B(D, NB) do {                                                               \
    _Pragma("unroll") for (int _n = 0; _n < 2; ++_n) {                                 \
        b[(NB) * 2 + _n][0] = *(const bf16x8*)(sc + (D) * 32768 + bBase + ((NB) * 2 + _n) * 2048 + ks0); \
        b[(NB) * 2 + _n][1] = *(const bf16x8*)(sc + (D) * 32768 + bBase + ((NB) * 2 + _n) * 2048 + ks1); \
    }                                                                                  \
} while (0)
#define MFMA16(MH, NB) do {                                                            \
    __builtin_amdgcn_s_setprio(1);                                                     \
    _Pragma("unroll") for (int _m = 0; _m < 4; ++_m)                                   \
    _Pragma("unroll") for (int _n = 0; _n < 2; ++_n)                                   \
    _Pragma("unroll") for (int _k = 0; _k < 2; ++_k)                                   \
        acc[(MH) * 4 + _m][(NB) * 2 + _n] = __builtin_amdgcn_mfma_f32_16x16x32_bf16(   \
            a[_m][_k], b[(NB) * 2 + _n][_k], acc[(MH) * 4 + _m][(NB) * 2 + _n], 0, 0, 0); \
    __builtin_amdgcn_s_setprio(0);                                                     \
} while (0)

template <int KDIM>
__global__ __launch_bounds__(512, 2) void gemm256(const bf16* __restrict__ A,
                                                  const bf16* __restrict__ Bt,
                                                  bf16* __restrict__ C,
                                                  const float* __restrict__ bias,
                                                  float* __restrict__ vsm,
                                                  int N) {
    __shared__ bf16 smem[65536];  // 128 KiB: A[0:64K), B[64K:128K)
    char* sc = (char*)smem;

    const int tid  = threadIdx.x;
    const int wv   = tid >> 6;
    const int lane = tid & 63;
    const int ll   = lane & 15;
    const int kh   = lane >> 4;
    const int wm   = wv >> 2;  // 0..1
    const int wn   = wv & 3;   // 0..3

    // XCD-aware swizzle: 192 blocks, 8 XCDs, 24 consecutive tiles per XCD
    // (m-fastest within XCD -> B-panel reuse stays XCD-local).
    const int flat = blockIdx.y * 16 + blockIdx.x;       // gridDim = (16,12)
    const int L    = (flat & 7) * 24 + (flat >> 3);      // bijective, 192%8==0
    const int m0   = (L & 15) * 256;
    const int n0   = (L >> 4) * 256;

    // Staging: per-thread inverse-swizzled global source, linear LDS dest.
    const int swcol = (((tid & 7) ^ ((tid >> 3) & 7)) << 3);  // element offset
    const bf16* aSrc = A + (size_t)(m0 + (tid >> 3)) * KDIM + swcol;
    const bf16* bSrc = Bt + (size_t)(n0 + (tid >> 3)) * KDIM + swcol;
    char* aDst = sc + wv * 1024;
    char* bDst = sc + 65536 + wv * 1024;

    // Read side: swizzle XOR = ((row&7)<<4), row&7 == ll&7 for all fragments.
    const int aBase = wm * 16384 + ll * 128;
    const int bBase = 65536 + (wn >> 1) * 16384 + ((wn & 1) * 64 + ll) * 128;
    const int ks0 = ((kh ^ (ll & 7)) << 4);        // k-slice 0 col-block byte
    const int ks1 = (((4 | kh) ^ (ll & 7)) << 4);  // k-slice 1

    f32x4 acc[8][4] = {};
    bf16x8 a[4][2], b[4][2];

    // ---- prologue: tile0 fully + tile1 {B.h0, B.h1, A.h0}; VMC(6) keeps 3
    //      half-tiles in flight entering steady state ----
    STAGE_B(0, 0, 0); STAGE_B(0, 1, 0); STAGE_A(0, 0, 0); STAGE_A(0, 1, 0);
    STAGE_B(1, 0, 1); STAGE_B(1, 1, 1); STAGE_A(1, 0, 1);
    VMC(6); BAR();

    constexpr int NT = KDIM / 64;  // K-tiles (even, >=4)

#pragma unroll 1
    for (int t = 0; t < NT - 2; t += 2) {
        RD_A(0, 0); RD_B(0, 0); STAGE_A(t + 1, 1, 1);                       BAR(); MFMA16(0, 0); BAR();
        RD_B(0, 1);                                                         BAR(); MFMA16(0, 1); BAR();
        RD_A(0, 1);             STAGE_B(t + 2, 0, 0);                       BAR(); MFMA16(1, 1); BAR();
                                STAGE_B(t + 2, 1, 0); STAGE_A(t + 2, 0, 0); BAR(); MFMA16(1, 0); VMC(6); BAR();
        RD_A(1, 0); RD_B(1, 0); STAGE_A(t + 2, 1, 0);                       BAR(); MFMA16(0, 0); BAR();
        RD_B(1, 1);                                                         BAR(); MFMA16(0, 1); BAR();
        RD_A(1, 1);             STAGE_B(t + 3, 0, 1);                       BAR(); MFMA16(1, 1); BAR();
                                STAGE_B(t + 3, 1, 1); STAGE_A(t + 3, 0, 1); BAR(); MFMA16(1, 0); VMC(6); BAR();
    }

    // ---- epilogue: tiles NT-2 (buf0), NT-1 (buf1) ----
    {
        RD_A(0, 0); RD_B(0, 0); STAGE_A(NT - 1, 1, 1); BAR(); MFMA16(0, 0); BAR();
        RD_B(0, 1);                                    BAR(); MFMA16(0, 1); BAR();
        RD_A(0, 1);                                    BAR(); MFMA16(1, 1); BAR();
                                                       BAR(); MFMA16(1, 0); VMC(0); BAR();
        RD_A(1, 0); RD_B(1, 0);                        BAR(); MFMA16(0, 0); BAR();
        RD_B(1, 1);                                    BAR(); MFMA16(0, 1); BAR();
        RD_A(1, 1);                                    BAR(); MFMA16(1, 1); BAR();
                                                              MFMA16(1, 0);
    }

    // ---- C write: row = wm*128+mf*16+kh*4+r, col = wn*64+nf*16+ll ----
#pragma unroll
    for (int nf = 0; nf < 4; ++nf) {
        const int col = n0 + wn * 64 + nf * 16 + ll;
        const float bv_ = bias[col];
#pragma unroll
        for (int mf = 0; mf < 8; ++mf) {
            const int row = m0 + wm * 128 + mf * 16 + kh * 4;
#pragma unroll
            for (int r = 0; r < 4; ++r)
                C[(size_t)(row + r) * N + col] = (bf16)(acc[mf][nf][r] + bv_);
        }
    }

    // ---- fused V column-sums: this block's 256-row partial per column ----
    if (n0 >= 2048) {
        const int bidx = m0 >> 11;  // batch (m0 multiple of 256, 2048 rows/batch)
        float* vdst = vsm + bidx * 1024 + (n0 - 2048) + wn * 64;
#pragma unroll
        for (int nf = 0; nf < 4; ++nf) {
            float p = 0.f;
#pragma unroll
            for (int mf = 0; mf < 8; ++mf)
#pragma unroll
                for (int r = 0; r < 4; ++r) p += acc[mf][nf][r];
            // reduce the 4 kh-lanes holding the same column (lane ^16, ^32)
            p += __shfl_xor(p, 16);
            p += __shfl_xor(p, 32);
            if (kh == 0) atomicAdd(vdst + nf * 16 + ll, p);
        }
    }
}

// ---------------------------------------------------------------------------
// Output projection: m97-style 128x128 tile, BK=32, 4 waves, 16 KB LDS ->
// ~6 blocks/CU; high TLP hides the per-tile vmcnt(0) drain (R3-proven).
// C fp32 = A(bf16) * Bt(bf16)^T + bias. + T1 XCD swizzle.
// ---------------------------------------------------------------------------
__global__ __launch_bounds__(256) void gemm_bt(const bf16* __restrict__ A,
                                               const bf16* __restrict__ Bt,
                                               float* __restrict__ C,
                                               const float* __restrict__ bias,
                                               int N, int K) {
    __shared__ bf16 As[128 * 32];
    __shared__ bf16 Bs[128 * 32];
    const int tid  = threadIdx.x;
    const int wave = tid >> 6;
    const int lane = tid & 63;

    // XCD swizzle: 256 blocks -> each XCD owns one n-panel (all 32 m-tiles).
    const int flat = blockIdx.y * 32 + blockIdx.x;   // gridDim = (32,8)
    const int L    = (flat & 7) * 32 + (flat >> 3);
    const int m0   = (L & 31) * 128;
    const int n0   = (L >> 5) * 128;

    const int wm = (wave >> 1) * 64;   // wave's 64x64 quadrant
    const int wn = (wave & 1) * 64;
    const int lrow = lane & 15;
    const int kh   = lane >> 4;        // 0..3
    const int srow = lane >> 2;        // staging: 16 rows per wave chunk
    const int scol = (lane & 3) * 16;  // byte offset within 64B k-row

    f32x4 acc[4][4] = {};

    for (int k0 = 0; k0 < K; k0 += 32) {
#pragma unroll
        for (int half = 0; half < 2; ++half) {
            int rbase = half * 64 + wave * 16;
            const char* ga = (const char*)(A + (size_t)(m0 + rbase + srow) * K + k0) + scol;
            gload_lds16(ga, (char*)As + rbase * 64);
            const char* gb = (const char*)(Bt + (size_t)(n0 + rbase + srow) * K + k0) + scol;
            gload_lds16(gb, (char*)Bs + rbase * 64);
        }
        __syncthreads();
        bf16x8 af[4], bfr[4];
#pragma unroll
        for (int mf = 0; mf < 4; ++mf)
            af[mf] = *(const bf16x8*)&As[(wm + mf * 16 + lrow) * 32 + kh * 8];
#pragma unroll
        for (int nf = 0; nf < 4; ++nf)
            bfr[nf] = *(const bf16x8*)&Bs[(wn + nf * 16 + lrow) * 32 + kh * 8];
#pragma unroll
        for (int mf = 0; mf < 4; ++mf)
#pragma unroll
            for (int nf = 0; nf < 4; ++nf)
                acc[mf][nf] = __builtin_amdgcn_mfma_f32_16x16x32_bf16(af[mf], bfr[nf], acc[mf][nf], 0, 0, 0);
        __syncthreads();
    }

#pragma unroll
    for (int mf = 0; mf < 4; ++mf) {
#pragma unroll
        for (int nf = 0; nf < 4; ++nf) {
            int col = n0 + wn + nf * 16 + lrow;
            float bv_ = bias[col];
#pragma unroll
            for (int r = 0; r < 4; ++r) {
                int row = m0 + wm + mf * 16 + kh * 4 + r;
                C[(size_t)row * N + col] = acc[mf][nf][r] + bv_;
            }
        }
    }
}

// ---------------------------------------------------------------------------
// Band attention. Per block: one (b, h, 64-row i-tile).
//   w_ij = expm1(q_i . k_j / 8)  for |i-j| <= 8, 0 <= j < S
//   ctx_i = (sum_j w_ij v_j + Vsum) / (sum_j w_ij + S)
// ---------------------------------------------------------------------------
__global__ __launch_bounds__(256) void band_attn(const bf16* __restrict__ qkv,
                                                 const float* __restrict__ vsum,
                                                 bf16* __restrict__ ctx) {
    int bid = blockIdx.x;
    int it = bid & 31;
    int h  = (bid >> 5) & 15;
    int b  = bid >> 9;
    const int i0 = it * 64;

    __shared__ bf16 qs[64 * 72];
    __shared__ bf16 ks[80 * 72];
    __shared__ bf16 vs[80 * 72];
    __shared__ float wsc[64 * 19];
    __shared__ float wsum[64];

    int tid = threadIdx.x;

    // load q tile (64 rows x 128B)
    for (int idx = tid; idx < 64 * 8; idx += 256) {
        int r = idx >> 3, c = idx & 7;
        size_t g = (size_t)(b * S_LEN + i0 + r) * 3072 + h * 64 + c * 8;
        *(int4*)&qs[r * 72 + c * 8] = *(const int4*)&qkv[g];
    }
    // load k/v tiles (80 rows, j = i0-8+r), zero-fill out of range
    for (int idx = tid; idx < 80 * 8; idx += 256) {
        int r = idx >> 3, c = idx & 7;
        int j = i0 - 8 + r;
        int4 kv = {0, 0, 0, 0}, vv = {0, 0, 0, 0};
        if (j >= 0 && j < S_LEN) {
            size_t base = (size_t)(b * S_LEN + j) * 3072 + h * 64 + c * 8;
            kv = *(const int4*)&qkv[base + 1024];
            vv = *(const int4*)&qkv[base + 2048];
        }
        *(int4*)&ks[r * 72 + c * 8] = kv;
        *(int4*)&vs[r * 72 + c * 8] = vv;
    }
    __syncthreads();

    // phase 2: band weights (q-row hoisted to registers, reused over jj)
    {
        int i = tid >> 2, jg = tid & 3;
        bf16x8 qv[8];
#pragma unroll
        for (int c = 0; c < 8; ++c) qv[c] = *(const bf16x8*)&qs[i * 72 + c * 8];
        for (int jj = jg; jj < 17; jj += 4) {
            int j = i0 + i - 8 + jj;
            float w = 0.f;
            if (j >= 0 && j < S_LEN) {
                float dot = 0.f;
#pragma unroll
                for (int c = 0; c < 8; ++c) {
                    bf16x8 kv = *(const bf16x8*)&ks[(i + jj) * 72 + c * 8];
#pragma unroll
                    for (int e = 0; e < 8; ++e) dot += (float)qv[c][e] * (float)kv[e];
                }
                w = expm1f(dot * 0.125f);
            }
            wsc[i * 19 + jj] = w;
        }
    }
    __syncthreads();
    if (tid < 64) {
        float s = 0.f;
#pragma unroll
        for (int jj = 0; jj < 17; ++jj) s += wsc[tid * 19 + jj];
        wsum[tid] = s + (float)S_LEN;
    }
    __syncthreads();

    // phase 3: weighted V accumulation, 2 cols/thread (b32 LDS reads, 4B stores)
    {
        int d0 = (tid & 31) * 2, ig = tid >> 5;
        float vb0 = vsum[(b * NH + h) * HD_DIM + d0];
        float vb1 = vsum[(b * NH + h) * HD_DIM + d0 + 1];
        for (int i = ig; i < 64; i += 8) {
            float a0 = vb0, a1 = vb1;
#pragma unroll
            for (int jj = 0; jj < 17; ++jj) {
                float w = wsc[i * 19 + jj];
                bf16x2 pv = *(const bf16x2*)&vs[(i + jj) * 72 + d0];
                a0 += w * (float)pv[0];
                a1 += w * (float)pv[1];
            }
            float inv = 1.0f / wsum[i];
            bf16x2 st;
            st[0] = (bf16)(a0 * inv);
            st[1] = (bf16)(a1 * inv);
            *(bf16x2*)&ctx[(size_t)(b * S_LEN + i0 + i) * 1024 + h * 64 + d0] = st;
        }
    }
}

// ---------------------------------------------------------------------------
extern "C" void kernel_launch(void* const* d_in, const int* in_sizes, int n_in,
                              void* d_out, int out_size, void* d_ws, size_t ws_size,
                              hipStream_t stream) {
    const float* x  = (const float*)d_in[0];
    const float* Wq = (const float*)d_in[1];
    const float* Wk = (const float*)d_in[2];
    const float* Wv = (const float*)d_in[3];
    const float* Wo = (const float*)d_in[4];
    const float* bq = (const float*)d_in[5];
    const float* bk = (const float*)d_in[6];
    const float* bv = (const float*)d_in[7];
    const float* bo = (const float*)d_in[8];

    char* ws = (char*)d_ws;
    bf16*  xb    = (bf16*)(ws);                       // 8 MB   x as bf16
    bf16*  wtall = (bf16*)(ws + 8388608);             // 6 MB   [Wq^T;Wk^T;Wv^T] bf16 [3072][1024]
    bf16*  wot   = (bf16*)(ws + 14680064);            // 2 MB   Wo^T bf16 [1024][1024]
    float* ball  = (float*)(ws + 16777216);           // 12 KB  bias concat [3072]
    bf16*  qkv   = (bf16*)(ws + 16789504);            // 24 MB  [4096][3072] bf16
    bf16*  ctxb  = (bf16*)(ws + 41955328);            // 8 MB   ctx bf16 [4096][1024]
    float* vsm   = (float*)(ws + 50343936);           // 8 KB   [2][1024] == [b][h*64+d]

    // fused: cvt(2048 blocks) + 4x transpose(1024) + bias+vsm-seed(12)
    prep_all<<<3084, 256, 0, stream>>>(x, Wq, Wk, Wv, Wo, bq, bk, bv,
                                       xb, wtall, wot, ball, vsm);

    // QKV projection (+fused V column sums): [4096][1024] x [3072][1024]^T
    gemm256<1024><<<dim3(16, 12), 512, 0, stream>>>(xb, wtall, qkv, ball, vsm, 3072);

    band_attn<<<1024, 256, 0, stream>>>(qkv, vsm, ctxb);

    // output projection -> d_out fp32
    gemm_bt<<<dim3(32, 8), 256, 0, stream>>>(ctxb, wot, (float*)d_out, bo, 1024, 1024);
}

// Round 8
// 85.329 us; speedup vs baseline: 1.3519x; 1.0535x over previous
//
#include <hip/hip_runtime.h>
#include <hip/hip_bf16.h>
#include <cmath>

// Problem constants (LocalAttention: B=2, S=2048, D=1024, H=16, HD=64, W=16)
#define S_LEN 2048
#define DMODEL 1024
#define NH 16
#define HD_DIM 64

typedef __bf16 bf16;
typedef __bf16 bf16x2 __attribute__((ext_vector_type(2)));
typedef __bf16 bf16x8 __attribute__((ext_vector_type(8)));
typedef float f32x4 __attribute__((ext_vector_type(4)));

// ---------------------------------------------------------------------------
// Fused preprocessing: block-range dispatch
//   [0,2048)      : x fp32 -> bf16 (8 elems/thread)
//   [2048,3072)   : W[K][N] fp32 -> Wt[N][K] bf16 transpose (4 matrices)
//   [3072,3084)   : bias concat bq|bk|bv -> ball[3072]; seed vsm = 2048*bv
// ---------------------------------------------------------------------------
__global__ __launch_bounds__(256) void prep_all(const float* __restrict__ x,
                                                const float* __restrict__ Wq,
                                                const float* __restrict__ Wk,
                                                const float* __restrict__ Wv,
                                                const float* __restrict__ Wo,
                                                const float* __restrict__ bq,
                                                const float* __restrict__ bk,
                                                const float* __restrict__ bv,
                                                bf16* __restrict__ xb,
                                                bf16* __restrict__ wtall,
                                                bf16* __restrict__ wot,
                                                float* __restrict__ ball,
                                                float* __restrict__ vsm) {
    __shared__ float tile[64][65];
    const int bid = blockIdx.x;
    const int tid = threadIdx.x;
    if (bid < 2048) {
        int i = (bid * 256 + tid) * 8;
        float4 v0 = *(const float4*)(x + i);
        float4 v1 = *(const float4*)(x + i + 4);
        bf16x8 o;
        o[0] = (bf16)v0.x; o[1] = (bf16)v0.y; o[2] = (bf16)v0.z; o[3] = (bf16)v0.w;
        o[4] = (bf16)v1.x; o[5] = (bf16)v1.y; o[6] = (bf16)v1.z; o[7] = (bf16)v1.w;
        *(bf16x8*)(xb + i) = o;
    } else if (bid < 3072) {
        int t = bid - 2048;
        int z = t >> 8;
        t &= 255;
        const float* W = (z == 0) ? Wq : (z == 1) ? Wk : (z == 2) ? Wv : Wo;
        bf16* Wt = (z == 3) ? wot : wtall + (size_t)z * 1048576;
        int n0 = (t & 15) * 64, k0 = (t >> 4) * 64;
        int tr = tid >> 6, tc = tid & 63;
#pragma unroll
        for (int i = 0; i < 16; ++i) {
            int r = tr + i * 4;
            tile[r][tc] = W[(size_t)(k0 + r) * DMODEL + n0 + tc];
        }
        __syncthreads();
#pragma unroll
        for (int i = 0; i < 16; ++i) {
            int r = tr + i * 4;  // local n index
            Wt[(size_t)(n0 + r) * DMODEL + k0 + tc] = (bf16)tile[tc][r];
        }
    } else {
        int i = (bid - 3072) * 256 + tid;  // 0..3071
        float v = (i < 1024) ? bq[i] : (i < 2048) ? bk[i - 1024] : bv[i - 2048];
        ball[i] = v;
        if (i >= 2048) {
            // seed V column-sum accumulators with the bias term (and clear poison)
            int c = i - 2048;
            vsm[c]        = 2048.0f * v;
            vsm[1024 + c] = 2048.0f * v;
        }
    }
}

// ---------------------------------------------------------------------------
// async global->LDS, 16B per lane (dest = wave-uniform base + lane*16)
// ---------------------------------------------------------------------------
__device__ __forceinline__ void gload_lds16(const void* g, void* l) {
    __builtin_amdgcn_global_load_lds((const __attribute__((address_space(1))) void*)g,
                                     (__attribute__((address_space(3))) void*)l, 16, 0, 0);
}

#define BAR() asm volatile("s_barrier" ::: "memory")
#define VMC(N) asm volatile("s_waitcnt vmcnt(" #N ")" ::: "memory")

// ===========================================================================
// QKV GEMM: 256x192 tile, grid (16,16) = 256 blocks (FULL chip), 512 threads
// = 8 waves (2M x 4N), per-wave 128x48 output (acc 8mf x 3nf).
// LDS 112 KiB: A dbuf 2x32KB [0,64K), B dbuf 2x24KB [64K,112K).
// Register-rotated 8-window schedule: each window reads NEXT window's
// fragments (alternate reg set) while MFMA consumes fragments read one
// window earlier -> ds_read overlaps MFMA, no same-window lgkm stalls.
// Staging pieces 8KB (A:4/tile, B:3/tile), counted VMC(2) at w3/w7.
// Epilogue folds V column-sums (col>=2048) into vsm (shfl + atomicAdd).
// ===========================================================================
#define QST_A(T, I) gload_lds16(aSrc + (size_t)((I) * 64) * KDIM + (T) * 64,           \
                                aDstW + ((T) & 1) * 32768 + (I) * 8192)
#define QST_B(T, J) gload_lds16(bSrc + (size_t)((J) * 64) * KDIM + (T) * 64,           \
                                bDstW + ((T) & 1) * 24576 + (J) * 8192)
#define QRD_A(DST, D, MH) do {                                                         \
    _Pragma("unroll") for (int _m = 0; _m < 4; ++_m) {                                 \
        DST[_m][0] = *(const bf16x8*)(sc + (D) * 32768 + aBase + ((MH) * 4 + _m) * 2048 + ks0); \
        DST[_m][1] = *(const bf16x8*)(sc + (D) * 32768 + aBase + ((MH) * 4 + _m) * 2048 + ks1); \
    }                                                                                  \
} while (0)
#define QRD_B01(DST, D) do {                                                           \
    _Pragma("unroll") for (int _n = 0; _n < 2; ++_n) {                                 \
        DST[_n][0] = *(const bf16x8*)(sc + (D) * 24576 + bBase + _n * 2048 + ks0);     \
        DST[_n][1] = *(const bf16x8*)(sc + (D) * 24576 + bBase + _n * 2048 + ks1);     \
    }                                                                                  \
} while (0)
#define QRD_B2(D) do {                                                                 \
    b2[0] = *(const bf16x8*)(sc + (D) * 24576 + bBase + 2 * 2048 + ks0);               \
    b2[1] = *(const bf16x8*)(sc + (D) * 24576 + bBase + 2 * 2048 + ks1);               \
} while (0)
#define QMF16(AS, BS, MH) do {                                                         \
    __builtin_amdgcn_s_setprio(1);                                                     \
    _Pragma("unroll") for (int _m = 0; _m < 4; ++_m)                                   \
    _Pragma("unroll") for (int _n = 0; _n < 2; ++_n)                                   \
    _Pragma("unroll") for (int _k = 0; _k < 2; ++_k)                                   \
        acc[(MH) * 4 + _m][_n] = __builtin_amdgcn_mfma_f32_16x16x32_bf16(              \
            AS[_m][_k], BS[_n][_k], acc[(MH) * 4 + _m][_n], 0, 0, 0);                  \
    __builtin_amdgcn_s_setprio(0);                                                     \
} while (0)
#define QMF8(AS, MH) do {                                                              \
    __builtin_amdgcn_s_setprio(1);                                                     \
    _Pragma("unroll") for (int _m = 0; _m < 4; ++_m)                                   \
    _Pragma("unroll") for (int _k = 0; _k < 2; ++_k)                                   \
        acc[(MH) * 4 + _m][2] = __builtin_amdgcn_mfma_f32_16x16x32_bf16(               \
            AS[_m][_k], b2[_k], acc[(MH) * 4 + _m][2], 0, 0, 0);                       \
    __builtin_amdgcn_s_setprio(0);                                                     \
} while (0)

template <int KDIM>
__global__ __launch_bounds__(512, 2) void gemm_qkv(const bf16* __restrict__ A,
                                                   const bf16* __restrict__ Bt,
                                                   bf16* __restrict__ C,
                                                   const float* __restrict__ bias,
                                                   float* __restrict__ vsm,
                                                   int N) {
    __shared__ bf16 smem[57344];  // 112 KiB
    char* sc = (char*)smem;

    const int tid  = threadIdx.x;
    const int wv   = tid >> 6;
    const int lane = tid & 63;
    const int ll   = lane & 15;
    const int kh   = lane >> 4;
    const int wm   = wv >> 2;  // 0..1
    const int wn   = wv & 3;   // 0..3

    // XCD swizzle: 256 blocks, 32/XCD (all 16 m-tiles x 2 n-panels per XCD)
    const int flat = blockIdx.y * 16 + blockIdx.x;   // gridDim = (16,16)
    const int L    = (flat & 7) * 32 + (flat >> 3);
    const int m0   = (L & 15) * 256;
    const int n0   = (L >> 4) * 192;

    // Staging: inverse-swizzled global source, linear LDS dest (8KB pieces).
    const int swcol = (((tid & 7) ^ ((tid >> 3) & 7)) << 3);
    const bf16* aSrc = A + (size_t)(m0 + (tid >> 3)) * KDIM + swcol;
    const bf16* bSrc = Bt + (size_t)(n0 + (tid >> 3)) * KDIM + swcol;
    char* aDstW = sc + wv * 1024;
    char* bDstW = sc + 65536 + wv * 1024;

    // Read side: XOR-swizzle ((row&7)<<4); row&7 == ll&7 for all fragments.
    const int aBase = wm * 16384 + ll * 128;
    const int bBase = 65536 + (wn * 48 + ll) * 128;
    const int ks0 = ((kh ^ (ll & 7)) << 4);
    const int ks1 = (((4 | kh) ^ (ll & 7)) << 4);

    f32x4 acc[8][3] = {};
    bf16x8 aX[4][2], aY[4][2], bP[2][2], bQ[2][2], b2[2];

    constexpr int NT = KDIM / 64;  // 16 K-tiles

    // ---- prologue: tile0 fully + tile1 {B0,B1}; drain tile0; pre-read w1 ----
    QST_B(0, 0); QST_B(0, 1); QST_B(0, 2);
    QST_A(0, 0); QST_A(0, 1); QST_A(0, 2); QST_A(0, 3);
    QST_B(1, 0); QST_B(1, 1);
    VMC(2); BAR();
    QRD_A(aX, 0, 0); QRD_B01(bP, 0);
    QST_B(1, 2); QST_A(1, 0);
    BAR();

    // ---- main loop: tiles t(buf0), t+1(buf1); stage t+1 tail, t+2, t+3 ----
#pragma unroll 1
    for (int i = 0; i < NT / 2 - 1; ++i) {
        const int t = 2 * i;
        /*w1*/ QRD_B2(0);                   QMF16(aX, bP, 0); QST_A(t + 1, 1); QST_A(t + 1, 2); BAR();
        /*w2*/ QRD_A(aY, 0, 1);             QMF8(aX, 0);      QST_A(t + 1, 3);                  BAR();
        /*w3*/                              QMF8(aY, 1);      QST_B(t + 2, 0); QST_B(t + 2, 1); VMC(2); BAR();
        /*w4*/ QRD_A(aX, 1, 0); QRD_B01(bQ, 1); QMF16(aY, bP, 1); QST_B(t + 2, 2); QST_A(t + 2, 0); BAR();
        /*w5*/ QRD_B2(1);                   QMF16(aX, bQ, 0); QST_A(t + 2, 1); QST_A(t + 2, 2); BAR();
        /*w6*/ QRD_A(aY, 1, 1);             QMF8(aX, 0);      QST_A(t + 2, 3);                  BAR();
        /*w7*/                              QMF8(aY, 1);      QST_B(t + 3, 0); QST_B(t + 3, 1); VMC(2); BAR();
        /*w8*/ QRD_A(aX, 0, 0); QRD_B01(bP, 0); QMF16(aY, bQ, 1); QST_B(t + 3, 2); QST_A(t + 3, 0); BAR();
    }

    // ---- epilogue: tiles NT-2 (buf0), NT-1 (buf1); finish NT-1 staging ----
    {
        const int t = NT - 2;
        /*w1*/ QRD_B2(0);                       QMF16(aX, bP, 0); QST_A(t + 1, 1); QST_A(t + 1, 2); BAR();
        /*w2*/ QRD_A(aY, 0, 1);                 QMF8(aX, 0);      QST_A(t + 1, 3);                  BAR();
        /*w3*/                                  QMF8(aY, 1);      VMC(0); BAR();
        /*w4*/ QRD_A(aX, 1, 0); QRD_B01(bQ, 1); QMF16(aY, bP, 1); BAR();
        /*w5*/ QRD_B2(1);                       QMF16(aX, bQ, 0); BAR();
        /*w6*/ QRD_A(aY, 1, 1);                 QMF8(aX, 0);      BAR();
        /*w7+w8*/                               QMF8(aY, 1);      QMF16(aY, bQ, 1);
    }

    // ---- C write: row = m0+wm*128+mf*16+kh*4+r, col = n0+wn*48+nf*16+ll ----
#pragma unroll
    for (int nf = 0; nf < 3; ++nf) {
        const int col = n0 + wn * 48 + nf * 16 + ll;
        const float bv_ = bias[col];
#pragma unroll
        for (int mf = 0; mf < 8; ++mf) {
            const int row = m0 + wm * 128 + mf * 16 + kh * 4;
#pragma unroll
            for (int r = 0; r < 4; ++r)
                C[(size_t)(row + r) * N + col] = (bf16)(acc[mf][nf][r] + bv_);
        }
    }

    // ---- fused V column-sums (V cols = 2048..3071) ----
    {
        const int bidx = m0 >> 11;
#pragma unroll
        for (int nf = 0; nf < 3; ++nf) {
            if (n0 + wn * 48 + nf * 16 >= 2048) {  // wave-uniform predicate
                float p = 0.f;
#pragma unroll
                for (int mf = 0; mf < 8; ++mf)
#pragma unroll
                    for (int r = 0; r < 4; ++r) p += acc[mf][nf][r];
                p += __shfl_xor(p, 16);
                p += __shfl_xor(p, 32);
                if (kh == 0)
                    atomicAdd(vsm + bidx * 1024 + (n0 + wn * 48 + nf * 16 + ll - 2048), p);
            }
        }
    }
}

// ---------------------------------------------------------------------------
// Output projection: m97-style 128x128 tile, BK=32, 4 waves, 16 KB LDS ->
// high TLP hides the per-tile drain (R3/R7-proven). fp32 out + T1 swizzle.
// ---------------------------------------------------------------------------
__global__ __launch_bounds__(256) void gemm_bt(const bf16* __restrict__ A,
                                               const bf16* __restrict__ Bt,
                                               float* __restrict__ C,
                                               const float* __restrict__ bias,
                                               int N, int K) {
    __shared__ bf16 As[128 * 32];
    __shared__ bf16 Bs[128 * 32];
    const int tid  = threadIdx.x;
    const int wave = tid >> 6;
    const int lane = tid & 63;

    const int flat = blockIdx.y * 32 + blockIdx.x;   // gridDim = (32,8)
    const int L    = (flat & 7) * 32 + (flat >> 3);
    const int m0   = (L & 31) * 128;
    const int n0   = (L >> 5) * 128;

    const int wm = (wave >> 1) * 64;
    const int wn = (wave & 1) * 64;
    const int lrow = lane & 15;
    const int kh   = lane >> 4;
    const int srow = lane >> 2;
    const int scol = (lane & 3) * 16;

    f32x4 acc[4][4] = {};

    for (int k0 = 0; k0 < K; k0 += 32) {
#pragma unroll
        for (int half = 0; half < 2; ++half) {
            int rbase = half * 64 + wave * 16;
            const char* ga = (const char*)(A + (size_t)(m0 + rbase + srow) * K + k0) + scol;
            gload_lds16(ga, (char*)As + rbase * 64);
            const char* gb = (const char*)(Bt + (size_t)(n0 + rbase + srow) * K + k0) + scol;
            gload_lds16(gb, (char*)Bs + rbase * 64);
        }
        __syncthreads();
        bf16x8 af[4], bfr[4];
#pragma unroll
        for (int mf = 0; mf < 4; ++mf)
            af[mf] = *(const bf16x8*)&As[(wm + mf * 16 + lrow) * 32 + kh * 8];
#pragma unroll
        for (int nf = 0; nf < 4; ++nf)
            bfr[nf] = *(const bf16x8*)&Bs[(wn + nf * 16 + lrow) * 32 + kh * 8];
#pragma unroll
        for (int mf = 0; mf < 4; ++mf)
#pragma unroll
            for (int nf = 0; nf < 4; ++nf)
                acc[mf][nf] = __builtin_amdgcn_mfma_f32_16x16x32_bf16(af[mf], bfr[nf], acc[mf][nf], 0, 0, 0);
        __syncthreads();
    }

#pragma unroll
    for (int mf = 0; mf < 4; ++mf) {
#pragma unroll
        for (int nf = 0; nf < 4; ++nf) {
            int col = n0 + wn + nf * 16 + lrow;
            float bv_ = bias[col];
#pragma unroll
            for (int r = 0; r < 4; ++r) {
                int row = m0 + wm + mf * 16 + kh * 4 + r;
                C[(size_t)row * N + col] = acc[mf][nf][r] + bv_;
            }
        }
    }
}

// ---------------------------------------------------------------------------
// Band attention. Per block: one (b, h, 64-row i-tile).
//   w_ij = expm1(q_i . k_j / 8)  for |i-j| <= 8, 0 <= j < S
//   ctx_i = (sum_j w_ij v_j + Vsum) / (sum_j w_ij + S)
// ---------------------------------------------------------------------------
__global__ __launch_bounds__(256) void band_attn(const bf16* __restrict__ qkv,
                                                 const float* __restrict__ vsum,
                                                 bf16* __restrict__ ctx) {
    int bid = blockIdx.x;
    int it = bid & 31;
    int h  = (bid >> 5) & 15;
    int b  = bid >> 9;
    const int i0 = it * 64;

    __shared__ bf16 qs[64 * 72];
    __shared__ bf16 ks[80 * 72];
    __shared__ bf16 vs[80 * 72];
    __shared__ float wsc[64 * 19];
    __shared__ float wsum[64];

    int tid = threadIdx.x;

    for (int idx = tid; idx < 64 * 8; idx += 256) {
        int r = idx >> 3, c = idx & 7;
        size_t g = (size_t)(b * S_LEN + i0 + r) * 3072 + h * 64 + c * 8;
        *(int4*)&qs[r * 72 + c * 8] = *(const int4*)&qkv[g];
    }
    for (int idx = tid; idx < 80 * 8; idx += 256) {
        int r = idx >> 3, c = idx & 7;
        int j = i0 - 8 + r;
        int4 kv = {0, 0, 0, 0}, vv = {0, 0, 0, 0};
        if (j >= 0 && j < S_LEN) {
            size_t base = (size_t)(b * S_LEN + j) * 3072 + h * 64 + c * 8;
            kv = *(const int4*)&qkv[base + 1024];
            vv = *(const int4*)&qkv[base + 2048];
        }
        *(int4*)&ks[r * 72 + c * 8] = kv;
        *(int4*)&vs[r * 72 + c * 8] = vv;
    }
    __syncthreads();

    {
        int i = tid >> 2, jg = tid & 3;
        bf16x8 qv[8];
#pragma unroll
        for (int c = 0; c < 8; ++c) qv[c] = *(const bf16x8*)&qs[i * 72 + c * 8];
        for (int jj = jg; jj < 17; jj += 4) {
            int j = i0 + i - 8 + jj;
            float w = 0.f;
            if (j >= 0 && j < S_LEN) {
                float dot = 0.f;
#pragma unroll
                for (int c = 0; c < 8; ++c) {
                    bf16x8 kv = *(const bf16x8*)&ks[(i + jj) * 72 + c * 8];
#pragma unroll
                    for (int e = 0; e < 8; ++e) dot += (float)qv[c][e] * (float)kv[e];
                }
                w = expm1f(dot * 0.125f);
            }
            wsc[i * 19 + jj] = w;
        }
    }
    __syncthreads();
    if (tid < 64) {
        float s = 0.f;
#pragma unroll
        for (int jj = 0; jj < 17; ++jj) s += wsc[tid * 19 + jj];
        wsum[tid] = s + (float)S_LEN;
    }
    __syncthreads();

    {
        int d0 = (tid & 31) * 2, ig = tid >> 5;
        float vb0 = vsum[(b * NH + h) * HD_DIM + d0];
        float vb1 = vsum[(b * NH + h) * HD_DIM + d0 + 1];
        for (int i = ig; i < 64; i += 8) {
            float a0 = vb0, a1 = vb1;
#pragma unroll
            for (int jj = 0; jj < 17; ++jj) {
                float w = wsc[i * 19 + jj];
                bf16x2 pv = *(const bf16x2*)&vs[(i + jj) * 72 + d0];
                a0 += w * (float)pv[0];
                a1 += w * (float)pv[1];
            }
            float inv = 1.0f / wsum[i];
            bf16x2 st;
            st[0] = (bf16)(a0 * inv);
            st[1] = (bf16)(a1 * inv);
            *(bf16x2*)&ctx[(size_t)(b * S_LEN + i0 + i) * 1024 + h * 64 + d0] = st;
        }
    }
}

// ---------------------------------------------------------------------------
extern "C" void kernel_launch(void* const* d_in, const int* in_sizes, int n_in,
                              void* d_out, int out_size, void* d_ws, size_t ws_size,
                              hipStream_t stream) {
    const float* x  = (const float*)d_in[0];
    const float* Wq = (const float*)d_in[1];
    const float* Wk = (const float*)d_in[2];
    const float* Wv = (const float*)d_in[3];
    const float* Wo = (const float*)d_in[4];
    const float* bq = (const float*)d_in[5];
    const float* bk = (const float*)d_in[6];
    const float* bv = (const float*)d_in[7];
    const float* bo = (const float*)d_in[8];

    char* ws = (char*)d_ws;
    bf16*  xb    = (bf16*)(ws);                       // 8 MB   x as bf16
    bf16*  wtall = (bf16*)(ws + 8388608);             // 6 MB   [Wq^T;Wk^T;Wv^T] bf16 [3072][1024]
    bf16*  wot   = (bf16*)(ws + 14680064);            // 2 MB   Wo^T bf16 [1024][1024]
    float* ball  = (float*)(ws + 16777216);           // 12 KB  bias concat [3072]
    bf16*  qkv   = (bf16*)(ws + 16789504);            // 24 MB  [4096][3072] bf16
    bf16*  ctxb  = (bf16*)(ws + 41955328);            // 8 MB   ctx bf16 [4096][1024]
    float* vsm   = (float*)(ws + 50343936);           // 8 KB   [2][1024] == [b][h*64+d]

    // fused: cvt(2048 blocks) + 4x transpose(1024) + bias+vsm-seed(12)
    prep_all<<<3084, 256, 0, stream>>>(x, Wq, Wk, Wv, Wo, bq, bk, bv,
                                       xb, wtall, wot, ball, vsm);

    // QKV projection (+fused V column sums): [4096][1024] x [3072][1024]^T
    gemm_qkv<1024><<<dim3(16, 16), 512, 0, stream>>>(xb, wtall, qkv, ball, vsm, 3072);

    band_attn<<<1024, 256, 0, stream>>>(qkv, vsm, ctxb);

    // output projection -> d_out fp32
    gemm_bt<<<dim3(32, 8), 256, 0, stream>>>(ctxb, wot, (float*)d_out, bo, 1024, 1024);
}

// Round 9
// 83.191 us; speedup vs baseline: 1.3866x; 1.0257x over previous
//
#include <hip/hip_runtime.h>
#include <hip/hip_bf16.h>
#include <cmath>

// Problem constants (LocalAttention: B=2, S=2048, D=1024, H=16, HD=64, W=16)
#define S_LEN 2048
#define DMODEL 1024
#define NH 16
#define HD_DIM 64

typedef __bf16 bf16;
typedef __bf16 bf16x2 __attribute__((ext_vector_type(2)));
typedef __bf16 bf16x8 __attribute__((ext_vector_type(8)));
typedef float f32x4 __attribute__((ext_vector_type(4)));

// ---------------------------------------------------------------------------
// Fused preprocessing: block-range dispatch
//   [0,2048)      : x fp32 -> bf16 (8 elems/thread)
//   [2048,3072)   : W[K][N] fp32 -> Wt[N][K] bf16 transpose (4 matrices)
//   [3072,3084)   : bias concat bq|bk|bv -> ball[3072]; seed vsm = 2048*bv
// ---------------------------------------------------------------------------
__global__ __launch_bounds__(256) void prep_all(const float* __restrict__ x,
                                                const float* __restrict__ Wq,
                                                const float* __restrict__ Wk,
                                                const float* __restrict__ Wv,
                                                const float* __restrict__ Wo,
                                                const float* __restrict__ bq,
                                                const float* __restrict__ bk,
                                                const float* __restrict__ bv,
                                                bf16* __restrict__ xb,
                                                bf16* __restrict__ wtall,
                                                bf16* __restrict__ wot,
                                                float* __restrict__ ball,
                                                float* __restrict__ vsm) {
    __shared__ float tile[64][65];
    const int bid = blockIdx.x;
    const int tid = threadIdx.x;
    if (bid < 2048) {
        int i = (bid * 256 + tid) * 8;
        float4 v0 = *(const float4*)(x + i);
        float4 v1 = *(const float4*)(x + i + 4);
        bf16x8 o;
        o[0] = (bf16)v0.x; o[1] = (bf16)v0.y; o[2] = (bf16)v0.z; o[3] = (bf16)v0.w;
        o[4] = (bf16)v1.x; o[5] = (bf16)v1.y; o[6] = (bf16)v1.z; o[7] = (bf16)v1.w;
        *(bf16x8*)(xb + i) = o;
    } else if (bid < 3072) {
        int t = bid - 2048;
        int z = t >> 8;
        t &= 255;
        const float* W = (z == 0) ? Wq : (z == 1) ? Wk : (z == 2) ? Wv : Wo;
        bf16* Wt = (z == 3) ? wot : wtall + (size_t)z * 1048576;
        int n0 = (t & 15) * 64, k0 = (t >> 4) * 64;
        int tr = tid >> 6, tc = tid & 63;
#pragma unroll
        for (int i = 0; i < 16; ++i) {
            int r = tr + i * 4;
            tile[r][tc] = W[(size_t)(k0 + r) * DMODEL + n0 + tc];
        }
        __syncthreads();
#pragma unroll
        for (int i = 0; i < 16; ++i) {
            int r = tr + i * 4;  // local n index
            Wt[(size_t)(n0 + r) * DMODEL + k0 + tc] = (bf16)tile[tc][r];
        }
    } else {
        int i = (bid - 3072) * 256 + tid;  // 0..3071
        float v = (i < 1024) ? bq[i] : (i < 2048) ? bk[i - 1024] : bv[i - 2048];
        ball[i] = v;
        if (i >= 2048) {
            // seed V column-sum accumulators with the bias term (and clear poison)
            int c = i - 2048;
            vsm[c]        = 2048.0f * v;
            vsm[1024 + c] = 2048.0f * v;
        }
    }
}

// ---------------------------------------------------------------------------
// async global->LDS, 16B per lane (dest = wave-uniform base + lane*16)
// ---------------------------------------------------------------------------
__device__ __forceinline__ void gload_lds16(const void* g, void* l) {
    __builtin_amdgcn_global_load_lds((const __attribute__((address_space(1))) void*)g,
                                     (__attribute__((address_space(3))) void*)l, 16, 0, 0);
}

#define BAR() asm volatile("s_barrier" ::: "memory")
#define VMC(N) asm volatile("s_waitcnt vmcnt(" #N ")" ::: "memory")

// ===========================================================================
// QKV GEMM v3: 128x192 tile, BK=64, 512 threads = 8 waves (2M x 4N),
// per-wave 64x48 output (acc 4mf x 3nf = 48 VGPR).
// LDS 80 KiB (A dbuf 2x16K + B dbuf 2x24K) -> 2 blocks/CU; launch_bounds
// caps VGPR at 128 so both blocks are resident: cross-block TLP covers the
// per-tile VMC(0) drain (R3/R4/R7-proven mechanism). T1 + T2 swizzles.
// Grid 512 blocks = 2 full residency waves.
// Epilogue folds V column-sums (cols >= 2048) into vsm (shfl + atomicAdd).
// ===========================================================================
#define QST(T, D) do {                                                                 \
    gload_lds16(aSrc + (size_t)(T) * 64, aDstW + (D) * 16384);                         \
    gload_lds16(aSrc + (size_t)64 * KDIM + (size_t)(T) * 64,                           \
                aDstW + (D) * 16384 + 8192);                                           \
    gload_lds16(bSrc + (size_t)(T) * 64, bDstW + (D) * 24576);                         \
    gload_lds16(bSrc + (size_t)64 * KDIM + (size_t)(T) * 64,                           \
                bDstW + (D) * 24576 + 8192);                                           \
    gload_lds16(bSrc + (size_t)128 * KDIM + (size_t)(T) * 64,                          \
                bDstW + (D) * 24576 + 16384);                                          \
} while (0)

template <int KDIM>
__global__ __launch_bounds__(512, 4) void gemm_qkv(const bf16* __restrict__ A,
                                                   const bf16* __restrict__ Bt,
                                                   bf16* __restrict__ C,
                                                   const float* __restrict__ bias,
                                                   float* __restrict__ vsm,
                                                   int N) {
    __shared__ bf16 smem[40960];  // 80 KiB: A[2][16K) at 0, B[2][24K) at 32768
    char* sc = (char*)smem;

    const int tid  = threadIdx.x;
    const int wv   = tid >> 6;
    const int lane = tid & 63;
    const int ll   = lane & 15;
    const int kh   = lane >> 4;
    const int wm   = wv >> 2;  // 0..1 : 64-row half
    const int wn   = wv & 3;   // 0..3 : 48-col quarter

    // XCD swizzle: 512 blocks, 64/XCD = all 32 m-tiles x 2 n-panels.
    const int flat = blockIdx.y * 32 + blockIdx.x;   // gridDim = (32,16)
    const int L    = (flat & 7) * 64 + (flat >> 3);  // bijective
    const int m0   = (L & 31) * 128;
    const int n0   = (L >> 5) * 192;

    // Staging: inverse-swizzled global source, linear LDS dest (8KB pieces).
    const int swcol = (((tid & 7) ^ ((tid >> 3) & 7)) << 3);
    const bf16* aSrc = A + (size_t)(m0 + (tid >> 3)) * KDIM + swcol;
    const bf16* bSrc = Bt + (size_t)(n0 + (tid >> 3)) * KDIM + swcol;
    char* aDstW = sc + wv * 1024;
    char* bDstW = sc + 32768 + wv * 1024;

    // Read side: XOR-swizzle ((row&7)<<4); row&7 == ll&7 for all fragments.
    const int aBase = wm * 8192 + ll * 128;          // rows wm*64 + ll
    const int bBase = (wn * 48 + ll) * 128;
    const int ks0 = ((kh ^ (ll & 7)) << 4);
    const int ks1 = (((4 | kh) ^ (ll & 7)) << 4);

    f32x4 acc[4][3] = {};

    constexpr int NT = KDIM / 64;  // 16 K-tiles

    QST(0, 0);
    VMC(0); BAR();

#pragma unroll 1
    for (int t = 0; t < NT; ++t) {
        const int d = t & 1;
        if (t + 1 < NT) QST(t + 1, d ^ 1);

        bf16x8 a[4][2], b[3][2];
#pragma unroll
        for (int mf = 0; mf < 4; ++mf) {
            a[mf][0] = *(const bf16x8*)(sc + d * 16384 + aBase + mf * 2048 + ks0);
            a[mf][1] = *(const bf16x8*)(sc + d * 16384 + aBase + mf * 2048 + ks1);
        }
#pragma unroll
        for (int nf = 0; nf < 3; ++nf) {
            b[nf][0] = *(const bf16x8*)(sc + 32768 + d * 24576 + bBase + nf * 2048 + ks0);
            b[nf][1] = *(const bf16x8*)(sc + 32768 + d * 24576 + bBase + nf * 2048 + ks1);
        }

        __builtin_amdgcn_s_setprio(1);
#pragma unroll
        for (int mf = 0; mf < 4; ++mf)
#pragma unroll
            for (int nf = 0; nf < 3; ++nf)
#pragma unroll
                for (int k = 0; k < 2; ++k)
                    acc[mf][nf] = __builtin_amdgcn_mfma_f32_16x16x32_bf16(
                        a[mf][k], b[nf][k], acc[mf][nf], 0, 0, 0);
        __builtin_amdgcn_s_setprio(0);

        VMC(0); BAR();  // next tile staged; other resident block covers drain
    }

    // ---- C write: row = m0+wm*64+mf*16+kh*4+r, col = n0+wn*48+nf*16+ll ----
#pragma unroll
    for (int nf = 0; nf < 3; ++nf) {
        const int col = n0 + wn * 48 + nf * 16 + ll;
        const float bv_ = bias[col];
#pragma unroll
        for (int mf = 0; mf < 4; ++mf) {
            const int row = m0 + wm * 64 + mf * 16 + kh * 4;
#pragma unroll
            for (int r = 0; r < 4; ++r)
                C[(size_t)(row + r) * N + col] = (bf16)(acc[mf][nf][r] + bv_);
        }
    }

    // ---- fused V column-sums (V cols = 2048..3071) ----
    {
        const int bidx = m0 >> 11;  // 128-row tile lies in one batch
#pragma unroll
        for (int nf = 0; nf < 3; ++nf) {
            if (n0 + wn * 48 + nf * 16 >= 2048) {  // wave-uniform predicate
                float p = 0.f;
#pragma unroll
                for (int mf = 0; mf < 4; ++mf)
#pragma unroll
                    for (int r = 0; r < 4; ++r) p += acc[mf][nf][r];
                p += __shfl_xor(p, 16);
                p += __shfl_xor(p, 32);
                if (kh == 0)
                    atomicAdd(vsm + bidx * 1024 + (n0 + wn * 48 + nf * 16 + ll - 2048), p);
            }
        }
    }
}

// ---------------------------------------------------------------------------
// Output projection: m97-style 128x128 tile, BK=32, 4 waves, 16 KB LDS ->
// high TLP hides the per-tile drain (R3/R7-proven). fp32 out + T1 swizzle.
// ---------------------------------------------------------------------------
__global__ __launch_bounds__(256) void gemm_bt(const bf16* __restrict__ A,
                                               const bf16* __restrict__ Bt,
                                               float* __restrict__ C,
                                               const float* __restrict__ bias,
                                               int N, int K) {
    __shared__ bf16 As[128 * 32];
    __shared__ bf16 Bs[128 * 32];
    const int tid  = threadIdx.x;
    const int wave = tid >> 6;
    const int lane = tid & 63;

    const int flat = blockIdx.y * 32 + blockIdx.x;   // gridDim = (32,8)
    const int L    = (flat & 7) * 32 + (flat >> 3);
    const int m0   = (L & 31) * 128;
    const int n0   = (L >> 5) * 128;

    const int wm = (wave >> 1) * 64;
    const int wn = (wave & 1) * 64;
    const int lrow = lane & 15;
    const int kh   = lane >> 4;
    const int srow = lane >> 2;
    const int scol = (lane & 3) * 16;

    f32x4 acc[4][4] = {};

    for (int k0 = 0; k0 < K; k0 += 32) {
#pragma unroll
        for (int half = 0; half < 2; ++half) {
            int rbase = half * 64 + wave * 16;
            const char* ga = (const char*)(A + (size_t)(m0 + rbase + srow) * K + k0) + scol;
            gload_lds16(ga, (char*)As + rbase * 64);
            const char* gb = (const char*)(Bt + (size_t)(n0 + rbase + srow) * K + k0) + scol;
            gload_lds16(gb, (char*)Bs + rbase * 64);
        }
        __syncthreads();
        bf16x8 af[4], bfr[4];
#pragma unroll
        for (int mf = 0; mf < 4; ++mf)
            af[mf] = *(const bf16x8*)&As[(wm + mf * 16 + lrow) * 32 + kh * 8];
#pragma unroll
        for (int nf = 0; nf < 4; ++nf)
            bfr[nf] = *(const bf16x8*)&Bs[(wn + nf * 16 + lrow) * 32 + kh * 8];
#pragma unroll
        for (int mf = 0; mf < 4; ++mf)
#pragma unroll
            for (int nf = 0; nf < 4; ++nf)
                acc[mf][nf] = __builtin_amdgcn_mfma_f32_16x16x32_bf16(af[mf], bfr[nf], acc[mf][nf], 0, 0, 0);
        __syncthreads();
    }

#pragma unroll
    for (int mf = 0; mf < 4; ++mf) {
#pragma unroll
        for (int nf = 0; nf < 4; ++nf) {
            int col = n0 + wn + nf * 16 + lrow;
            float bv_ = bias[col];
#pragma unroll
            for (int r = 0; r < 4; ++r) {
                int row = m0 + wm + mf * 16 + kh * 4 + r;
                C[(size_t)row * N + col] = acc[mf][nf][r] + bv_;
            }
        }
    }
}

// ---------------------------------------------------------------------------
// Band attention. Per block: one (b, h, 64-row i-tile).
//   w_ij = expm1(q_i . k_j / 8)  for |i-j| <= 8, 0 <= j < S
//   ctx_i = (sum_j w_ij v_j + Vsum) / (sum_j w_ij + S)
// ---------------------------------------------------------------------------
__global__ __launch_bounds__(256) void band_attn(const bf16* __restrict__ qkv,
                                                 const float* __restrict__ vsum,
                                                 bf16* __restrict__ ctx) {
    int bid = blockIdx.x;
    int it = bid & 31;
    int h  = (bid >> 5) & 15;
    int b  = bid >> 9;
    const int i0 = it * 64;

    __shared__ bf16 qs[64 * 72];
    __shared__ bf16 ks[80 * 72];
    __shared__ bf16 vs[80 * 72];
    __shared__ float wsc[64 * 19];
    __shared__ float wsum[64];

    int tid = threadIdx.x;

    for (int idx = tid; idx < 64 * 8; idx += 256) {
        int r = idx >> 3, c = idx & 7;
        size_t g = (size_t)(b * S_LEN + i0 + r) * 3072 + h * 64 + c * 8;
        *(int4*)&qs[r * 72 + c * 8] = *(const int4*)&qkv[g];
    }
    for (int idx = tid; idx < 80 * 8; idx += 256) {
        int r = idx >> 3, c = idx & 7;
        int j = i0 - 8 + r;
        int4 kv = {0, 0, 0, 0}, vv = {0, 0, 0, 0};
        if (j >= 0 && j < S_LEN) {
            size_t base = (size_t)(b * S_LEN + j) * 3072 + h * 64 + c * 8;
            kv = *(const int4*)&qkv[base + 1024];
            vv = *(const int4*)&qkv[base + 2048];
        }
        *(int4*)&ks[r * 72 + c * 8] = kv;
        *(int4*)&vs[r * 72 + c * 8] = vv;
    }
    __syncthreads();

    {
        int i = tid >> 2, jg = tid & 3;
        bf16x8 qv[8];
#pragma unroll
        for (int c = 0; c < 8; ++c) qv[c] = *(const bf16x8*)&qs[i * 72 + c * 8];
        for (int jj = jg; jj < 17; jj += 4) {
            int j = i0 + i - 8 + jj;
            float w = 0.f;
            if (j >= 0 && j < S_LEN) {
                float dot = 0.f;
#pragma unroll
                for (int c = 0; c < 8; ++c) {
                    bf16x8 kv = *(const bf16x8*)&ks[(i + jj) * 72 + c * 8];
#pragma unroll
                    for (int e = 0; e < 8; ++e) dot += (float)qv[c][e] * (float)kv[e];
                }
                w = expm1f(dot * 0.125f);
            }
            wsc[i * 19 + jj] = w;
        }
    }
    __syncthreads();
    if (tid < 64) {
        float s = 0.f;
#pragma unroll
        for (int jj = 0; jj < 17; ++jj) s += wsc[tid * 19 + jj];
        wsum[tid] = s + (float)S_LEN;
    }
    __syncthreads();

    {
        int d0 = (tid & 31) * 2, ig = tid >> 5;
        float vb0 = vsum[(b * NH + h) * HD_DIM + d0];
        float vb1 = vsum[(b * NH + h) * HD_DIM + d0 + 1];
        for (int i = ig; i < 64; i += 8) {
            float a0 = vb0, a1 = vb1;
#pragma unroll
            for (int jj = 0; jj < 17; ++jj) {
                float w = wsc[i * 19 + jj];
                bf16x2 pv = *(const bf16x2*)&vs[(i + jj) * 72 + d0];
                a0 += w * (float)pv[0];
                a1 += w * (float)pv[1];
            }
            float inv = 1.0f / wsum[i];
            bf16x2 st;
            st[0] = (bf16)(a0 * inv);
            st[1] = (bf16)(a1 * inv);
            *(bf16x2*)&ctx[(size_t)(b * S_LEN + i0 + i) * 1024 + h * 64 + d0] = st;
        }
    }
}

// ---------------------------------------------------------------------------
extern "C" void kernel_launch(void* const* d_in, const int* in_sizes, int n_in,
                              void* d_out, int out_size, void* d_ws, size_t ws_size,
                              hipStream_t stream) {
    const float* x  = (const float*)d_in[0];
    const float* Wq = (const float*)d_in[1];
    const float* Wk = (const float*)d_in[2];
    const float* Wv = (const float*)d_in[3];
    const float* Wo = (const float*)d_in[4];
    const float* bq = (const float*)d_in[5];
    const float* bk = (const float*)d_in[6];
    const float* bv = (const float*)d_in[7];
    const float* bo = (const float*)d_in[8];

    char* ws = (char*)d_ws;
    bf16*  xb    = (bf16*)(ws);                       // 8 MB   x as bf16
    bf16*  wtall = (bf16*)(ws + 8388608);             // 6 MB   [Wq^T;Wk^T;Wv^T] bf16 [3072][1024]
    bf16*  wot   = (bf16*)(ws + 14680064);            // 2 MB   Wo^T bf16 [1024][1024]
    float* ball  = (float*)(ws + 16777216);           // 12 KB  bias concat [3072]
    bf16*  qkv   = (bf16*)(ws + 16789504);             // 24 MB  [4096][3072] bf16
    bf16*  ctxb  = (bf16*)(ws + 41955328);            // 8 MB   ctx bf16 [4096][1024]
    float* vsm   = (float*)(ws + 50343936);           // 8 KB   [2][1024] == [b][h*64+d]

    // fused: cvt(2048 blocks) + 4x transpose(1024) + bias+vsm-seed(12)
    prep_all<<<3084, 256, 0, stream>>>(x, Wq, Wk, Wv, Wo, bq, bk, bv,
                                       xb, wtall, wot, ball, vsm);

    // QKV projection (+fused V column sums): [4096][1024] x [3072][1024]^T
    gemm_qkv<1024><<<dim3(32, 16), 512, 0, stream>>>(xb, wtall, qkv, ball, vsm, 3072);

    band_attn<<<1024, 256, 0, stream>>>(qkv, vsm, ctxb);

    // output projection -> d_out fp32
    gemm_bt<<<dim3(32, 8), 256, 0, stream>>>(ctxb, wot, (float*)d_out, bo, 1024, 1024);
}

// Round 10
// 80.487 us; speedup vs baseline: 1.4332x; 1.0336x over previous
//
#include <hip/hip_runtime.h>
#include <hip/hip_bf16.h>
#include <cmath>

// Problem constants (LocalAttention: B=2, S=2048, D=1024, H=16, HD=64, W=16)
#define S_LEN 2048
#define DMODEL 1024
#define NH 16
#define HD_DIM 64

typedef __bf16 bf16;
typedef __bf16 bf16x2 __attribute__((ext_vector_type(2)));
typedef __bf16 bf16x8 __attribute__((ext_vector_type(8)));
typedef float f32x4 __attribute__((ext_vector_type(4)));

// ---------------------------------------------------------------------------
// Fused preprocessing: block-range dispatch
//   [0,2048)      : x fp32 -> bf16 (8 elems/thread)
//   [2048,3072)   : W[K][N] fp32 -> Wt[N][K] bf16 transpose (4 matrices)
//   [3072,3084)   : bias concat bq|bk|bv -> ball[3072]; seed vsm = 2048*bv
// ---------------------------------------------------------------------------
__global__ __launch_bounds__(256) void prep_all(const float* __restrict__ x,
                                                const float* __restrict__ Wq,
                                                const float* __restrict__ Wk,
                                                const float* __restrict__ Wv,
                                                const float* __restrict__ Wo,
                                                const float* __restrict__ bq,
                                                const float* __restrict__ bk,
                                                const float* __restrict__ bv,
                                                bf16* __restrict__ xb,
                                                bf16* __restrict__ wtall,
                                                bf16* __restrict__ wot,
                                                float* __restrict__ ball,
                                                float* __restrict__ vsm) {
    __shared__ float tile[64][65];
    const int bid = blockIdx.x;
    const int tid = threadIdx.x;
    if (bid < 2048) {
        int i = (bid * 256 + tid) * 8;
        float4 v0 = *(const float4*)(x + i);
        float4 v1 = *(const float4*)(x + i + 4);
        bf16x8 o;
        o[0] = (bf16)v0.x; o[1] = (bf16)v0.y; o[2] = (bf16)v0.z; o[3] = (bf16)v0.w;
        o[4] = (bf16)v1.x; o[5] = (bf16)v1.y; o[6] = (bf16)v1.z; o[7] = (bf16)v1.w;
        *(bf16x8*)(xb + i) = o;
    } else if (bid < 3072) {
        int t = bid - 2048;
        int z = t >> 8;
        t &= 255;
        const float* W = (z == 0) ? Wq : (z == 1) ? Wk : (z == 2) ? Wv : Wo;
        bf16* Wt = (z == 3) ? wot : wtall + (size_t)z * 1048576;
        int n0 = (t & 15) * 64, k0 = (t >> 4) * 64;
        int tr = tid >> 6, tc = tid & 63;
#pragma unroll
        for (int i = 0; i < 16; ++i) {
            int r = tr + i * 4;
            tile[r][tc] = W[(size_t)(k0 + r) * DMODEL + n0 + tc];
        }
        __syncthreads();
#pragma unroll
        for (int i = 0; i < 16; ++i) {
            int r = tr + i * 4;  // local n index
            Wt[(size_t)(n0 + r) * DMODEL + k0 + tc] = (bf16)tile[tc][r];
        }
    } else {
        int i = (bid - 3072) * 256 + tid;  // 0..3071
        float v = (i < 1024) ? bq[i] : (i < 2048) ? bk[i - 1024] : bv[i - 2048];
        ball[i] = v;
        if (i >= 2048) {
            // seed V column-sum accumulators with the bias term (and clear poison)
            int c = i - 2048;
            vsm[c]        = 2048.0f * v;
            vsm[1024 + c] = 2048.0f * v;
        }
    }
}

// ---------------------------------------------------------------------------
// async global->LDS, 16B per lane (dest = wave-uniform base + lane*16)
// ---------------------------------------------------------------------------
__device__ __forceinline__ void gload_lds16(const void* g, void* l) {
    __builtin_amdgcn_global_load_lds((const __attribute__((address_space(1))) void*)g,
                                     (__attribute__((address_space(3))) void*)l, 16, 0, 0);
}

#define BAR() asm volatile("s_barrier" ::: "memory")
#define VMC(N) asm volatile("s_waitcnt vmcnt(" #N ")" ::: "memory")

// ===========================================================================
// QKV GEMM v4: 128x192 tile, BK=64, 256 threads = 4 waves (2M x 2N),
// per-wave 64x96 output (acc 4mf x 6nf = 96 VGPR).
// LDS-BW optimization vs v3: A fragment-read amplification 4 -> 2
// (LDS reads 1.75 -> 1.28 MB/block over K=1024), same MFMA count, 2x
// per-wave ILP. LDS 80 KiB dbuf -> 2 blocks/CU (cross-block TLP covers
// the per-tile VMC(0) drain). T1 + T2 swizzles. Grid 512 blocks.
// Epilogue folds V column-sums (cols >= 2048) into vsm (shfl + atomicAdd).
// ===========================================================================
#define QST(T, D) do {                                                                 \
    _Pragma("unroll") for (int _p = 0; _p < 4; ++_p)                                   \
        gload_lds16(aSrc + (size_t)(32 * _p) * KDIM + (size_t)(T) * 64,                \
                    aDstW + (D) * 16384 + _p * 4096);                                  \
    _Pragma("unroll") for (int _p = 0; _p < 6; ++_p)                                   \
        gload_lds16(bSrc + (size_t)(32 * _p) * KDIM + (size_t)(T) * 64,                \
                    bDstW + (D) * 24576 + _p * 4096);                                  \
} while (0)

template <int KDIM>
__global__ __launch_bounds__(256, 2) void gemm_qkv(const bf16* __restrict__ A,
                                                   const bf16* __restrict__ Bt,
                                                   bf16* __restrict__ C,
                                                   const float* __restrict__ bias,
                                                   float* __restrict__ vsm,
                                                   int N) {
    __shared__ bf16 smem[40960];  // 80 KiB: A[2][16K) at 0, B[2][24K) at 32768
    char* sc = (char*)smem;

    const int tid  = threadIdx.x;
    const int wv   = tid >> 6;
    const int lane = tid & 63;
    const int ll   = lane & 15;
    const int kh   = lane >> 4;
    const int wm   = wv >> 1;  // 0..1 : 64-row half
    const int wn   = wv & 1;   // 0..1 : 96-col half

    // XCD swizzle: 512 blocks, 64/XCD = all 32 m-tiles x 2 n-panels.
    const int flat = blockIdx.y * 32 + blockIdx.x;   // gridDim = (32,16)
    const int L    = (flat & 7) * 64 + (flat >> 3);  // bijective
    const int m0   = (L & 31) * 128;
    const int n0   = (L >> 5) * 192;

    // Staging: inverse-swizzled global source, linear LDS dest (4KB pieces,
    // 32 rows each; row%8 == (tid>>3)%8 for every piece -> one swcol works).
    const int swcol = (((tid & 7) ^ ((tid >> 3) & 7)) << 3);
    const bf16* aSrc = A + (size_t)(m0 + (tid >> 3)) * KDIM + swcol;
    const bf16* bSrc = Bt + (size_t)(n0 + (tid >> 3)) * KDIM + swcol;
    char* aDstW = sc + wv * 1024;
    char* bDstW = sc + 32768 + wv * 1024;

    // Read side: XOR-swizzle ((row&7)<<4); row&7 == ll&7 for all fragments.
    const int aBase = wm * 8192 + ll * 128;          // rows wm*64 + mf*16 + ll
    const int bBase = (wn * 96 + ll) * 128;          // rows wn*96 + nf*16 + ll
    const int ks0 = ((kh ^ (ll & 7)) << 4);
    const int ks1 = (((4 | kh) ^ (ll & 7)) << 4);

    f32x4 acc[4][6] = {};

    constexpr int NT = KDIM / 64;  // 16 K-tiles

    QST(0, 0);
    VMC(0); BAR();

#pragma unroll 1
    for (int t = 0; t < NT; ++t) {
        const int d = t & 1;
        if (t + 1 < NT) QST(t + 1, d ^ 1);

        bf16x8 a[4][2], b[3][2];
#pragma unroll
        for (int mf = 0; mf < 4; ++mf) {
            a[mf][0] = *(const bf16x8*)(sc + d * 16384 + aBase + mf * 2048 + ks0);
            a[mf][1] = *(const bf16x8*)(sc + d * 16384 + aBase + mf * 2048 + ks1);
        }
        // B chunk 0: nf 0..2
#pragma unroll
        for (int nf = 0; nf < 3; ++nf) {
            b[nf][0] = *(const bf16x8*)(sc + 32768 + d * 24576 + bBase + nf * 2048 + ks0);
            b[nf][1] = *(const bf16x8*)(sc + 32768 + d * 24576 + bBase + nf * 2048 + ks1);
        }
        __builtin_amdgcn_s_setprio(1);
#pragma unroll
        for (int mf = 0; mf < 4; ++mf)
#pragma unroll
            for (int nf = 0; nf < 3; ++nf)
#pragma unroll
                for (int k = 0; k < 2; ++k)
                    acc[mf][nf] = __builtin_amdgcn_mfma_f32_16x16x32_bf16(
                        a[mf][k], b[nf][k], acc[mf][nf], 0, 0, 0);
        __builtin_amdgcn_s_setprio(0);
        // B chunk 1: nf 3..5
#pragma unroll
        for (int nf = 0; nf < 3; ++nf) {
            b[nf][0] = *(const bf16x8*)(sc + 32768 + d * 24576 + bBase + (nf + 3) * 2048 + ks0);
            b[nf][1] = *(const bf16x8*)(sc + 32768 + d * 24576 + bBase + (nf + 3) * 2048 + ks1);
        }
        __builtin_amdgcn_s_setprio(1);
#pragma unroll
        for (int mf = 0; mf < 4; ++mf)
#pragma unroll
            for (int nf = 0; nf < 3; ++nf)
#pragma unroll
                for (int k = 0; k < 2; ++k)
                    acc[mf][nf + 3] = __builtin_amdgcn_mfma_f32_16x16x32_bf16(
                        a[mf][k], b[nf][k], acc[mf][nf + 3], 0, 0, 0);
        __builtin_amdgcn_s_setprio(0);

        VMC(0); BAR();  // next tile staged; co-resident block covers drain
    }

    // ---- C write: row = m0+wm*64+mf*16+kh*4+r, col = n0+wn*96+nf*16+ll ----
#pragma unroll
    for (int nf = 0; nf < 6; ++nf) {
        const int col = n0 + wn * 96 + nf * 16 + ll;
        const float bv_ = bias[col];
#pragma unroll
        for (int mf = 0; mf < 4; ++mf) {
            const int row = m0 + wm * 64 + mf * 16 + kh * 4;
#pragma unroll
            for (int r = 0; r < 4; ++r)
                C[(size_t)(row + r) * N + col] = (bf16)(acc[mf][nf][r] + bv_);
        }
    }

    // ---- fused V column-sums (V cols = 2048..3071) ----
    {
        const int bidx = m0 >> 11;  // 128-row tile lies in one batch
#pragma unroll
        for (int nf = 0; nf < 6; ++nf) {
            if (n0 + wn * 96 + nf * 16 >= 2048) {  // wave-uniform predicate
                float p = 0.f;
#pragma unroll
                for (int mf = 0; mf < 4; ++mf)
#pragma unroll
                    for (int r = 0; r < 4; ++r) p += acc[mf][nf][r];
                p += __shfl_xor(p, 16);
                p += __shfl_xor(p, 32);
                if (kh == 0)
                    atomicAdd(vsm + bidx * 1024 + (n0 + wn * 96 + nf * 16 + ll - 2048), p);
            }
        }
    }
}

// ---------------------------------------------------------------------------
// Output projection v2: 64x128 tile, BK=32, 4 waves (2M x 2N), 12 KB LDS,
// grid (64,8) = 512 blocks -> 2 blocks/CU (was grid-limited to 1): cross-
// block TLP covers the per-tile drain. m97-proven inner structure.
// XCD swizzle: each XCD owns exactly one 128-col Wo^T panel (L2-resident).
// ---------------------------------------------------------------------------
__global__ __launch_bounds__(256) void gemm_bt(const bf16* __restrict__ A,
                                               const bf16* __restrict__ Bt,
                                               float* __restrict__ C,
                                               const float* __restrict__ bias,
                                               int N, int K) {
    __shared__ bf16 As[64 * 32];    // 4 KB
    __shared__ bf16 Bs[128 * 32];   // 8 KB
    const int tid  = threadIdx.x;
    const int wave = tid >> 6;
    const int lane = tid & 63;

    const int flat = blockIdx.y * 64 + blockIdx.x;   // gridDim = (64,8)
    const int L    = (flat & 7) * 64 + (flat >> 3);  // bijective
    const int m0   = (L & 63) * 64;
    const int n0   = (L >> 6) * 128;

    const int wm = (wave >> 1) * 32;   // 0..1 -> 32-row half
    const int wn = (wave & 1) * 64;    // 0..1 -> 64-col half
    const int lrow = lane & 15;
    const int kh   = lane >> 4;        // 0..3
    const int srow = tid >> 2;         // staging row (256 thr, 64B rows)
    const int scol = (tid & 3) * 16;   // byte offset within 64B k-row

    f32x4 acc[2][4] = {};

    for (int k0 = 0; k0 < K; k0 += 32) {
        // A: 64 rows x 64B = 1 piece; B: 128 rows = 2 pieces
        {
            const char* ga = (const char*)(A + (size_t)(m0 + srow) * K + k0) + scol;
            gload_lds16(ga, (char*)As + wave * 1024);
#pragma unroll
            for (int p = 0; p < 2; ++p) {
                const char* gb = (const char*)(Bt + (size_t)(n0 + p * 64 + srow) * K + k0) + scol;
                gload_lds16(gb, (char*)Bs + p * 4096 + wave * 1024);
            }
        }
        __syncthreads();
        bf16x8 af[2], bfr[4];
#pragma unroll
        for (int mf = 0; mf < 2; ++mf)
            af[mf] = *(const bf16x8*)&As[(wm + mf * 16 + lrow) * 32 + kh * 8];
#pragma unroll
        for (int nf = 0; nf < 4; ++nf)
            bfr[nf] = *(const bf16x8*)&Bs[(wn + nf * 16 + lrow) * 32 + kh * 8];
#pragma unroll
        for (int mf = 0; mf < 2; ++mf)
#pragma unroll
            for (int nf = 0; nf < 4; ++nf)
                acc[mf][nf] = __builtin_amdgcn_mfma_f32_16x16x32_bf16(af[mf], bfr[nf], acc[mf][nf], 0, 0, 0);
        __syncthreads();
    }

#pragma unroll
    for (int mf = 0; mf < 2; ++mf) {
#pragma unroll
        for (int nf = 0; nf < 4; ++nf) {
            int col = n0 + wn + nf * 16 + lrow;
            float bv_ = bias[col];
#pragma unroll
            for (int r = 0; r < 4; ++r) {
                int row = m0 + wm + mf * 16 + kh * 4 + r;
                C[(size_t)row * N + col] = acc[mf][nf][r] + bv_;
            }
        }
    }
}

// ---------------------------------------------------------------------------
// Band attention. Per block: one (b, h, 64-row i-tile).
//   w_ij = expm1(q_i . k_j / 8)  for |i-j| <= 8, 0 <= j < S
//   ctx_i = (sum_j w_ij v_j + Vsum) / (sum_j w_ij + S)
// ---------------------------------------------------------------------------
__global__ __launch_bounds__(256) void band_attn(const bf16* __restrict__ qkv,
                                                 const float* __restrict__ vsum,
                                                 bf16* __restrict__ ctx) {
    int bid = blockIdx.x;
    int it = bid & 31;
    int h  = (bid >> 5) & 15;
    int b  = bid >> 9;
    const int i0 = it * 64;

    __shared__ bf16 qs[64 * 72];
    __shared__ bf16 ks[80 * 72];
    __shared__ bf16 vs[80 * 72];
    __shared__ float wsc[64 * 19];
    __shared__ float wsum[64];

    int tid = threadIdx.x;

    for (int idx = tid; idx < 64 * 8; idx += 256) {
        int r = idx >> 3, c = idx & 7;
        size_t g = (size_t)(b * S_LEN + i0 + r) * 3072 + h * 64 + c * 8;
        *(int4*)&qs[r * 72 + c * 8] = *(const int4*)&qkv[g];
    }
    for (int idx = tid; idx < 80 * 8; idx += 256) {
        int r = idx >> 3, c = idx & 7;
        int j = i0 - 8 + r;
        int4 kv = {0, 0, 0, 0}, vv = {0, 0, 0, 0};
        if (j >= 0 && j < S_LEN) {
            size_t base = (size_t)(b * S_LEN + j) * 3072 + h * 64 + c * 8;
            kv = *(const int4*)&qkv[base + 1024];
            vv = *(const int4*)&qkv[base + 2048];
        }
        *(int4*)&ks[r * 72 + c * 8] = kv;
        *(int4*)&vs[r * 72 + c * 8] = vv;
    }
    __syncthreads();

    {
        int i = tid >> 2, jg = tid & 3;
        bf16x8 qv[8];
#pragma unroll
        for (int c = 0; c < 8; ++c) qv[c] = *(const bf16x8*)&qs[i * 72 + c * 8];
        for (int jj = jg; jj < 17; jj += 4) {
            int j = i0 + i - 8 + jj;
            float w = 0.f;
            if (j >= 0 && j < S_LEN) {
                float dot = 0.f;
#pragma unroll
                for (int c = 0; c < 8; ++c) {
                    bf16x8 kv = *(const bf16x8*)&ks[(i + jj) * 72 + c * 8];
#pragma unroll
                    for (int e = 0; e < 8; ++e) dot += (float)qv[c][e] * (float)kv[e];
                }
                w = expm1f(dot * 0.125f);
            }
            wsc[i * 19 + jj] = w;
        }
    }
    __syncthreads();
    if (tid < 64) {
        float s = 0.f;
#pragma unroll
        for (int jj = 0; jj < 17; ++jj) s += wsc[tid * 19 + jj];
        wsum[tid] = s + (float)S_LEN;
    }
    __syncthreads();

    {
        int d0 = (tid & 31) * 2, ig = tid >> 5;
        float vb0 = vsum[(b * NH + h) * HD_DIM + d0];
        float vb1 = vsum[(b * NH + h) * HD_DIM + d0 + 1];
        for (int i = ig; i < 64; i += 8) {
            float a0 = vb0, a1 = vb1;
#pragma unroll
            for (int jj = 0; jj < 17; ++jj) {
                float w = wsc[i * 19 + jj];
                bf16x2 pv = *(const bf16x2*)&vs[(i + jj) * 72 + d0];
                a0 += w * (float)pv[0];
                a1 += w * (float)pv[1];
            }
            float inv = 1.0f / wsum[i];
            bf16x2 st;
            st[0] = (bf16)(a0 * inv);
            st[1] = (bf16)(a1 * inv);
            *(bf16x2*)&ctx[(size_t)(b * S_LEN + i0 + i) * 1024 + h * 64 + d0] = st;
        }
    }
}

// ---------------------------------------------------------------------------
extern "C" void kernel_launch(void* const* d_in, const int* in_sizes, int n_in,
                              void* d_out, int out_size, void* d_ws, size_t ws_size,
                              hipStream_t stream) {
    const float* x  = (const float*)d_in[0];
    const float* Wq = (const float*)d_in[1];
    const float* Wk = (const float*)d_in[2];
    const float* Wv = (const float*)d_in[3];
    const float* Wo = (const float*)d_in[4];
    const float* bq = (const float*)d_in[5];
    const float* bk = (const float*)d_in[6];
    const float* bv = (const float*)d_in[7];
    const float* bo = (const float*)d_in[8];

    char* ws = (char*)d_ws;
    bf16*  xb    = (bf16*)(ws);                       // 8 MB   x as bf16
    bf16*  wtall = (bf16*)(ws + 8388608);             // 6 MB   [Wq^T;Wk^T;Wv^T] bf16 [3072][1024]
    bf16*  wot   = (bf16*)(ws + 14680064);            // 2 MB   Wo^T bf16 [1024][1024]
    float* ball  = (float*)(ws + 16777216);           // 12 KB  bias concat [3072]
    bf16*  qkv   = (bf16*)(ws + 16789504);            // 24 MB  [4096][3072] bf16
    bf16*  ctxb  = (bf16*)(ws + 41955328);            // 8 MB   ctx bf16 [4096][1024]
    float* vsm   = (float*)(ws + 50343936);           // 8 KB   [2][1024] == [b][h*64+d]

    // fused: cvt(2048 blocks) + 4x transpose(1024) + bias+vsm-seed(12)
    prep_all<<<3084, 256, 0, stream>>>(x, Wq, Wk, Wv, Wo, bq, bk, bv,
                                       xb, wtall, wot, ball, vsm);

    // QKV projection (+fused V column sums): [4096][1024] x [3072][1024]^T
    gemm_qkv<1024><<<dim3(32, 16), 256, 0, stream>>>(xb, wtall, qkv, ball, vsm, 3072);

    band_attn<<<1024, 256, 0, stream>>>(qkv, vsm, ctxb);

    // output projection -> d_out fp32
    gemm_bt<<<dim3(64, 8), 256, 0, stream>>>(ctxb, wot, (float*)d_out, bo, 1024, 1024);
}

// Round 11
// 72.531 us; speedup vs baseline: 1.5904x; 1.1097x over previous
//
#include <hip/hip_runtime.h>
#include <hip/hip_bf16.h>
#include <cmath>

// Problem constants (LocalAttention: B=2, S=2048, D=1024, H=16, HD=64, W=16)
#define S_LEN 2048
#define DMODEL 1024
#define NH 16
#define HD_DIM 64

typedef __bf16 bf16;
typedef __bf16 bf16x2 __attribute__((ext_vector_type(2)));
typedef __bf16 bf16x8 __attribute__((ext_vector_type(8)));
typedef float f32x4 __attribute__((ext_vector_type(4)));

// ---------------------------------------------------------------------------
// Fused preprocessing: block-range dispatch
//   [0,2048)      : x fp32 -> bf16 (8 elems/thread)
//   [2048,3072)   : W[K][N] fp32 -> Wt[N][K] bf16 transpose (4 matrices)
//   [3072,3084)   : bias concat bq|bk|bv -> ball[3072]; seed vsm = 2048*bv
// ---------------------------------------------------------------------------
__global__ __launch_bounds__(256) void prep_all(const float* __restrict__ x,
                                                const float* __restrict__ Wq,
                                                const float* __restrict__ Wk,
                                                const float* __restrict__ Wv,
                                                const float* __restrict__ Wo,
                                                const float* __restrict__ bq,
                                                const float* __restrict__ bk,
                                                const float* __restrict__ bv,
                                                bf16* __restrict__ xb,
                                                bf16* __restrict__ wtall,
                                                bf16* __restrict__ wot,
                                                float* __restrict__ ball,
                                                float* __restrict__ vsm) {
    __shared__ float tile[64][65];
    const int bid = blockIdx.x;
    const int tid = threadIdx.x;
    if (bid < 2048) {
        int i = (bid * 256 + tid) * 8;
        float4 v0 = *(const float4*)(x + i);
        float4 v1 = *(const float4*)(x + i + 4);
        bf16x8 o;
        o[0] = (bf16)v0.x; o[1] = (bf16)v0.y; o[2] = (bf16)v0.z; o[3] = (bf16)v0.w;
        o[4] = (bf16)v1.x; o[5] = (bf16)v1.y; o[6] = (bf16)v1.z; o[7] = (bf16)v1.w;
        *(bf16x8*)(xb + i) = o;
    } else if (bid < 3072) {
        int t = bid - 2048;
        int z = t >> 8;
        t &= 255;
        const float* W = (z == 0) ? Wq : (z == 1) ? Wk : (z == 2) ? Wv : Wo;
        bf16* Wt = (z == 3) ? wot : wtall + (size_t)z * 1048576;
        int n0 = (t & 15) * 64, k0 = (t >> 4) * 64;
        int tr = tid >> 6, tc = tid & 63;
#pragma unroll
        for (int i = 0; i < 16; ++i) {
            int r = tr + i * 4;
            tile[r][tc] = W[(size_t)(k0 + r) * DMODEL + n0 + tc];
        }
        __syncthreads();
#pragma unroll
        for (int i = 0; i < 16; ++i) {
            int r = tr + i * 4;  // local n index
            Wt[(size_t)(n0 + r) * DMODEL + k0 + tc] = (bf16)tile[tc][r];
        }
    } else {
        int i = (bid - 3072) * 256 + tid;  // 0..3071
        float v = (i < 1024) ? bq[i] : (i < 2048) ? bk[i - 1024] : bv[i - 2048];
        ball[i] = v;
        if (i >= 2048) {
            // seed V column-sum accumulators with the bias term (and clear poison)
            int c = i - 2048;
            vsm[c]        = 2048.0f * v;
            vsm[1024 + c] = 2048.0f * v;
        }
    }
}

// ---------------------------------------------------------------------------
// async global->LDS, 16B per lane (dest = wave-uniform base + lane*16)
// ---------------------------------------------------------------------------
__device__ __forceinline__ void gload_lds16(const void* g, void* l) {
    __builtin_amdgcn_global_load_lds((const __attribute__((address_space(1))) void*)g,
                                     (__attribute__((address_space(3))) void*)l, 16, 0, 0);
}

#define BAR() asm volatile("s_barrier" ::: "memory")
#define VMC(N) asm volatile("s_waitcnt vmcnt(" #N ")" ::: "memory")

// ===========================================================================
// QKV GEMM v4: 128x192 tile, BK=64, 256 threads = 4 waves (2M x 2N),
// per-wave 64x96 output (acc 4mf x 6nf = 96 VGPR).
// LDS 80 KiB dbuf -> 2 blocks/CU (cross-block TLP covers per-tile drain).
// XCD swizzle v2: same-m block pairs adjacent within an XCD (concurrent) so
// the 256 KB A row-panel's second read is an L2 hit instead of L3.
// Epilogue folds V column-sums (cols >= 2048) into vsm (shfl + atomicAdd).
// ===========================================================================
#define QST(T, D) do {                                                                 \
    _Pragma("unroll") for (int _p = 0; _p < 4; ++_p)                                   \
        gload_lds16(aSrc + (size_t)(32 * _p) * KDIM + (size_t)(T) * 64,                \
                    aDstW + (D) * 16384 + _p * 4096);                                  \
    _Pragma("unroll") for (int _p = 0; _p < 6; ++_p)                                   \
        gload_lds16(bSrc + (size_t)(32 * _p) * KDIM + (size_t)(T) * 64,                \
                    bDstW + (D) * 24576 + _p * 4096);                                  \
} while (0)

template <int KDIM>
__global__ __launch_bounds__(256, 2) void gemm_qkv(const bf16* __restrict__ A,
                                                   const bf16* __restrict__ Bt,
                                                   bf16* __restrict__ C,
                                                   const float* __restrict__ bias,
                                                   float* __restrict__ vsm,
                                                   int N) {
    __shared__ bf16 smem[40960];  // 80 KiB: A[2][16K) at 0, B[2][24K) at 32768
    char* sc = (char*)smem;

    const int tid  = threadIdx.x;
    const int wv   = tid >> 6;
    const int lane = tid & 63;
    const int ll   = lane & 15;
    const int kh   = lane >> 4;
    const int wm   = wv >> 1;  // 0..1 : 64-row half
    const int wn   = wv & 1;   // 0..1 : 96-col half

    // XCD swizzle v2: XCD = flat%8 owns n-panels {2*xcd, 2*xcd+1}; within the
    // XCD, blocks are ordered (m, n-pair) so same-m blocks are concurrent.
    const int flat = blockIdx.y * 32 + blockIdx.x;   // gridDim = (32,16)
    const int L    = (flat & 7) * 64 + (flat >> 3);  // bijective (512 blocks)
    const int m0   = ((L & 63) >> 1) * 128;          // 0..31
    const int n0   = ((L >> 6) * 2 + (L & 1)) * 192; // 0..15

    // Staging: inverse-swizzled global source, linear LDS dest (4KB pieces,
    // 32 rows each; row%8 == (tid>>3)%8 for every piece -> one swcol works).
    const int swcol = (((tid & 7) ^ ((tid >> 3) & 7)) << 3);
    const bf16* aSrc = A + (size_t)(m0 + (tid >> 3)) * KDIM + swcol;
    const bf16* bSrc = Bt + (size_t)(n0 + (tid >> 3)) * KDIM + swcol;
    char* aDstW = sc + wv * 1024;
    char* bDstW = sc + 32768 + wv * 1024;

    // Read side: XOR-swizzle ((row&7)<<4); row&7 == ll&7 for all fragments.
    const int aBase = wm * 8192 + ll * 128;          // rows wm*64 + mf*16 + ll
    const int bBase = (wn * 96 + ll) * 128;          // rows wn*96 + nf*16 + ll
    const int ks0 = ((kh ^ (ll & 7)) << 4);
    const int ks1 = (((4 | kh) ^ (ll & 7)) << 4);

    f32x4 acc[4][6] = {};

    constexpr int NT = KDIM / 64;  // 16 K-tiles

    QST(0, 0);
    VMC(0); BAR();

#pragma unroll 1
    for (int t = 0; t < NT; ++t) {
        const int d = t & 1;
        if (t + 1 < NT) QST(t + 1, d ^ 1);

        bf16x8 a[4][2], b[3][2];
#pragma unroll
        for (int mf = 0; mf < 4; ++mf) {
            a[mf][0] = *(const bf16x8*)(sc + d * 16384 + aBase + mf * 2048 + ks0);
            a[mf][1] = *(const bf16x8*)(sc + d * 16384 + aBase + mf * 2048 + ks1);
        }
        // B chunk 0: nf 0..2
#pragma unroll
        for (int nf = 0; nf < 3; ++nf) {
            b[nf][0] = *(const bf16x8*)(sc + 32768 + d * 24576 + bBase + nf * 2048 + ks0);
            b[nf][1] = *(const bf16x8*)(sc + 32768 + d * 24576 + bBase + nf * 2048 + ks1);
        }
        __builtin_amdgcn_s_setprio(1);
#pragma unroll
        for (int mf = 0; mf < 4; ++mf)
#pragma unroll
            for (int nf = 0; nf < 3; ++nf)
#pragma unroll
                for (int k = 0; k < 2; ++k)
                    acc[mf][nf] = __builtin_amdgcn_mfma_f32_16x16x32_bf16(
                        a[mf][k], b[nf][k], acc[mf][nf], 0, 0, 0);
        __builtin_amdgcn_s_setprio(0);
        // B chunk 1: nf 3..5
#pragma unroll
        for (int nf = 0; nf < 3; ++nf) {
            b[nf][0] = *(const bf16x8*)(sc + 32768 + d * 24576 + bBase + (nf + 3) * 2048 + ks0);
            b[nf][1] = *(const bf16x8*)(sc + 32768 + d * 24576 + bBase + (nf + 3) * 2048 + ks1);
        }
        __builtin_amdgcn_s_setprio(1);
#pragma unroll
        for (int mf = 0; mf < 4; ++mf)
#pragma unroll
            for (int nf = 0; nf < 3; ++nf)
#pragma unroll
                for (int k = 0; k < 2; ++k)
                    acc[mf][nf + 3] = __builtin_amdgcn_mfma_f32_16x16x32_bf16(
                        a[mf][k], b[nf][k], acc[mf][nf + 3], 0, 0, 0);
        __builtin_amdgcn_s_setprio(0);

        VMC(0); BAR();  // next tile staged; co-resident block covers drain
    }

    // ---- C write: row = m0+wm*64+mf*16+kh*4+r, col = n0+wn*96+nf*16+ll ----
#pragma unroll
    for (int nf = 0; nf < 6; ++nf) {
        const int col = n0 + wn * 96 + nf * 16 + ll;
        const float bv_ = bias[col];
#pragma unroll
        for (int mf = 0; mf < 4; ++mf) {
            const int row = m0 + wm * 64 + mf * 16 + kh * 4;
#pragma unroll
            for (int r = 0; r < 4; ++r)
                C[(size_t)(row + r) * N + col] = (bf16)(acc[mf][nf][r] + bv_);
        }
    }

    // ---- fused V column-sums (V cols = 2048..3071) ----
    {
        const int bidx = m0 >> 11;  // 128-row tile lies in one batch
#pragma unroll
        for (int nf = 0; nf < 6; ++nf) {
            if (n0 + wn * 96 + nf * 16 >= 2048) {  // wave-uniform predicate
                float p = 0.f;
#pragma unroll
                for (int mf = 0; mf < 4; ++mf)
#pragma unroll
                    for (int r = 0; r < 4; ++r) p += acc[mf][nf][r];
                p += __shfl_xor(p, 16);
                p += __shfl_xor(p, 32);
                if (kh == 0)
                    atomicAdd(vsm + bidx * 1024 + (n0 + wn * 96 + nf * 16 + ll - 2048), p);
            }
        }
    }
}

// ===========================================================================
// Output projection v3: 64x128 tile, BK=64, double-buffered (qkv-v4
// structure): stage t+1 before compute t, one VMC(0)+BAR per tile -> 16
// covered drains instead of 32 exposed ones. LDS 48 KiB -> 2 blocks/CU
// resident (capacity 3). 4 waves (2M x 2N), per-wave 32x64 (acc 2x4).
// T1 XCD swizzle (each XCD owns one 128-col Wo^T panel) + T2 swizzle.
// ===========================================================================
#define OST(T, D) do {                                                                 \
    _Pragma("unroll") for (int _p = 0; _p < 2; ++_p)                                   \
        gload_lds16(aSrc + (size_t)(32 * _p) * 1024 + (size_t)(T) * 64,                \
                    aDstW + (D) * 8192 + _p * 4096);                                   \
    _Pragma("unroll") for (int _p = 0; _p < 4; ++_p)                                   \
        gload_lds16(bSrc + (size_t)(32 * _p) * 1024 + (size_t)(T) * 64,                \
                    bDstW + (D) * 16384 + _p * 4096);                                  \
} while (0)

__global__ __launch_bounds__(256, 2) void gemm_bt(const bf16* __restrict__ A,
                                                  const bf16* __restrict__ Bt,
                                                  float* __restrict__ C,
                                                  const float* __restrict__ bias,
                                                  int N, int K) {
    __shared__ bf16 smem[24576];  // 48 KiB: A[2][8K) at 0, B[2][16K) at 16384
    char* sc = (char*)smem;
    const int tid  = threadIdx.x;
    const int wv   = tid >> 6;
    const int lane = tid & 63;
    const int ll   = lane & 15;
    const int kh   = lane >> 4;
    const int wm   = wv >> 1;  // 0..1 : 32-row half
    const int wn   = wv & 1;   // 0..1 : 64-col half

    // XCD swizzle: 512 blocks; XCD owns one n-panel x all 64 m-tiles.
    const int flat = blockIdx.y * 64 + blockIdx.x;   // gridDim = (64,8)
    const int L    = (flat & 7) * 64 + (flat >> 3);  // bijective
    const int m0   = (L & 63) * 64;
    const int n0   = (L >> 6) * 128;

    const int swcol = (((tid & 7) ^ ((tid >> 3) & 7)) << 3);
    const bf16* aSrc = A + (size_t)(m0 + (tid >> 3)) * 1024 + swcol;
    const bf16* bSrc = Bt + (size_t)(n0 + (tid >> 3)) * 1024 + swcol;
    char* aDstW = sc + wv * 1024;
    char* bDstW = sc + 16384 + wv * 1024;

    const int aBase = wm * 4096 + ll * 128;          // rows wm*32 + mf*16 + ll
    const int bBase = (wn * 64 + ll) * 128;          // rows wn*64 + nf*16 + ll
    const int ks0 = ((kh ^ (ll & 7)) << 4);
    const int ks1 = (((4 | kh) ^ (ll & 7)) << 4);

    f32x4 acc[2][4] = {};
    const int NT = K / 64;  // 16

    OST(0, 0);
    VMC(0); BAR();

#pragma unroll 1
    for (int t = 0; t < NT; ++t) {
        const int d = t & 1;
        if (t + 1 < NT) OST(t + 1, d ^ 1);

        bf16x8 a[2][2], b[4][2];
#pragma unroll
        for (int mf = 0; mf < 2; ++mf) {
            a[mf][0] = *(const bf16x8*)(sc + d * 8192 + aBase + mf * 2048 + ks0);
            a[mf][1] = *(const bf16x8*)(sc + d * 8192 + aBase + mf * 2048 + ks1);
        }
#pragma unroll
        for (int nf = 0; nf < 4; ++nf) {
            b[nf][0] = *(const bf16x8*)(sc + 16384 + d * 16384 + bBase + nf * 2048 + ks0);
            b[nf][1] = *(const bf16x8*)(sc + 16384 + d * 16384 + bBase + nf * 2048 + ks1);
        }

        __builtin_amdgcn_s_setprio(1);
#pragma unroll
        for (int mf = 0; mf < 2; ++mf)
#pragma unroll
            for (int nf = 0; nf < 4; ++nf)
#pragma unroll
                for (int k = 0; k < 2; ++k)
                    acc[mf][nf] = __builtin_amdgcn_mfma_f32_16x16x32_bf16(
                        a[mf][k], b[nf][k], acc[mf][nf], 0, 0, 0);
        __builtin_amdgcn_s_setprio(0);

        VMC(0); BAR();
    }

#pragma unroll
    for (int mf = 0; mf < 2; ++mf) {
#pragma unroll
        for (int nf = 0; nf < 4; ++nf) {
            int col = n0 + wn * 64 + nf * 16 + ll;
            float bv_ = bias[col];
#pragma unroll
            for (int r = 0; r < 4; ++r) {
                int row = m0 + wm * 32 + mf * 16 + kh * 4 + r;
                C[(size_t)row * N + col] = acc[mf][nf][r] + bv_;
            }
        }
    }
}

// ---------------------------------------------------------------------------
// Band attention. Per block: one (b, h, 64-row i-tile).
//   w_ij = expm1(q_i . k_j / 8)  for |i-j| <= 8, 0 <= j < S
//   ctx_i = (sum_j w_ij v_j + Vsum) / (sum_j w_ij + S)
// ---------------------------------------------------------------------------
__global__ __launch_bounds__(256) void band_attn(const bf16* __restrict__ qkv,
                                                 const float* __restrict__ vsum,
                                                 bf16* __restrict__ ctx) {
    int bid = blockIdx.x;
    int it = bid & 31;
    int h  = (bid >> 5) & 15;
    int b  = bid >> 9;
    const int i0 = it * 64;

    __shared__ bf16 qs[64 * 72];
    __shared__ bf16 ks[80 * 72];
    __shared__ bf16 vs[80 * 72];
    __shared__ float wsc[64 * 19];
    __shared__ float wsum[64];

    int tid = threadIdx.x;

    for (int idx = tid; idx < 64 * 8; idx += 256) {
        int r = idx >> 3, c = idx & 7;
        size_t g = (size_t)(b * S_LEN + i0 + r) * 3072 + h * 64 + c * 8;
        *(int4*)&qs[r * 72 + c * 8] = *(const int4*)&qkv[g];
    }
    for (int idx = tid; idx < 80 * 8; idx += 256) {
        int r = idx >> 3, c = idx & 7;
        int j = i0 - 8 + r;
        int4 kv = {0, 0, 0, 0}, vv = {0, 0, 0, 0};
        if (j >= 0 && j < S_LEN) {
            size_t base = (size_t)(b * S_LEN + j) * 3072 + h * 64 + c * 8;
            kv = *(const int4*)&qkv[base + 1024];
            vv = *(const int4*)&qkv[base + 2048];
        }
        *(int4*)&ks[r * 72 + c * 8] = kv;
        *(int4*)&vs[r * 72 + c * 8] = vv;
    }
    __syncthreads();

    {
        int i = tid >> 2, jg = tid & 3;
        bf16x8 qv[8];
#pragma unroll
        for (int c = 0; c < 8; ++c) qv[c] = *(const bf16x8*)&qs[i * 72 + c * 8];
        for (int jj = jg; jj < 17; jj += 4) {
            int j = i0 + i - 8 + jj;
            float w = 0.f;
            if (j >= 0 && j < S_LEN) {
                float dot = 0.f;
#pragma unroll
                for (int c = 0; c < 8; ++c) {
                    bf16x8 kv = *(const bf16x8*)&ks[(i + jj) * 72 + c * 8];
#pragma unroll
                    for (int e = 0; e < 8; ++e) dot += (float)qv[c][e] * (float)kv[e];
                }
                w = expm1f(dot * 0.125f);
            }
            wsc[i * 19 + jj] = w;
        }
    }
    __syncthreads();
    if (tid < 64) {
        float s = 0.f;
#pragma unroll
        for (int jj = 0; jj < 17; ++jj) s += wsc[tid * 19 + jj];
        wsum[tid] = s + (float)S_LEN;
    }
    __syncthreads();

    {
        int d0 = (tid & 31) * 2, ig = tid >> 5;
        float vb0 = vsum[(b * NH + h) * HD_DIM + d0];
        float vb1 = vsum[(b * NH + h) * HD_DIM + d0 + 1];
        for (int i = ig; i < 64; i += 8) {
            float a0 = vb0, a1 = vb1;
#pragma unroll
            for (int jj = 0; jj < 17; ++jj) {
                float w = wsc[i * 19 + jj];
                bf16x2 pv = *(const bf16x2*)&vs[(i + jj) * 72 + d0];
                a0 += w * (float)pv[0];
                a1 += w * (float)pv[1];
            }
            float inv = 1.0f / wsum[i];
            bf16x2 st;
            st[0] = (bf16)(a0 * inv);
            st[1] = (bf16)(a1 * inv);
            *(bf16x2*)&ctx[(size_t)(b * S_LEN + i0 + i) * 1024 + h * 64 + d0] = st;
        }
    }
}

// ---------------------------------------------------------------------------
extern "C" void kernel_launch(void* const* d_in, const int* in_sizes, int n_in,
                              void* d_out, int out_size, void* d_ws, size_t ws_size,
                              hipStream_t stream) {
    const float* x  = (const float*)d_in[0];
    const float* Wq = (const float*)d_in[1];
    const float* Wk = (const float*)d_in[2];
    const float* Wv = (const float*)d_in[3];
    const float* Wo = (const float*)d_in[4];
    const float* bq = (const float*)d_in[5];
    const float* bk = (const float*)d_in[6];
    const float* bv = (const float*)d_in[7];
    const float* bo = (const float*)d_in[8];

    char* ws = (char*)d_ws;
    bf16*  xb    = (bf16*)(ws);                       // 8 MB   x as bf16
    bf16*  wtall = (bf16*)(ws + 8388608);             // 6 MB   [Wq^T;Wk^T;Wv^T] bf16 [3072][1024]
    bf16*  wot   = (bf16*)(ws + 14680064);            // 2 MB   Wo^T bf16 [1024][1024]
    float* ball  = (float*)(ws + 16777216);           // 12 KB  bias concat [3072]
    bf16*  qkv   = (bf16*)(ws + 16789504);            // 24 MB  [4096][3072] bf16
    bf16*  ctxb  = (bf16*)(ws + 41955328);            // 8 MB   ctx bf16 [4096][1024]
    float* vsm   = (float*)(ws + 50343936);           // 8 KB   [2][1024] == [b][h*64+d]

    // fused: cvt(2048 blocks) + 4x transpose(1024) + bias+vsm-seed(12)
    prep_all<<<3084, 256, 0, stream>>>(x, Wq, Wk, Wv, Wo, bq, bk, bv,
                                       xb, wtall, wot, ball, vsm);

    // QKV projection (+fused V column sums): [4096][1024] x [3072][1024]^T
    gemm_qkv<1024><<<dim3(32, 16), 256, 0, stream>>>(xb, wtall, qkv, ball, vsm, 3072);

    band_attn<<<1024, 256, 0, stream>>>(qkv, vsm, ctxb);

    // output projection -> d_out fp32
    gemm_bt<<<dim3(64, 8), 256, 0, stream>>>(ctxb, wot, (float*)d_out, bo, 1024, 1024);
}

// Round 13
// 71.113 us; speedup vs baseline: 1.6221x; 1.0199x over previous
//
#include <hip/hip_runtime.h>
#include <hip/hip_bf16.h>
#include <cmath>

// Problem constants (LocalAttention: B=2, S=2048, D=1024, H=16, HD=64, W=16)
#define S_LEN 2048
#define DMODEL 1024
#define NH 16
#define HD_DIM 64

typedef __bf16 bf16;
typedef __bf16 bf16x2 __attribute__((ext_vector_type(2)));
typedef __bf16 bf16x8 __attribute__((ext_vector_type(8)));
typedef float f32x4 __attribute__((ext_vector_type(4)));

// ---------------------------------------------------------------------------
// Fused preprocessing: block-range dispatch
//   [0,2048)      : x fp32 -> bf16 (8 elems/thread)
//   [2048,3072)   : W[K][N] fp32 -> Wt[N][K] bf16 transpose (4 matrices)
//   [3072,3084)   : bias concat bq|bk|bv -> ball[3072]; seed vsm = 2048*bv
// ---------------------------------------------------------------------------
__global__ __launch_bounds__(256) void prep_all(const float* __restrict__ x,
                                                const float* __restrict__ Wq,
                                                const float* __restrict__ Wk,
                                                const float* __restrict__ Wv,
                                                const float* __restrict__ Wo,
                                                const float* __restrict__ bq,
                                                const float* __restrict__ bk,
                                                const float* __restrict__ bv,
                                                bf16* __restrict__ xb,
                                                bf16* __restrict__ wtall,
                                                bf16* __restrict__ wot,
                                                float* __restrict__ ball,
                                                float* __restrict__ vsm) {
    __shared__ float tile[64][65];
    const int bid = blockIdx.x;
    const int tid = threadIdx.x;
    if (bid < 2048) {
        int i = (bid * 256 + tid) * 8;
        float4 v0 = *(const float4*)(x + i);
        float4 v1 = *(const float4*)(x + i + 4);
        bf16x8 o;
        o[0] = (bf16)v0.x; o[1] = (bf16)v0.y; o[2] = (bf16)v0.z; o[3] = (bf16)v0.w;
        o[4] = (bf16)v1.x; o[5] = (bf16)v1.y; o[6] = (bf16)v1.z; o[7] = (bf16)v1.w;
        *(bf16x8*)(xb + i) = o;
    } else if (bid < 3072) {
        int t = bid - 2048;
        int z = t >> 8;
        t &= 255;
        const float* W = (z == 0) ? Wq : (z == 1) ? Wk : (z == 2) ? Wv : Wo;
        bf16* Wt = (z == 3) ? wot : wtall + (size_t)z * 1048576;
        int n0 = (t & 15) * 64, k0 = (t >> 4) * 64;
        int tr = tid >> 6, tc = tid & 63;
#pragma unroll
        for (int i = 0; i < 16; ++i) {
            int r = tr + i * 4;
            tile[r][tc] = W[(size_t)(k0 + r) * DMODEL + n0 + tc];
        }
        __syncthreads();
#pragma unroll
        for (int i = 0; i < 16; ++i) {
            int r = tr + i * 4;  // local n index
            Wt[(size_t)(n0 + r) * DMODEL + k0 + tc] = (bf16)tile[tc][r];
        }
    } else {
        int i = (bid - 3072) * 256 + tid;  // 0..3071
        float v = (i < 1024) ? bq[i] : (i < 2048) ? bk[i - 1024] : bv[i - 2048];
        ball[i] = v;
        if (i >= 2048) {
            // seed V column-sum accumulators with the bias term (and clear poison)
            int c = i - 2048;
            vsm[c]        = 2048.0f * v;
            vsm[1024 + c] = 2048.0f * v;
        }
    }
}

// ---------------------------------------------------------------------------
// async global->LDS, 16B per lane (dest = wave-uniform base + lane*16)
// ---------------------------------------------------------------------------
__device__ __forceinline__ void gload_lds16(const void* g, void* l) {
    __builtin_amdgcn_global_load_lds((const __attribute__((address_space(1))) void*)g,
                                     (__attribute__((address_space(3))) void*)l, 16, 0, 0);
}

#define BAR() asm volatile("s_barrier" ::: "memory")
#define VMC(N) asm volatile("s_waitcnt vmcnt(" #N ")" ::: "memory")

// ===========================================================================
// QKV GEMM v4 (R11-proven): 128x192 tile, BK=64, 256 threads = 4 waves
// (2M x 2N), per-wave 64x96 output (acc 4mf x 6nf = 96 VGPR).
// LDS 80 KiB dbuf -> 2 blocks/CU (cross-block TLP covers per-tile drain).
// NOTE on sync (R12 lesson): vmcnt is per-wave but the LDS tile is filled by
// all 4 waves cooperatively -> every load group needs wait-THEN-barrier for
// cross-wave visibility. VMC(0); BAR() per tile satisfies this; counted
// waits placed after the barrier do NOT (that was R12's race).
// XCD swizzle v2: same-m block pairs adjacent within an XCD (concurrent) so
// the 256 KB A row-panel's second read is an L2 hit instead of L3.
// Epilogue folds V column-sums (cols >= 2048) into vsm (shfl + atomicAdd).
// ===========================================================================
#define QST(T, D) do {                                                                 \
    _Pragma("unroll") for (int _p = 0; _p < 4; ++_p)                                   \
        gload_lds16(aSrc + (size_t)(32 * _p) * KDIM + (size_t)(T) * 64,                \
                    aDstW + (D) * 16384 + _p * 4096);                                  \
    _Pragma("unroll") for (int _p = 0; _p < 6; ++_p)                                   \
        gload_lds16(bSrc + (size_t)(32 * _p) * KDIM + (size_t)(T) * 64,                \
                    bDstW + (D) * 24576 + _p * 4096);                                  \
} while (0)

template <int KDIM>
__global__ __launch_bounds__(256, 2) void gemm_qkv(const bf16* __restrict__ A,
                                                   const bf16* __restrict__ Bt,
                                                   bf16* __restrict__ C,
                                                   const float* __restrict__ bias,
                                                   float* __restrict__ vsm,
                                                   int N) {
    __shared__ bf16 smem[40960];  // 80 KiB: A[2][16K) at 0, B[2][24K) at 32768
    char* sc = (char*)smem;

    const int tid  = threadIdx.x;
    const int wv   = tid >> 6;
    const int lane = tid & 63;
    const int ll   = lane & 15;
    const int kh   = lane >> 4;
    const int wm   = wv >> 1;  // 0..1 : 64-row half
    const int wn   = wv & 1;   // 0..1 : 96-col half

    // XCD swizzle v2: XCD = flat%8 owns n-panels {2*xcd, 2*xcd+1}; within the
    // XCD, blocks are ordered (m, n-pair) so same-m blocks are concurrent.
    const int flat = blockIdx.y * 32 + blockIdx.x;   // gridDim = (32,16)
    const int L    = (flat & 7) * 64 + (flat >> 3);  // bijective (512 blocks)
    const int m0   = ((L & 63) >> 1) * 128;          // 0..31
    const int n0   = ((L >> 6) * 2 + (L & 1)) * 192; // 0..15

    // Staging: inverse-swizzled global source, linear LDS dest (4KB pieces,
    // 32 rows each; row%8 == (tid>>3)%8 for every piece -> one swcol works).
    const int swcol = (((tid & 7) ^ ((tid >> 3) & 7)) << 3);
    const bf16* aSrc = A + (size_t)(m0 + (tid >> 3)) * KDIM + swcol;
    const bf16* bSrc = Bt + (size_t)(n0 + (tid >> 3)) * KDIM + swcol;
    char* aDstW = sc + wv * 1024;
    char* bDstW = sc + 32768 + wv * 1024;

    // Read side: XOR-swizzle ((row&7)<<4); row&7 == ll&7 for all fragments.
    const int aBase = wm * 8192 + ll * 128;          // rows wm*64 + mf*16 + ll
    const int bBase = (wn * 96 + ll) * 128;          // rows wn*96 + nf*16 + ll
    const int ks0 = ((kh ^ (ll & 7)) << 4);
    const int ks1 = (((4 | kh) ^ (ll & 7)) << 4);

    f32x4 acc[4][6] = {};

    constexpr int NT = KDIM / 64;  // 16 K-tiles

    QST(0, 0);
    VMC(0); BAR();

#pragma unroll 1
    for (int t = 0; t < NT; ++t) {
        const int d = t & 1;
        if (t + 1 < NT) QST(t + 1, d ^ 1);

        bf16x8 a[4][2], b[3][2];
#pragma unroll
        for (int mf = 0; mf < 4; ++mf) {
            a[mf][0] = *(const bf16x8*)(sc + d * 16384 + aBase + mf * 2048 + ks0);
            a[mf][1] = *(const bf16x8*)(sc + d * 16384 + aBase + mf * 2048 + ks1);
        }
        // B chunk 0: nf 0..2
#pragma unroll
        for (int nf = 0; nf < 3; ++nf) {
            b[nf][0] = *(const bf16x8*)(sc + 32768 + d * 24576 + bBase + nf * 2048 + ks0);
            b[nf][1] = *(const bf16x8*)(sc + 32768 + d * 24576 + bBase + nf * 2048 + ks1);
        }
        __builtin_amdgcn_s_setprio(1);
#pragma unroll
        for (int mf = 0; mf < 4; ++mf)
#pragma unroll
            for (int nf = 0; nf < 3; ++nf)
#pragma unroll
                for (int k = 0; k < 2; ++k)
                    acc[mf][nf] = __builtin_amdgcn_mfma_f32_16x16x32_bf16(
                        a[mf][k], b[nf][k], acc[mf][nf], 0, 0, 0);
        __builtin_amdgcn_s_setprio(0);
        // B chunk 1: nf 3..5
#pragma unroll
        for (int nf = 0; nf < 3; ++nf) {
            b[nf][0] = *(const bf16x8*)(sc + 32768 + d * 24576 + bBase + (nf + 3) * 2048 + ks0);
            b[nf][1] = *(const bf16x8*)(sc + 32768 + d * 24576 + bBase + (nf + 3) * 2048 + ks1);
        }
        __builtin_amdgcn_s_setprio(1);
#pragma unroll
        for (int mf = 0; mf < 4; ++mf)
#pragma unroll
            for (int nf = 0; nf < 3; ++nf)
#pragma unroll
                for (int k = 0; k < 2; ++k)
                    acc[mf][nf + 3] = __builtin_amdgcn_mfma_f32_16x16x32_bf16(
                        a[mf][k], b[nf][k], acc[mf][nf + 3], 0, 0, 0);
        __builtin_amdgcn_s_setprio(0);

        VMC(0); BAR();  // next tile staged; co-resident block covers drain
    }

    // ---- C write: row = m0+wm*64+mf*16+kh*4+r, col = n0+wn*96+nf*16+ll ----
#pragma unroll
    for (int nf = 0; nf < 6; ++nf) {
        const int col = n0 + wn * 96 + nf * 16 + ll;
        const float bv_ = bias[col];
#pragma unroll
        for (int mf = 0; mf < 4; ++mf) {
            const int row = m0 + wm * 64 + mf * 16 + kh * 4;
#pragma unroll
            for (int r = 0; r < 4; ++r)
                C[(size_t)(row + r) * N + col] = (bf16)(acc[mf][nf][r] + bv_);
        }
    }

    // ---- fused V column-sums (V cols = 2048..3071) ----
    {
        const int bidx = m0 >> 11;  // 128-row tile lies in one batch
#pragma unroll
        for (int nf = 0; nf < 6; ++nf) {
            if (n0 + wn * 96 + nf * 16 >= 2048) {  // wave-uniform predicate
                float p = 0.f;
#pragma unroll
                for (int mf = 0; mf < 4; ++mf)
#pragma unroll
                    for (int r = 0; r < 4; ++r) p += acc[mf][nf][r];
                p += __shfl_xor(p, 16);
                p += __shfl_xor(p, 32);
                if (kh == 0)
                    atomicAdd(vsm + bidx * 1024 + (n0 + wn * 96 + nf * 16 + ll - 2048), p);
            }
        }
    }
}

// ===========================================================================
// Output projection v3 (R11-proven): 64x128 tile, BK=64, dbuf 48 KiB,
// 4 waves (2M x 2N), per-wave 32x64 (acc 2x4); stage t+1 before compute t,
// one VMC(0)+BAR per tile (wait-then-barrier: cross-wave-safe).
// T1 XCD swizzle (each XCD owns one 128-col Wo^T panel) + T2 swizzle.
// ===========================================================================
#define OST(T, D) do {                                                                 \
    _Pragma("unroll") for (int _p = 0; _p < 2; ++_p)                                   \
        gload_lds16(aSrc + (size_t)(32 * _p) * 1024 + (size_t)(T) * 64,                \
                    aDstW + (D) * 8192 + _p * 4096);                                   \
    _Pragma("unroll") for (int _p = 0; _p < 4; ++_p)                                   \
        gload_lds16(bSrc + (size_t)(32 * _p) * 1024 + (size_t)(T) * 64,                \
                    bDstW + (D) * 16384 + _p * 4096);                                  \
} while (0)

__global__ __launch_bounds__(256, 2) void gemm_bt(const bf16* __restrict__ A,
                                                  const bf16* __restrict__ Bt,
                                                  float* __restrict__ C,
                                                  const float* __restrict__ bias,
                                                  int N, int K) {
    __shared__ bf16 smem[24576];  // 48 KiB: A[2][8K) at 0, B[2][16K) at 16384
    char* sc = (char*)smem;
    const int tid  = threadIdx.x;
    const int wv   = tid >> 6;
    const int lane = tid & 63;
    const int ll   = lane & 15;
    const int kh   = lane >> 4;
    const int wm   = wv >> 1;  // 0..1 : 32-row half
    const int wn   = wv & 1;   // 0..1 : 64-col half

    // XCD swizzle: 512 blocks; XCD owns one n-panel x all 64 m-tiles.
    const int flat = blockIdx.y * 64 + blockIdx.x;   // gridDim = (64,8)
    const int L    = (flat & 7) * 64 + (flat >> 3);  // bijective
    const int m0   = (L & 63) * 64;
    const int n0   = (L >> 6) * 128;

    const int swcol = (((tid & 7) ^ ((tid >> 3) & 7)) << 3);
    const bf16* aSrc = A + (size_t)(m0 + (tid >> 3)) * 1024 + swcol;
    const bf16* bSrc = Bt + (size_t)(n0 + (tid >> 3)) * 1024 + swcol;
    char* aDstW = sc + wv * 1024;
    char* bDstW = sc + 16384 + wv * 1024;

    const int aBase = wm * 4096 + ll * 128;          // rows wm*32 + mf*16 + ll
    const int bBase = (wn * 64 + ll) * 128;          // rows wn*64 + nf*16 + ll
    const int ks0 = ((kh ^ (ll & 7)) << 4);
    const int ks1 = (((4 | kh) ^ (ll & 7)) << 4);

    f32x4 acc[2][4] = {};
    const int NT = K / 64;  // 16

    OST(0, 0);
    VMC(0); BAR();

#pragma unroll 1
    for (int t = 0; t < NT; ++t) {
        const int d = t & 1;
        if (t + 1 < NT) OST(t + 1, d ^ 1);

        bf16x8 a[2][2], b[4][2];
#pragma unroll
        for (int mf = 0; mf < 2; ++mf) {
            a[mf][0] = *(const bf16x8*)(sc + d * 8192 + aBase + mf * 2048 + ks0);
            a[mf][1] = *(const bf16x8*)(sc + d * 8192 + aBase + mf * 2048 + ks1);
        }
#pragma unroll
        for (int nf = 0; nf < 4; ++nf) {
            b[nf][0] = *(const bf16x8*)(sc + 16384 + d * 16384 + bBase + nf * 2048 + ks0);
            b[nf][1] = *(const bf16x8*)(sc + 16384 + d * 16384 + bBase + nf * 2048 + ks1);
        }

        __builtin_amdgcn_s_setprio(1);
#pragma unroll
        for (int mf = 0; mf < 2; ++mf)
#pragma unroll
            for (int nf = 0; nf < 4; ++nf)
#pragma unroll
                for (int k = 0; k < 2; ++k)
                    acc[mf][nf] = __builtin_amdgcn_mfma_f32_16x16x32_bf16(
                        a[mf][k], b[nf][k], acc[mf][nf], 0, 0, 0);
        __builtin_amdgcn_s_setprio(0);

        VMC(0); BAR();
    }

#pragma unroll
    for (int mf = 0; mf < 2; ++mf) {
#pragma unroll
        for (int nf = 0; nf < 4; ++nf) {
            int col = n0 + wn * 64 + nf * 16 + ll;
            float bv_ = bias[col];
#pragma unroll
            for (int r = 0; r < 4; ++r) {
                int row = m0 + wm * 32 + mf * 16 + kh * 4 + r;
                C[(size_t)row * N + col] = acc[mf][nf][r] + bv_;
            }
        }
    }
}

// ---------------------------------------------------------------------------
// Band attention. Per block: one (b, h, 64-row i-tile).
//   w_ij = expm1(q_i . k_j / 8)  for |i-j| <= 8, 0 <= j < S
//   ctx_i = (sum_j w_ij v_j + Vsum) / (sum_j w_ij + S)
// ---------------------------------------------------------------------------
__global__ __launch_bounds__(256) void band_attn(const bf16* __restrict__ qkv,
                                                 const float* __restrict__ vsum,
                                                 bf16* __restrict__ ctx) {
    int bid = blockIdx.x;
    int it = bid & 31;
    int h  = (bid >> 5) & 15;
    int b  = bid >> 9;
    const int i0 = it * 64;

    __shared__ bf16 qs[64 * 72];
    __shared__ bf16 ks[80 * 72];
    __shared__ bf16 vs[80 * 72];
    __shared__ float wsc[64 * 19];
    __shared__ float wsum[64];

    int tid = threadIdx.x;

    for (int idx = tid; idx < 64 * 8; idx += 256) {
        int r = idx >> 3, c = idx & 7;
        size_t g = (size_t)(b * S_LEN + i0 + r) * 3072 + h * 64 + c * 8;
        *(int4*)&qs[r * 72 + c * 8] = *(const int4*)&qkv[g];
    }
    for (int idx = tid; idx < 80 * 8; idx += 256) {
        int r = idx >> 3, c = idx & 7;
        int j = i0 - 8 + r;
        int4 kv = {0, 0, 0, 0}, vv = {0, 0, 0, 0};
        if (j >= 0 && j < S_LEN) {
            size_t base = (size_t)(b * S_LEN + j) * 3072 + h * 64 + c * 8;
            kv = *(const int4*)&qkv[base + 1024];
            vv = *(const int4*)&qkv[base + 2048];
        }
        *(int4*)&ks[r * 72 + c * 8] = kv;
        *(int4*)&vs[r * 72 + c * 8] = vv;
    }
    __syncthreads();

    // phase 2: band weights (q-row hoisted to registers, reused over jj)
    {
        int i = tid >> 2, jg = tid & 3;
        bf16x8 qv[8];
#pragma unroll
        for (int c = 0; c < 8; ++c) qv[c] = *(const bf16x8*)&qs[i * 72 + c * 8];
        for (int jj = jg; jj < 17; jj += 4) {
            int j = i0 + i - 8 + jj;
            float w = 0.f;
            if (j >= 0 && j < S_LEN) {
                float dot = 0.f;
#pragma unroll
                for (int c = 0; c < 8; ++c) {
                    bf16x8 kv = *(const bf16x8*)&ks[(i + jj) * 72 + c * 8];
#pragma unroll
                    for (int e = 0; e < 8; ++e) dot += (float)qv[c][e] * (float)kv[e];
                }
                w = expm1f(dot * 0.125f);
            }
            wsc[i * 19 + jj] = w;
        }
    }
    __syncthreads();
    if (tid < 64) {
        float s = 0.f;
#pragma unroll
        for (int jj = 0; jj < 17; ++jj) s += wsc[tid * 19 + jj];
        wsum[tid] = s + (float)S_LEN;
    }
    __syncthreads();

    // phase 3: weighted V accumulation, 8 cols/thread (b128 LDS reads: 34
    // instead of 136 b32 per thread; 16B stores). Alignment: vs row stride
    // 144B and d0*2 are both multiples of 16.
    {
        int d0 = (tid & 7) * 8, ig = tid >> 3;  // 8 col-groups x 32 i-groups
        const float* vbp = vsum + (b * NH + h) * HD_DIM + d0;
        float vb[8];
#pragma unroll
        for (int e = 0; e < 8; ++e) vb[e] = vbp[e];
        for (int i = ig; i < 64; i += 32) {
            float a[8];
#pragma unroll
            for (int e = 0; e < 8; ++e) a[e] = vb[e];
#pragma unroll
            for (int jj = 0; jj < 17; ++jj) {
                float w = wsc[i * 19 + jj];
                bf16x8 pv = *(const bf16x8*)&vs[(i + jj) * 72 + d0];
#pragma unroll
                for (int e = 0; e < 8; ++e) a[e] += w * (float)pv[e];
            }
            float inv = 1.0f / wsum[i];
            bf16x8 st;
#pragma unroll
            for (int e = 0; e < 8; ++e) st[e] = (bf16)(a[e] * inv);
            *(bf16x8*)&ctx[(size_t)(b * S_LEN + i0 + i) * 1024 + h * 64 + d0] = st;
        }
    }
}

// ---------------------------------------------------------------------------
extern "C" void kernel_launch(void* const* d_in, const int* in_sizes, int n_in,
                              void* d_out, int out_size, void* d_ws, size_t ws_size,
                              hipStream_t stream) {
    const float* x  = (const float*)d_in[0];
    const float* Wq = (const float*)d_in[1];
    const float* Wk = (const float*)d_in[2];
    const float* Wv = (const float*)d_in[3];
    const float* Wo = (const float*)d_in[4];
    const float* bq = (const float*)d_in[5];
    const float* bk = (const float*)d_in[6];
    const float* bv = (const float*)d_in[7];
    const float* bo = (const float*)d_in[8];

    char* ws = (char*)d_ws;
    bf16*  xb    = (bf16*)(ws);                       // 8 MB   x as bf16
    bf16*  wtall = (bf16*)(ws + 8388608);             // 6 MB   [Wq^T;Wk^T;Wv^T] bf16 [3072][1024]
    bf16*  wot   = (bf16*)(ws + 14680064);            // 2 MB   Wo^T bf16 [1024][1024]
    float* ball  = (float*)(ws + 16777216);           // 12 KB  bias concat [3072]
    bf16*  qkv   = (bf16*)(ws + 16789504);            // 24 MB  [4096][3072] bf16
    bf16*  ctxb  = (bf16*)(ws + 41955328);            // 8 MB   ctx bf16 [4096][1024]
    float* vsm   = (float*)(ws + 50343936);           // 8 KB   [2][1024] == [b][h*64+d]

    // fused: cvt(2048 blocks) + 4x transpose(1024) + bias+vsm-seed(12)
    prep_all<<<3084, 256, 0, stream>>>(x, Wq, Wk, Wv, Wo, bq, bk, bv,
                                       xb, wtall, wot, ball, vsm);

    // QKV projection (+fused V column sums): [4096][1024] x [3072][1024]^T
    gemm_qkv<1024><<<dim3(32, 16), 256, 0, stream>>>(xb, wtall, qkv, ball, vsm, 3072);

    band_attn<<<1024, 256, 0, stream>>>(qkv, vsm, ctxb);

    // output projection -> d_out fp32
    gemm_bt<<<dim3(64, 8), 256, 0, stream>>>(ctxb, wot, (float*)d_out, bo, 1024, 1024);
}